// Round 5
// baseline (8787.286 us; speedup 1.0000x reference)
//
#include <hip/hip_runtime.h>
#include <stdint.h>

typedef __attribute__((ext_vector_type(8))) __bf16 bf16x8;
typedef __attribute__((ext_vector_type(4))) float f32x4;
typedef __attribute__((ext_vector_type(8))) short short8;

__device__ __forceinline__ unsigned short f2bf(float f) {
  unsigned int u = __float_as_uint(f);
  u += 0x7FFFu + ((u >> 16) & 1u);
  return (unsigned short)(u >> 16);
}
__device__ __forceinline__ float bf2f(unsigned short h) {
  return __uint_as_float((unsigned int)h << 16);
}
__device__ __forceinline__ void split2(float v, unsigned short& h, unsigned short& l) {
  h = f2bf(v);
  l = f2bf(v - bf2f(h));
}

// ---------------------------------------------------------------------------
// Split-bf16 MFMA GEMM: C = act(A @ Wt^T + bias), f32-equivalent precision.
// A logical [M,K] f32; W planes rowpair [N][2K] bf16 (hi K || lo K).
// C ~= Ah*Bh + Ah*Bl + Al*Bh (3 MFMAs), f32 accum.
// BM=BN=128, BK=32, 256 threads (4 waves 2x2), 16x16x32 bf16 MFMA.
// ASRC: 0 = A planes rowpair [M][2K]; 1 = A f32 [M][K], relu+split at staging;
//       2 = gather: row r=(i*52+j)*32+b -> concat(pn[i*32+b], pn[j*32+b]),
//           pn planes rowpair [1664][1024] (K=1024).
// COUT: 0 = f32 raw (+bias); 1 = relu planes rowpair [M][2*ldc];
//       2 = maxout: relu(colmax+bias) -> atomicMax f32-bits Omax[obj*512+n],
//           obj=(m_base+m0)>>10 (128 rows per block are within one object).
// ---------------------------------------------------------------------------
template<int ASRC, int COUT>
__global__ __launch_bounds__(256)
void gemm_split(const void* __restrict__ Asrc,
                const unsigned short* __restrict__ Wt,
                const float* __restrict__ bias,
                void* __restrict__ Cdst,
                unsigned int* __restrict__ Omax,
                int M, int K, int ldc, int ntn, int swz8, int m_base)
{
  __shared__ __align__(16) short AsH[128][40];  // 32 k + 8 pad (80B rows)
  __shared__ __align__(16) short AsL[128][40];
  __shared__ __align__(16) short BsH[128][40];
  __shared__ __align__(16) short BsL[128][40];

  int bid = blockIdx.x;
  int mt, nt;
  if (swz8) {                      // XCD-aware swizzle (requires Mtiles%8==0)
    int xcd = bid & 7;
    int slot = bid >> 3;
    nt = slot % ntn;
    mt = (slot / ntn) * 8 + xcd;
  } else {
    mt = bid / ntn;
    nt = bid - mt * ntn;
  }
  const int m0 = mt * 128, n0 = nt * 128;
  const int tid = threadIdx.x;
  const int wave = tid >> 6, lane = tid & 63;
  const int wm = wave >> 1, wn = wave & 1;
  const int l15 = lane & 15, l4 = lane >> 4;

  const unsigned short* arow[2];
  const unsigned short* arow2[2];
  const float* arowf[2];
  const unsigned short* brow[2];
  #pragma unroll
  for (int rep = 0; rep < 2; ++rep) {
    int idx = rep * 256 + tid;
    int row = idx >> 2;
    int r = m0 + row;
    if (ASRC == 2) {
      int b = r & 31;
      int pair = r >> 5;
      int i = pair / 52;
      int j = pair - i * 52;
      arow[rep]  = (const unsigned short*)Asrc + (size_t)(i * 32 + b) * 1024;
      arow2[rep] = (const unsigned short*)Asrc + (size_t)(j * 32 + b) * 1024;
    } else if (ASRC == 1) {
      arowf[rep] = (const float*)Asrc + (size_t)r * K;
    } else {
      arow[rep] = (const unsigned short*)Asrc + (size_t)r * 2 * K;
    }
    brow[rep] = Wt + (size_t)(n0 + row) * 2 * K;
  }

  f32x4 acc[4][4];
  #pragma unroll
  for (int a = 0; a < 4; ++a)
    #pragma unroll
    for (int b = 0; b < 4; ++b)
      acc[a][b] = (f32x4){0.f, 0.f, 0.f, 0.f};

  for (int k0 = 0; k0 < K; k0 += 32) {
    #pragma unroll
    for (int rep = 0; rep < 2; ++rep) {
      int idx = rep * 256 + tid;
      int row = idx >> 2;
      int ch = idx & 3;
      int k = k0 + ch * 8;
      short8 hi, lo;
      if (ASRC == 1) {
        f32x4 v0 = *reinterpret_cast<const f32x4*>(arowf[rep] + k);
        f32x4 v1 = *reinterpret_cast<const f32x4*>(arowf[rep] + k + 4);
        #pragma unroll
        for (int e = 0; e < 4; ++e) {
          unsigned short h, l;
          split2(fmaxf(v0[e], 0.f), h, l);
          hi[e] = (short)h; lo[e] = (short)l;
          split2(fmaxf(v1[e], 0.f), h, l);
          hi[4 + e] = (short)h; lo[4 + e] = (short)l;
        }
      } else if (ASRC == 2) {
        const unsigned short* base = (k0 < 512) ? arow[rep] : arow2[rep];
        int kk = (k0 < 512) ? k : (k - 512);
        hi = *reinterpret_cast<const short8*>(base + kk);
        lo = *reinterpret_cast<const short8*>(base + 512 + kk);
      } else {
        hi = *reinterpret_cast<const short8*>(arow[rep] + k);
        lo = *reinterpret_cast<const short8*>(arow[rep] + K + k);
      }
      *reinterpret_cast<short8*>(&AsH[row][ch * 8]) = hi;
      *reinterpret_cast<short8*>(&AsL[row][ch * 8]) = lo;
      short8 wh = *reinterpret_cast<const short8*>(brow[rep] + k);
      short8 wl = *reinterpret_cast<const short8*>(brow[rep] + K + k);
      *reinterpret_cast<short8*>(&BsH[row][ch * 8]) = wh;
      *reinterpret_cast<short8*>(&BsL[row][ch * 8]) = wl;
    }
    __syncthreads();
    {
      bf16x8 ah[4], al[4], bh[4], bl[4];
      #pragma unroll
      for (int mi = 0; mi < 4; ++mi) {
        ah[mi] = *reinterpret_cast<const bf16x8*>(&AsH[wm * 64 + mi * 16 + l15][l4 * 8]);
        al[mi] = *reinterpret_cast<const bf16x8*>(&AsL[wm * 64 + mi * 16 + l15][l4 * 8]);
      }
      #pragma unroll
      for (int ni = 0; ni < 4; ++ni) {
        bh[ni] = *reinterpret_cast<const bf16x8*>(&BsH[wn * 64 + ni * 16 + l15][l4 * 8]);
        bl[ni] = *reinterpret_cast<const bf16x8*>(&BsL[wn * 64 + ni * 16 + l15][l4 * 8]);
      }
      #pragma unroll
      for (int mi = 0; mi < 4; ++mi)
        #pragma unroll
        for (int ni = 0; ni < 4; ++ni) {
          acc[mi][ni] = __builtin_amdgcn_mfma_f32_16x16x32_bf16(ah[mi], bh[ni], acc[mi][ni], 0, 0, 0);
          acc[mi][ni] = __builtin_amdgcn_mfma_f32_16x16x32_bf16(ah[mi], bl[ni], acc[mi][ni], 0, 0, 0);
          acc[mi][ni] = __builtin_amdgcn_mfma_f32_16x16x32_bf16(al[mi], bh[ni], acc[mi][ni], 0, 0, 0);
        }
    }
    __syncthreads();
  }

  if (COUT == 2) {
    int obj = (m_base + m0) >> 10;
    #pragma unroll
    for (int ni = 0; ni < 4; ++ni) {
      int n = n0 + wn * 64 + ni * 16 + l15;
      float v = acc[0][ni][0];
      #pragma unroll
      for (int mi = 0; mi < 4; ++mi)
        #pragma unroll
        for (int i = 0; i < 4; ++i)
          v = fmaxf(v, acc[mi][ni][i]);
      v = fmaxf(v + bias[n], 0.0f);       // max then +bias then relu == max of relu
      v = fmaxf(v, __shfl_xor(v, 16));
      v = fmaxf(v, __shfl_xor(v, 32));
      if (l4 == 0)
        atomicMax(&Omax[(size_t)obj * 512 + n], __float_as_uint(v));
    }
  } else if (COUT == 1) {
    unsigned short* Cp = (unsigned short*)Cdst;
    #pragma unroll
    for (int mi = 0; mi < 4; ++mi) {
      #pragma unroll
      for (int i = 0; i < 4; ++i) {
        int m = m0 + wm * 64 + mi * 16 + l4 * 4 + i;
        size_t base = (size_t)m * 2 * ldc + n0 + wn * 64;
        #pragma unroll
        for (int ni = 0; ni < 4; ++ni) {
          int nl = ni * 16 + l15;
          float v = fmaxf(acc[mi][ni][i] + bias[n0 + wn * 64 + nl], 0.f);
          unsigned short h, l;
          split2(v, h, l);
          Cp[base + nl] = h;
          Cp[base + ldc + nl] = l;
        }
      }
    }
  } else {
    float* Cf = (float*)Cdst;
    #pragma unroll
    for (int mi = 0; mi < 4; ++mi) {
      #pragma unroll
      for (int i = 0; i < 4; ++i) {
        int m = m0 + wm * 64 + mi * 16 + l4 * 4 + i;
        float* crow = Cf + (size_t)m * ldc + n0 + wn * 64;
        #pragma unroll
        for (int ni = 0; ni < 4; ++ni) {
          int nl = ni * 16 + l15;
          crow[nl] = acc[mi][ni][i] + bias[n0 + wn * 64 + nl];
        }
      }
    }
  }
}

// ---------------------------------------------------------------------------
// Per-point MLPs (f32 exact), outputs stored as relu'd hi/lo planes:
//   sparse: (x,y,z) -> 32 -> 64   -> s2 rowpair [pt][128]
//   dense:  6 -> 64 -> 128        -> h2 rowpair [pt][256]
// ---------------------------------------------------------------------------
__global__ __launch_bounds__(256)
void points_kernel(const float* __restrict__ obj6,
                   const float* __restrict__ sW0, const float* __restrict__ sb0,
                   const float* __restrict__ sW1, const float* __restrict__ sb1,
                   const float* __restrict__ dW0, const float* __restrict__ db0,
                   const float* __restrict__ dW1, const float* __restrict__ db1,
                   unsigned short* __restrict__ s2,
                   unsigned short* __restrict__ h2)
{
  __shared__ float sw0[96], sbb0[32], sw1[2048], sbb1[64];
  __shared__ float dw0[384], dbb0[64], dw1[8192], dbb1[128];
  int tid = threadIdx.x;
  for (int i = tid; i < 96; i += 256) sw0[i] = sW0[i];
  if (tid < 32) sbb0[tid] = sb0[tid];
  for (int i = tid; i < 2048; i += 256) sw1[i] = sW1[i];
  if (tid < 64) sbb1[tid] = sb1[tid];
  for (int i = tid; i < 384; i += 256) dw0[i] = dW0[i];
  if (tid < 64) dbb0[tid] = db0[tid];
  for (int i = tid; i < 8192; i += 256) dw1[i] = dW1[i];
  if (tid < 128) dbb1[tid] = db1[tid];
  __syncthreads();

  int pt = blockIdx.x * 256 + tid;
  const float* in = obj6 + (size_t)pt * 6;
  float c0 = in[0], c1 = in[1], c2 = in[2], c3 = in[3], c4 = in[4], c5 = in[5];

  {  // sparse (xyz only)
    float h1[32];
    #pragma unroll
    for (int j = 0; j < 32; ++j)
      h1[j] = fmaxf(c0 * sw0[j] + c1 * sw0[32 + j] + c2 * sw0[64 + j] + sbb0[j], 0.f);
    unsigned short* orow = s2 + (size_t)pt * 128;
    #pragma unroll
    for (int j8 = 0; j8 < 8; ++j8) {
      float a[8];
      #pragma unroll
      for (int e = 0; e < 8; ++e) a[e] = sbb1[j8 * 8 + e];
      #pragma unroll
      for (int i = 0; i < 32; ++i) {
        float hv = h1[i];
        #pragma unroll
        for (int e = 0; e < 8; ++e) a[e] += hv * sw1[i * 64 + j8 * 8 + e];
      }
      short8 oh, ol;
      #pragma unroll
      for (int e = 0; e < 8; ++e) {
        unsigned short h, l;
        split2(fmaxf(a[e], 0.f), h, l);
        oh[e] = (short)h; ol[e] = (short)l;
      }
      *reinterpret_cast<short8*>(orow + j8 * 8) = oh;
      *reinterpret_cast<short8*>(orow + 64 + j8 * 8) = ol;
    }
  }

  {  // dense (all 6 dims)
    float h1[64];
    #pragma unroll
    for (int j = 0; j < 64; ++j) {
      float a = dbb0[j] + c0 * dw0[j] + c1 * dw0[64 + j] + c2 * dw0[128 + j]
              + c3 * dw0[192 + j] + c4 * dw0[256 + j] + c5 * dw0[320 + j];
      h1[j] = fmaxf(a, 0.f);
    }
    unsigned short* orow = h2 + (size_t)pt * 256;
    #pragma unroll
    for (int ch = 0; ch < 4; ++ch) {
      float a[32];
      #pragma unroll
      for (int e = 0; e < 32; ++e) a[e] = dbb1[ch * 32 + e];
      #pragma unroll 8
      for (int i = 0; i < 64; ++i) {
        float hv = h1[i];
        #pragma unroll
        for (int e = 0; e < 32; ++e) a[e] += hv * dw1[i * 128 + ch * 32 + e];
      }
      #pragma unroll
      for (int e8 = 0; e8 < 4; ++e8) {
        short8 oh, ol;
        #pragma unroll
        for (int e = 0; e < 8; ++e) {
          unsigned short h, l;
          split2(fmaxf(a[e8 * 8 + e], 0.f), h, l);
          oh[e] = (short)h; ol[e] = (short)l;
        }
        *reinterpret_cast<short8*>(orow + ch * 32 + e8 * 8) = oh;
        *reinterpret_cast<short8*>(orow + 128 + ch * 32 + e8 * 8) = ol;
      }
    }
  }
}

// ---------------------------------------------------------------------------
// [K,N] f32 -> planes rowpair [N][2K] bf16 (hi row || lo row)
__global__ void transpose_split(const float* __restrict__ W, unsigned short* __restrict__ Wt,
                                int K, int N)
{
  int id = blockIdx.x * 256 + threadIdx.x;
  if (id >= K * N) return;
  int k = id / N, n = id - k * N;
  unsigned short h, l;
  split2(W[id], h, l);
  Wt[(size_t)n * 2 * K + k] = h;
  Wt[(size_t)n * 2 * K + K + k] = l;
}

__global__ void zero_kernel(unsigned int* __restrict__ p, int n)
{
  int id = blockIdx.x * 256 + threadIdx.x;
  if (id < n) p[id] = 0u;
}

// pnmax f32 (indexed o=b*52+n) -> pn planes rowpair [(n*32+b)][1024]
__global__ void pn_split_kernel(const float* __restrict__ pnf, unsigned short* __restrict__ pnp)
{
  int id = blockIdx.x * 256 + threadIdx.x;  // 851968
  int o = id >> 9, c = id & 511;
  int b = o / 52, n = o - b * 52;
  unsigned short h, l;
  split2(pnf[id], h, l);
  size_t base = (size_t)(n * 32 + b) * 1024;
  pnp[base + c] = h;
  pnp[base + 512 + c] = l;
}

// ---------------------------------------------------------------------------
// Object MLP (f32 exact): 512 -> 128 -> 256 -> 607, block per row r=n*32+b.
// ---------------------------------------------------------------------------
__global__ __launch_bounds__(256)
void objmlp_kernel(const float* __restrict__ obj,
                   const float* __restrict__ W0, const float* __restrict__ b0,
                   const float* __restrict__ W1, const float* __restrict__ b1,
                   const float* __restrict__ W2, const float* __restrict__ b2,
                   float* __restrict__ out)
{
  __shared__ float x[512];
  __shared__ float h1[128];
  __shared__ float h2[256];
  int tid = threadIdx.x;
  int r = blockIdx.x;          // r = n*32 + b
  int n = r >> 5, b = r & 31;
  int o = b * 52 + n;          // obj buffer indexed o = b*52 + n
  const float* xs = obj + (size_t)o * 512;
  x[tid] = xs[tid];
  x[tid + 256] = xs[tid + 256];
  __syncthreads();
  if (tid < 128) {
    float a = b0[tid];
    #pragma unroll 8
    for (int k = 0; k < 512; ++k) a += x[k] * W0[k * 128 + tid];
    h1[tid] = fmaxf(a, 0.f);
  }
  __syncthreads();
  {
    float a = b1[tid];
    #pragma unroll 8
    for (int k = 0; k < 128; ++k) a += h1[k] * W1[k * 256 + tid];
    h2[tid] = fmaxf(a, 0.f);
  }
  __syncthreads();
  for (int j = tid; j < 607; j += 256) {
    float a = b2[j];
    #pragma unroll 8
    for (int k = 0; k < 256; ++k) a += h2[k] * W2[k * 607 + j];
    out[(size_t)r * 607 + j] = a;
  }
}

// ---------------------------------------------------------------------------
extern "C" void kernel_launch(void* const* d_in, const int* in_sizes, int n_in,
                              void* d_out, int out_size, void* d_ws, size_t ws_size,
                              hipStream_t stream)
{
  const float* objects = (const float*)d_in[1];
  const float* de_W0 = (const float*)d_in[3];  const float* de_b0 = (const float*)d_in[4];
  const float* de_W1 = (const float*)d_in[5];  const float* de_b1 = (const float*)d_in[6];
  const float* de_W2 = (const float*)d_in[7];  const float* de_b2 = (const float*)d_in[8];
  const float* de_W3 = (const float*)d_in[9];  const float* de_b3 = (const float*)d_in[10];
  const float* de_W4 = (const float*)d_in[11]; const float* de_b4 = (const float*)d_in[12];
  const float* se_W0 = (const float*)d_in[13]; const float* se_b0 = (const float*)d_in[14];
  const float* se_W1 = (const float*)d_in[15]; const float* se_b1 = (const float*)d_in[16];
  const float* se_W2 = (const float*)d_in[17]; const float* se_b2 = (const float*)d_in[18];
  const float* om_W0 = (const float*)d_in[19]; const float* om_b0 = (const float*)d_in[20];
  const float* om_W1 = (const float*)d_in[21]; const float* om_b1 = (const float*)d_in[22];
  const float* om_W2 = (const float*)d_in[23]; const float* om_b2 = (const float*)d_in[24];
  const float* r1_W = (const float*)d_in[25];  const float* r1_b = (const float*)d_in[26];
  const float* r2_W = (const float*)d_in[27];  const float* r2_b = (const float*)d_in[28];
  const float* m1_W = (const float*)d_in[29];  const float* m1_b = (const float*)d_in[30];
  const float* m2_W = (const float*)d_in[31];  const float* m2_b = (const float*)d_in[32];
  (void)in_sizes; (void)n_in; (void)out_size;

  // ---- d_out is FLOAT32 (reference output dtype) ----
  float* outf = (float*)d_out;
  float* out_obj = outf;                          // [52,32,607]   = 1,010,048 f32
  float* out_rel = outf + 1010048;                // [52,52,32,512] = 44,302,336 f32
  float* out_multi = out_rel + 44302336;

  // ---- workspace: weight planes + t2 chunks ----
  char* ws = (char*)d_ws;
  size_t off = 0;
  auto alloc = [&](size_t bytes) -> void* {
    void* p = ws + off;
    off += (bytes + 255) & ~(size_t)255;
    return p;
  };
  unsigned short* wt_se2 = (unsigned short*)alloc((size_t)512 * 128 * 2);   // [512][2*64]
  unsigned short* wt_de2 = (unsigned short*)alloc((size_t)256 * 256 * 2);   // [256][2*128]
  unsigned short* wt_de3 = (unsigned short*)alloc((size_t)512 * 512 * 2);   // [512][2*256]
  unsigned short* wt_de4 = (unsigned short*)alloc((size_t)512 * 1024 * 2);  // [512][2*512]
  unsigned short* wt_r1  = (unsigned short*)alloc((size_t)512 * 2048 * 2);  // [512][2*1024]
  unsigned short* wt_r2  = (unsigned short*)alloc((size_t)512 * 1024 * 2);
  unsigned short* wt_m1  = (unsigned short*)alloc((size_t)512 * 1024 * 2);
  unsigned short* wt_m2  = (unsigned short*)alloc((size_t)512 * 1024 * 2);
  size_t avail = (ws_size > off + 256) ? (ws_size - off - 256) : 0;
  int Tc = (int)(avail / 262144);        // t2 tiles: 128 rows x [2*512] bf16
  if (Tc < 1) Tc = 1;
  if (Tc > 676) Tc = 676;
  unsigned short* t2 = (unsigned short*)alloc((size_t)Tc * 262144);

  // ---- arena inside d_out (rel+multi regions, 354,418,688 B) ----
  char* arena = (char*)out_rel;
  unsigned int* pnmax   = (unsigned int*)(arena);              // 851,968 f32-bits
  float*        obj_f32 = (float*)(arena + 3407872);           // 851,968 f32
  unsigned short* pn_p  = (unsigned short*)(arena + 6815744);  // [1664][1024] bf16
  char* cbuf = arena + 10223616;                               // chunk buffers
  const size_t PC = 65536;                                     // pts/chunk, 26 chunks
  unsigned short* s2_c = (unsigned short*)(cbuf);                    // PC*256 B
  unsigned short* h2_c = (unsigned short*)(cbuf + PC * 256);         // PC*512 B
  unsigned short* h3_c = (unsigned short*)(cbuf + PC * 768);         // PC*1024 B
  unsigned short* h4_c = (unsigned short*)(cbuf + PC * 1792);        // PC*2048 B
  unsigned short* t1   = (unsigned short*)out_multi;  // [86528][2*512] planes

  // zero atomic-max accumulators (pnmax + obj_f32, adjacent)
  zero_kernel<<<(2 * 851968) / 256, 256, 0, stream>>>(pnmax, 2 * 851968);

  // weight plane transposes
  auto tlaunch = [&](const float* W, unsigned short* Dst, int K, int N) {
    int n = K * N;
    transpose_split<<<(n + 255) / 256, 256, 0, stream>>>(W, Dst, K, N);
  };
  tlaunch(se_W2, wt_se2, 64, 512);
  tlaunch(de_W2, wt_de2, 128, 256);
  tlaunch(de_W3, wt_de3, 256, 512);
  tlaunch(de_W4, wt_de4, 512, 512);
  tlaunch(r1_W,  wt_r1, 1024, 512);
  tlaunch(r2_W,  wt_r2, 512, 512);
  tlaunch(m1_W,  wt_m1, 512, 512);
  tlaunch(m2_W,  wt_m2, 512, 512);

  // ---- point-cloud chains: 26 chunks x 64 objects (65,536 pts, 512 m-tiles) ----
  for (int c = 0; c < 26; ++c) {
    int base = c * (int)PC;
    points_kernel<<<PC / 256, 256, 0, stream>>>(
        objects + (size_t)base * 6,
        se_W0, se_b0, se_W1, se_b1, de_W0, de_b0, de_W1, de_b1, s2_c, h2_c);
    gemm_split<0, 2><<<4 * (PC / 128), 256, 0, stream>>>(
        s2_c, wt_se2, se_b2, nullptr, pnmax, PC, 64, 512, 4, 1, base);
    gemm_split<0, 1><<<2 * (PC / 128), 256, 0, stream>>>(
        h2_c, wt_de2, de_b2, h3_c, nullptr, PC, 128, 256, 2, 1, 0);
    gemm_split<0, 1><<<4 * (PC / 128), 256, 0, stream>>>(
        h3_c, wt_de3, de_b3, h4_c, nullptr, PC, 256, 512, 4, 1, 0);
    gemm_split<0, 2><<<4 * (PC / 128), 256, 0, stream>>>(
        h4_c, wt_de4, de_b4, nullptr, (unsigned int*)obj_f32, PC, 512, 512, 4, 1, base);
  }

  // pn planes from pnmax; object MLP (must finish before r2 clobbers rel region)
  pn_split_kernel<<<851968 / 256, 256, 0, stream>>>((const float*)pnmax, pn_p);
  objmlp_kernel<<<1664, 256, 0, stream>>>(obj_f32, om_W0, om_b0, om_W1, om_b1,
                                          om_W2, om_b2, out_obj);

  // ---- relation chain (M = 86528) ----
  // r1: gather pn -> t1 = relu planes (multi region)
  gemm_split<2, 1><<<4 * 676, 256, 0, stream>>>(
      pn_p, wt_r1, r1_b, t1, nullptr, 86528, 1024, 512, 4, 0, 0);
  // r2: t1 -> rel finals f32 (rel region; overwrites pnmax/obj/pn scratch - all dead)
  gemm_split<0, 0><<<4 * 676, 256, 0, stream>>>(
      t1, wt_r2, r2_b, out_rel, nullptr, 86528, 512, 512, 4, 0, 0);
  // m1/m2 chunked: m1 reads rel f32 (relu+split at staging) -> t2 planes (ws);
  // m2 reads t2 -> multi finals f32 (over dead t1 rows)
  for (int tb = 0; tb < 676; tb += Tc) {
    int tiles = (676 - tb < Tc) ? (676 - tb) : Tc;
    int rows = tiles * 128;
    size_t rb = (size_t)tb * 128 * 512;
    gemm_split<1, 1><<<4 * tiles, 256, 0, stream>>>(
        out_rel + rb, wt_m1, m1_b, t2, nullptr, rows, 512, 512, 4, 0, 0);
    gemm_split<0, 0><<<4 * tiles, 256, 0, stream>>>(
        t2, wt_m2, m2_b, out_multi + rb, nullptr, rows, 512, 512, 4, 0, 0);
  }
}

// Round 6
// 7900.587 us; speedup vs baseline: 1.1122x; 1.1122x over previous
//
#include <hip/hip_runtime.h>
#include <stdint.h>

typedef __attribute__((ext_vector_type(8))) __bf16 bf16x8;
typedef __attribute__((ext_vector_type(4))) float f32x4;
typedef __attribute__((ext_vector_type(8))) short short8;

__device__ __forceinline__ unsigned short f2bf(float f) {
  unsigned int u = __float_as_uint(f);
  u += 0x7FFFu + ((u >> 16) & 1u);
  return (unsigned short)(u >> 16);
}
__device__ __forceinline__ float bf2f(unsigned short h) {
  return __uint_as_float((unsigned int)h << 16);
}
__device__ __forceinline__ void split2(float v, unsigned short& h, unsigned short& l) {
  h = f2bf(v);
  l = f2bf(v - bf2f(h));
}

// ---------------------------------------------------------------------------
// Split-bf16 MFMA GEMM v2: C = act(A @ Wt^T + bias), f32-equivalent precision.
// C ~= Ah*Bh + Ah*Bl + Al*Bh (3 MFMAs), f32 accum.
// BM=BN=128, BK=64, 256 threads (4 waves 2x2), 16x16x32 bf16 MFMA.
// Staging via global_load_lds(16B) into linear [128][64]-short tiles with
// XOR slot-swizzle applied on the SOURCE address (s_phys = s_log ^ (row&7));
// ds_read applies the same XOR -> conflict-free (8 accesses/bank-quad = min).
// ASRC: 0 = A planes rowpair [M][2K] (gload_lds);
//       1 = A f32 [M][K], relu+split reg-staged (swizzled ds_write);
//       2 = gather r=(i*52+j)*32+b -> concat(pn[i*32+b],pn[j*32+b]) planes
//           [1664][1024], K=1024 (gload_lds, per-lane source).
// COUT: 0 = f32 raw (+bias); 1 = relu planes rowpair [M][2*ldc];
//       2 = maxout relu(colmax+bias) -> atomicMax f32-bits Omax[obj*512+n].
// ---------------------------------------------------------------------------
template<int ASRC, int COUT>
__global__ __launch_bounds__(256)
void gemm2(const void* __restrict__ Asrc,
           const unsigned short* __restrict__ Wt,
           const float* __restrict__ bias,
           void* __restrict__ Cdst,
           unsigned int* __restrict__ Omax,
           int M, int K, int ldc, int ntn, int swz8, int m_base)
{
  __shared__ __align__(16) short SM[4][128][64];  // AH, AL, BH, BL = 64 KiB

  int bid = blockIdx.x;
  int mt, nt;
  if (swz8) {                      // XCD-aware swizzle (requires Mtiles%8==0)
    int xcd = bid & 7;
    int slot = bid >> 3;
    nt = slot % ntn;
    mt = (slot / ntn) * 8 + xcd;
  } else {
    mt = bid / ntn;
    nt = bid - mt * ntn;
  }
  const int m0 = mt * 128, n0 = nt * 128;
  const int tid = threadIdx.x;
  const int wave = tid >> 6, lane = tid & 63;
  const int wm = wave >> 1, wn = wave & 1;
  const int l15 = lane & 15, l4 = lane >> 4;

  // staging geometry: physical 16B slot p = c*256+tid -> row p>>3, slot p&7
  const int rr = tid >> 3;          // row within 32-row group
  const int sp = tid & 7;           // physical slot
  const int sl = sp ^ (rr & 7);     // logical slot ((c*32+rr)&7 == rr&7)
  const int slE = sl * 8;           // logical element offset (shorts / f32s)

  const unsigned short* ah_p[4];
  const unsigned short* aj_p[4];
  const float* af_p[4];
  const unsigned short* b_p[4];
  #pragma unroll
  for (int c = 0; c < 4; ++c) {
    int rt = c * 32 + rr;
    int r = m0 + rt;
    if (ASRC == 2) {
      int b = r & 31;
      int pair = r >> 5;
      int i = pair / 52;
      int j = pair - i * 52;
      ah_p[c] = (const unsigned short*)Asrc + (size_t)(i * 32 + b) * 1024 + slE;
      aj_p[c] = (const unsigned short*)Asrc + (size_t)(j * 32 + b) * 1024 + slE;
    } else if (ASRC == 1) {
      af_p[c] = (const float*)Asrc + (size_t)r * K + slE;
    } else {
      ah_p[c] = (const unsigned short*)Asrc + (size_t)r * 2 * K + slE;
    }
    b_p[c] = Wt + (size_t)(n0 + rt) * 2 * K + slE;
  }

  f32x4 acc[4][4];
  #pragma unroll
  for (int a = 0; a < 4; ++a)
    #pragma unroll
    for (int b = 0; b < 4; ++b)
      acc[a][b] = (f32x4){0.f, 0.f, 0.f, 0.f};

  char* const smbase = (char*)&SM[0][0][0];

  for (int k0 = 0; k0 < K; k0 += 64) {
    #pragma unroll
    for (int c = 0; c < 4; ++c) {
      char* lb = smbase + c * 4096 + (tid & 192) * 16;  // + wave*1024
      if (ASRC == 1) {
        f32x4 v0 = *reinterpret_cast<const f32x4*>(af_p[c] + k0);
        f32x4 v1 = *reinterpret_cast<const f32x4*>(af_p[c] + k0 + 4);
        short8 hi, lo;
        #pragma unroll
        for (int e = 0; e < 4; ++e) {
          unsigned short h, l;
          split2(fmaxf(v0[e], 0.f), h, l);
          hi[e] = (short)h; lo[e] = (short)l;
          split2(fmaxf(v1[e], 0.f), h, l);
          hi[4 + e] = (short)h; lo[4 + e] = (short)l;
        }
        int rt = c * 32 + rr;
        *reinterpret_cast<short8*>(&SM[0][rt][sp * 8]) = hi;
        *reinterpret_cast<short8*>(&SM[1][rt][sp * 8]) = lo;
      } else if (ASRC == 2) {
        const unsigned short* s = (k0 < 512) ? (ah_p[c] + k0) : (aj_p[c] + (k0 - 512));
        __builtin_amdgcn_global_load_lds(s, (void*)lb, 16, 0, 0);
        __builtin_amdgcn_global_load_lds(s + 512, (void*)(lb + 16384), 16, 0, 0);
      } else {
        __builtin_amdgcn_global_load_lds(ah_p[c] + k0, (void*)lb, 16, 0, 0);
        __builtin_amdgcn_global_load_lds(ah_p[c] + K + k0, (void*)(lb + 16384), 16, 0, 0);
      }
      __builtin_amdgcn_global_load_lds(b_p[c] + k0, (void*)(lb + 32768), 16, 0, 0);
      __builtin_amdgcn_global_load_lds(b_p[c] + K + k0, (void*)(lb + 49152), 16, 0, 0);
    }
    __syncthreads();
    #pragma unroll
    for (int kf = 0; kf < 2; ++kf) {
      bf16x8 ah[4], al[4], bh[4], bl[4];
      #pragma unroll
      for (int mi = 0; mi < 4; ++mi) {
        int R = wm * 64 + mi * 16 + l15;
        int sph = (kf * 4 + l4) ^ (R & 7);
        ah[mi] = *reinterpret_cast<const bf16x8*>(&SM[0][R][sph * 8]);
        al[mi] = *reinterpret_cast<const bf16x8*>(&SM[1][R][sph * 8]);
      }
      #pragma unroll
      for (int ni = 0; ni < 4; ++ni) {
        int R = wn * 64 + ni * 16 + l15;
        int sph = (kf * 4 + l4) ^ (R & 7);
        bh[ni] = *reinterpret_cast<const bf16x8*>(&SM[2][R][sph * 8]);
        bl[ni] = *reinterpret_cast<const bf16x8*>(&SM[3][R][sph * 8]);
      }
      #pragma unroll
      for (int mi = 0; mi < 4; ++mi)
        #pragma unroll
        for (int ni = 0; ni < 4; ++ni) {
          acc[mi][ni] = __builtin_amdgcn_mfma_f32_16x16x32_bf16(ah[mi], bh[ni], acc[mi][ni], 0, 0, 0);
          acc[mi][ni] = __builtin_amdgcn_mfma_f32_16x16x32_bf16(ah[mi], bl[ni], acc[mi][ni], 0, 0, 0);
          acc[mi][ni] = __builtin_amdgcn_mfma_f32_16x16x32_bf16(al[mi], bh[ni], acc[mi][ni], 0, 0, 0);
        }
    }
    __syncthreads();
  }

  if (COUT == 2) {
    int obj = (m_base + m0) >> 10;
    #pragma unroll
    for (int ni = 0; ni < 4; ++ni) {
      int n = n0 + wn * 64 + ni * 16 + l15;
      float v = acc[0][ni][0];
      #pragma unroll
      for (int mi = 0; mi < 4; ++mi)
        #pragma unroll
        for (int i = 0; i < 4; ++i)
          v = fmaxf(v, acc[mi][ni][i]);
      v = fmaxf(v + bias[n], 0.0f);
      v = fmaxf(v, __shfl_xor(v, 16));
      v = fmaxf(v, __shfl_xor(v, 32));
      if (l4 == 0)
        atomicMax(&Omax[(size_t)obj * 512 + n], __float_as_uint(v));
    }
  } else if (COUT == 1) {
    unsigned short* Cp = (unsigned short*)Cdst;
    #pragma unroll
    for (int mi = 0; mi < 4; ++mi) {
      #pragma unroll
      for (int i = 0; i < 4; ++i) {
        int m = m0 + wm * 64 + mi * 16 + l4 * 4 + i;
        size_t base = (size_t)m * 2 * ldc + n0 + wn * 64;
        #pragma unroll
        for (int ni = 0; ni < 4; ++ni) {
          int nl = ni * 16 + l15;
          float v = fmaxf(acc[mi][ni][i] + bias[n0 + wn * 64 + nl], 0.f);
          unsigned short h, l;
          split2(v, h, l);
          Cp[base + nl] = h;
          Cp[base + ldc + nl] = l;
        }
      }
    }
  } else {
    float* Cf = (float*)Cdst;
    #pragma unroll
    for (int mi = 0; mi < 4; ++mi) {
      #pragma unroll
      for (int i = 0; i < 4; ++i) {
        int m = m0 + wm * 64 + mi * 16 + l4 * 4 + i;
        float* crow = Cf + (size_t)m * ldc + n0 + wn * 64;
        #pragma unroll
        for (int ni = 0; ni < 4; ++ni) {
          int nl = ni * 16 + l15;
          crow[nl] = acc[mi][ni][i] + bias[n0 + wn * 64 + nl];
        }
      }
    }
  }
}

// ---------------------------------------------------------------------------
// Per-point MLPs (f32 exact), outputs stored as relu'd hi/lo planes:
//   sparse: (x,y,z) -> 32 -> 64   -> s2 rowpair [pt][128]
//   dense:  6 -> 64 -> 128        -> h2 rowpair [pt][256]
// ---------------------------------------------------------------------------
__global__ __launch_bounds__(256)
void points_kernel(const float* __restrict__ obj6,
                   const float* __restrict__ sW0, const float* __restrict__ sb0,
                   const float* __restrict__ sW1, const float* __restrict__ sb1,
                   const float* __restrict__ dW0, const float* __restrict__ db0,
                   const float* __restrict__ dW1, const float* __restrict__ db1,
                   unsigned short* __restrict__ s2,
                   unsigned short* __restrict__ h2)
{
  __shared__ float sw0[96], sbb0[32], sw1[2048], sbb1[64];
  __shared__ float dw0[384], dbb0[64], dw1[8192], dbb1[128];
  int tid = threadIdx.x;
  for (int i = tid; i < 96; i += 256) sw0[i] = sW0[i];
  if (tid < 32) sbb0[tid] = sb0[tid];
  for (int i = tid; i < 2048; i += 256) sw1[i] = sW1[i];
  if (tid < 64) sbb1[tid] = sb1[tid];
  for (int i = tid; i < 384; i += 256) dw0[i] = dW0[i];
  if (tid < 64) dbb0[tid] = db0[tid];
  for (int i = tid; i < 8192; i += 256) dw1[i] = dW1[i];
  if (tid < 128) dbb1[tid] = db1[tid];
  __syncthreads();

  int pt = blockIdx.x * 256 + tid;
  const float* in = obj6 + (size_t)pt * 6;
  float c0 = in[0], c1 = in[1], c2 = in[2], c3 = in[3], c4 = in[4], c5 = in[5];

  {  // sparse (xyz only)
    float h1[32];
    #pragma unroll
    for (int j = 0; j < 32; ++j)
      h1[j] = fmaxf(c0 * sw0[j] + c1 * sw0[32 + j] + c2 * sw0[64 + j] + sbb0[j], 0.f);
    unsigned short* orow = s2 + (size_t)pt * 128;
    #pragma unroll
    for (int j8 = 0; j8 < 8; ++j8) {
      float a[8];
      #pragma unroll
      for (int e = 0; e < 8; ++e) a[e] = sbb1[j8 * 8 + e];
      #pragma unroll
      for (int i = 0; i < 32; ++i) {
        float hv = h1[i];
        #pragma unroll
        for (int e = 0; e < 8; ++e) a[e] += hv * sw1[i * 64 + j8 * 8 + e];
      }
      short8 oh, ol;
      #pragma unroll
      for (int e = 0; e < 8; ++e) {
        unsigned short h, l;
        split2(fmaxf(a[e], 0.f), h, l);
        oh[e] = (short)h; ol[e] = (short)l;
      }
      *reinterpret_cast<short8*>(orow + j8 * 8) = oh;
      *reinterpret_cast<short8*>(orow + 64 + j8 * 8) = ol;
    }
  }

  {  // dense (all 6 dims)
    float h1[64];
    #pragma unroll
    for (int j = 0; j < 64; ++j) {
      float a = dbb0[j] + c0 * dw0[j] + c1 * dw0[64 + j] + c2 * dw0[128 + j]
              + c3 * dw0[192 + j] + c4 * dw0[256 + j] + c5 * dw0[320 + j];
      h1[j] = fmaxf(a, 0.f);
    }
    unsigned short* orow = h2 + (size_t)pt * 256;
    #pragma unroll
    for (int ch = 0; ch < 4; ++ch) {
      float a[32];
      #pragma unroll
      for (int e = 0; e < 32; ++e) a[e] = dbb1[ch * 32 + e];
      #pragma unroll 8
      for (int i = 0; i < 64; ++i) {
        float hv = h1[i];
        #pragma unroll
        for (int e = 0; e < 32; ++e) a[e] += hv * dw1[i * 128 + ch * 32 + e];
      }
      #pragma unroll
      for (int e8 = 0; e8 < 4; ++e8) {
        short8 oh, ol;
        #pragma unroll
        for (int e = 0; e < 8; ++e) {
          unsigned short h, l;
          split2(fmaxf(a[e8 * 8 + e], 0.f), h, l);
          oh[e] = (short)h; ol[e] = (short)l;
        }
        *reinterpret_cast<short8*>(orow + ch * 32 + e8 * 8) = oh;
        *reinterpret_cast<short8*>(orow + 128 + ch * 32 + e8 * 8) = ol;
      }
    }
  }
}

// ---------------------------------------------------------------------------
// [K,N] f32 -> planes rowpair [N][2K] bf16 (hi row || lo row)
__global__ void transpose_split(const float* __restrict__ W, unsigned short* __restrict__ Wt,
                                int K, int N)
{
  int id = blockIdx.x * 256 + threadIdx.x;
  if (id >= K * N) return;
  int k = id / N, n = id - k * N;
  unsigned short h, l;
  split2(W[id], h, l);
  Wt[(size_t)n * 2 * K + k] = h;
  Wt[(size_t)n * 2 * K + K + k] = l;
}

__global__ void zero_kernel(unsigned int* __restrict__ p, int n)
{
  int id = blockIdx.x * 256 + threadIdx.x;
  if (id < n) p[id] = 0u;
}

// pnmax f32 (indexed o=b*52+n) -> pn planes rowpair [(n*32+b)][1024]
__global__ void pn_split_kernel(const float* __restrict__ pnf, unsigned short* __restrict__ pnp)
{
  int id = blockIdx.x * 256 + threadIdx.x;  // 851968
  int o = id >> 9, c = id & 511;
  int b = o / 52, n = o - b * 52;
  unsigned short h, l;
  split2(pnf[id], h, l);
  size_t base = (size_t)(n * 32 + b) * 1024;
  pnp[base + c] = h;
  pnp[base + 512 + c] = l;
}

// ---------------------------------------------------------------------------
// Object MLP (f32 exact): 512 -> 128 -> 256 -> 607, block per row r=n*32+b.
// ---------------------------------------------------------------------------
__global__ __launch_bounds__(256)
void objmlp_kernel(const float* __restrict__ obj,
                   const float* __restrict__ W0, const float* __restrict__ b0,
                   const float* __restrict__ W1, const float* __restrict__ b1,
                   const float* __restrict__ W2, const float* __restrict__ b2,
                   float* __restrict__ out)
{
  __shared__ float x[512];
  __shared__ float h1[128];
  __shared__ float h2[256];
  int tid = threadIdx.x;
  int r = blockIdx.x;          // r = n*32 + b
  int n = r >> 5, b = r & 31;
  int o = b * 52 + n;          // obj buffer indexed o = b*52 + n
  const float* xs = obj + (size_t)o * 512;
  x[tid] = xs[tid];
  x[tid + 256] = xs[tid + 256];
  __syncthreads();
  if (tid < 128) {
    float a = b0[tid];
    #pragma unroll 8
    for (int k = 0; k < 512; ++k) a += x[k] * W0[k * 128 + tid];
    h1[tid] = fmaxf(a, 0.f);
  }
  __syncthreads();
  {
    float a = b1[tid];
    #pragma unroll 8
    for (int k = 0; k < 128; ++k) a += h1[k] * W1[k * 256 + tid];
    h2[tid] = fmaxf(a, 0.f);
  }
  __syncthreads();
  for (int j = tid; j < 607; j += 256) {
    float a = b2[j];
    #pragma unroll 8
    for (int k = 0; k < 256; ++k) a += h2[k] * W2[k * 607 + j];
    out[(size_t)r * 607 + j] = a;
  }
}

// ---------------------------------------------------------------------------
extern "C" void kernel_launch(void* const* d_in, const int* in_sizes, int n_in,
                              void* d_out, int out_size, void* d_ws, size_t ws_size,
                              hipStream_t stream)
{
  const float* objects = (const float*)d_in[1];
  const float* de_W0 = (const float*)d_in[3];  const float* de_b0 = (const float*)d_in[4];
  const float* de_W1 = (const float*)d_in[5];  const float* de_b1 = (const float*)d_in[6];
  const float* de_W2 = (const float*)d_in[7];  const float* de_b2 = (const float*)d_in[8];
  const float* de_W3 = (const float*)d_in[9];  const float* de_b3 = (const float*)d_in[10];
  const float* de_W4 = (const float*)d_in[11]; const float* de_b4 = (const float*)d_in[12];
  const float* se_W0 = (const float*)d_in[13]; const float* se_b0 = (const float*)d_in[14];
  const float* se_W1 = (const float*)d_in[15]; const float* se_b1 = (const float*)d_in[16];
  const float* se_W2 = (const float*)d_in[17]; const float* se_b2 = (const float*)d_in[18];
  const float* om_W0 = (const float*)d_in[19]; const float* om_b0 = (const float*)d_in[20];
  const float* om_W1 = (const float*)d_in[21]; const float* om_b1 = (const float*)d_in[22];
  const float* om_W2 = (const float*)d_in[23]; const float* om_b2 = (const float*)d_in[24];
  const float* r1_W = (const float*)d_in[25];  const float* r1_b = (const float*)d_in[26];
  const float* r2_W = (const float*)d_in[27];  const float* r2_b = (const float*)d_in[28];
  const float* m1_W = (const float*)d_in[29];  const float* m1_b = (const float*)d_in[30];
  const float* m2_W = (const float*)d_in[31];  const float* m2_b = (const float*)d_in[32];
  (void)in_sizes; (void)n_in; (void)out_size;

  // ---- d_out is FLOAT32 (reference output dtype) ----
  float* outf = (float*)d_out;
  float* out_obj = outf;                          // [52,32,607]
  float* out_rel = outf + 1010048;                // [52,52,32,512]
  float* out_multi = out_rel + 44302336;

  // ---- workspace: weight planes + t2 chunks ----
  char* ws = (char*)d_ws;
  size_t off = 0;
  auto alloc = [&](size_t bytes) -> void* {
    void* p = ws + off;
    off += (bytes + 255) & ~(size_t)255;
    return p;
  };
  unsigned short* wt_se2 = (unsigned short*)alloc((size_t)512 * 128 * 2);
  unsigned short* wt_de2 = (unsigned short*)alloc((size_t)256 * 256 * 2);
  unsigned short* wt_de3 = (unsigned short*)alloc((size_t)512 * 512 * 2);
  unsigned short* wt_de4 = (unsigned short*)alloc((size_t)512 * 1024 * 2);
  unsigned short* wt_r1  = (unsigned short*)alloc((size_t)512 * 2048 * 2);
  unsigned short* wt_r2  = (unsigned short*)alloc((size_t)512 * 1024 * 2);
  unsigned short* wt_m1  = (unsigned short*)alloc((size_t)512 * 1024 * 2);
  unsigned short* wt_m2  = (unsigned short*)alloc((size_t)512 * 1024 * 2);
  size_t avail = (ws_size > off + 256) ? (ws_size - off - 256) : 0;
  int Tc = (int)(avail / 262144);        // t2 tiles: 128 rows x [2*512] bf16
  if (Tc < 1) Tc = 1;
  if (Tc > 676) Tc = 676;
  unsigned short* t2 = (unsigned short*)alloc((size_t)Tc * 262144);

  // ---- arena inside d_out (rel+multi regions, 354,418,688 B) ----
  char* arena = (char*)out_rel;
  unsigned int* pnmax   = (unsigned int*)(arena);              // 851,968 f32-bits
  float*        obj_f32 = (float*)(arena + 3407872);           // 851,968 f32
  unsigned short* pn_p  = (unsigned short*)(arena + 6815744);  // [1664][1024] bf16
  char* cbuf = arena + 10223616;                               // chunk buffers
  const size_t PC = 65536;                                     // pts/chunk, 26 chunks
  unsigned short* s2_c = (unsigned short*)(cbuf);                    // PC*256 B
  unsigned short* h2_c = (unsigned short*)(cbuf + PC * 256);         // PC*512 B
  unsigned short* h3_c = (unsigned short*)(cbuf + PC * 768);         // PC*1024 B
  unsigned short* h4_c = (unsigned short*)(cbuf + PC * 1792);        // PC*2048 B
  unsigned short* t1   = (unsigned short*)out_multi;  // [86528][2*512] planes

  // zero atomic-max accumulators (pnmax + obj_f32, adjacent)
  zero_kernel<<<(2 * 851968) / 256, 256, 0, stream>>>(pnmax, 2 * 851968);

  // weight plane transposes
  auto tlaunch = [&](const float* W, unsigned short* Dst, int K, int N) {
    int n = K * N;
    transpose_split<<<(n + 255) / 256, 256, 0, stream>>>(W, Dst, K, N);
  };
  tlaunch(se_W2, wt_se2, 64, 512);
  tlaunch(de_W2, wt_de2, 128, 256);
  tlaunch(de_W3, wt_de3, 256, 512);
  tlaunch(de_W4, wt_de4, 512, 512);
  tlaunch(r1_W,  wt_r1, 1024, 512);
  tlaunch(r2_W,  wt_r2, 512, 512);
  tlaunch(m1_W,  wt_m1, 512, 512);
  tlaunch(m2_W,  wt_m2, 512, 512);

  // ---- point-cloud chains: 26 chunks x 64 objects (65,536 pts, 512 m-tiles) ----
  for (int c = 0; c < 26; ++c) {
    int base = c * (int)PC;
    points_kernel<<<PC / 256, 256, 0, stream>>>(
        objects + (size_t)base * 6,
        se_W0, se_b0, se_W1, se_b1, de_W0, de_b0, de_W1, de_b1, s2_c, h2_c);
    gemm2<0, 2><<<4 * (PC / 128), 256, 0, stream>>>(
        s2_c, wt_se2, se_b2, nullptr, pnmax, PC, 64, 512, 4, 1, base);
    gemm2<0, 1><<<2 * (PC / 128), 256, 0, stream>>>(
        h2_c, wt_de2, de_b2, h3_c, nullptr, PC, 128, 256, 2, 1, 0);
    gemm2<0, 1><<<4 * (PC / 128), 256, 0, stream>>>(
        h3_c, wt_de3, de_b3, h4_c, nullptr, PC, 256, 512, 4, 1, 0);
    gemm2<0, 2><<<4 * (PC / 128), 256, 0, stream>>>(
        h4_c, wt_de4, de_b4, nullptr, (unsigned int*)obj_f32, PC, 512, 512, 4, 1, base);
  }

  // pn planes from pnmax; object MLP (before r2 clobbers rel region)
  pn_split_kernel<<<851968 / 256, 256, 0, stream>>>((const float*)pnmax, pn_p);
  objmlp_kernel<<<1664, 256, 0, stream>>>(obj_f32, om_W0, om_b0, om_W1, om_b1,
                                          om_W2, om_b2, out_obj);

  // ---- relation chain (M = 86528) ----
  gemm2<2, 1><<<4 * 676, 256, 0, stream>>>(
      pn_p, wt_r1, r1_b, t1, nullptr, 86528, 1024, 512, 4, 0, 0);
  gemm2<0, 0><<<4 * 676, 256, 0, stream>>>(
      t1, wt_r2, r2_b, out_rel, nullptr, 86528, 512, 512, 4, 0, 0);
  for (int tb = 0; tb < 676; tb += Tc) {
    int tiles = (676 - tb < Tc) ? (676 - tb) : Tc;
    int rows = tiles * 128;
    size_t rb = (size_t)tb * 128 * 512;
    gemm2<1, 1><<<4 * tiles, 256, 0, stream>>>(
        out_rel + rb, wt_m1, m1_b, t2, nullptr, rows, 512, 512, 4, 0, 0);
    gemm2<0, 0><<<4 * tiles, 256, 0, stream>>>(
        t2, wt_m2, m2_b, out_multi + rb, nullptr, rows, 512, 512, 4, 0, 0);
  }
}

// Round 7
// 6123.280 us; speedup vs baseline: 1.4351x; 1.2903x over previous
//
#include <hip/hip_runtime.h>
#include <stdint.h>

typedef __attribute__((ext_vector_type(8))) __bf16 bf16x8;
typedef __attribute__((ext_vector_type(4))) float f32x4;
typedef __attribute__((ext_vector_type(8))) short short8;

__device__ __forceinline__ unsigned short f2bf(float f) {
  unsigned int u = __float_as_uint(f);
  u += 0x7FFFu + ((u >> 16) & 1u);
  return (unsigned short)(u >> 16);
}
__device__ __forceinline__ float bf2f(unsigned short h) {
  return __uint_as_float((unsigned int)h << 16);
}
__device__ __forceinline__ void split2(float v, unsigned short& h, unsigned short& l) {
  h = f2bf(v);
  l = f2bf(v - bf2f(h));
}

// ---------------------------------------------------------------------------
// Split-2 MFMA GEMM: C = act(A @ W + bias); A bf16 single plane, W = Wh+Wl
// planes (f32-precise weights). C ~= A*Wh + A*Wl, f32 accum, 2 MFMAs/pair.
// BM=BN=128, BK=64, 256 threads (4 waves 2x2), 16x16x32 bf16 MFMA.
// LDS: SM[3][128][64] shorts (A, BH, BL) = 48 KiB, linear dest via
// global_load_lds(16B); XOR slot-swizzle pre-applied on SOURCE address
// (phys slot sp holds logical slot sp^(row&7)); ds_read applies same XOR.
// ASRC: 0 = A bf16 plane [M][K]; 1 = A f32 [M][K], relu+round reg-staged.
// COUT: 0 = f32 raw (+bias) via LDS bounce, coalesced f32x4 stores;
//       1 = relu bf16 plane via LDS bounce, coalesced short8 stores;
//       2 = maxout relu(colmax+bias) -> atomicMax f32-bits Omax[obj*512+n].
// ---------------------------------------------------------------------------
template<int ASRC, int COUT>
__global__ __launch_bounds__(256)
void gemm3(const void* __restrict__ Asrc,
           const unsigned short* __restrict__ Wt,   // [N][2K] hi||lo
           const float* __restrict__ bias,
           void* __restrict__ Cdst,
           unsigned int* __restrict__ Omax,
           int M, int K, int ldc, int ntn, int swz8, int m_base)
{
  __shared__ __align__(16) short SM[3][128][64];   // 48 KiB

  int bid = blockIdx.x;
  int mt, nt;
  if (swz8) {                      // XCD-aware swizzle (requires Mtiles%8==0)
    int xcd = bid & 7;
    int slot = bid >> 3;
    nt = slot % ntn;
    mt = (slot / ntn) * 8 + xcd;
  } else {
    mt = bid / ntn;
    nt = bid - mt * ntn;
  }
  const int m0 = mt * 128, n0 = nt * 128;
  const int tid = threadIdx.x;
  const int wave = tid >> 6, lane = tid & 63;
  const int wm = wave >> 1, wn = wave & 1;
  const int l15 = lane & 15, l4 = lane >> 4;

  // staging geometry: physical 16B slot; logical slot = sp ^ (row&7)
  const int rr = tid >> 3;          // row within 32-row group
  const int sp = tid & 7;           // physical slot
  const int sl = sp ^ (rr & 7);     // logical slot
  const int slE = sl * 8;           // element offset (shorts or f32s)

  const unsigned short* a_p[4];
  const float* af_p[4];
  const unsigned short* b_p[4];
  #pragma unroll
  for (int c = 0; c < 4; ++c) {
    int rt = c * 32 + rr;
    int r = m0 + rt;
    if (ASRC == 1) af_p[c] = (const float*)Asrc + (size_t)r * K + slE;
    else           a_p[c]  = (const unsigned short*)Asrc + (size_t)r * K + slE;
    b_p[c] = Wt + (size_t)(n0 + rt) * 2 * K + slE;
  }

  f32x4 acc[4][4];
  #pragma unroll
  for (int a = 0; a < 4; ++a)
    #pragma unroll
    for (int b = 0; b < 4; ++b)
      acc[a][b] = (f32x4){0.f, 0.f, 0.f, 0.f};

  char* const smb = (char*)&SM[0][0][0];

  for (int k0 = 0; k0 < K; k0 += 64) {
    #pragma unroll
    for (int c = 0; c < 4; ++c) {
      char* lb = smb + c * 4096 + (tid & 192) * 16;   // + wave*1024
      if (ASRC == 1) {
        f32x4 v0 = *reinterpret_cast<const f32x4*>(af_p[c] + k0);
        f32x4 v1 = *reinterpret_cast<const f32x4*>(af_p[c] + k0 + 4);
        short8 hi;
        #pragma unroll
        for (int e = 0; e < 4; ++e) {
          hi[e]     = (short)f2bf(fmaxf(v0[e], 0.f));
          hi[4 + e] = (short)f2bf(fmaxf(v1[e], 0.f));
        }
        int rt = c * 32 + rr;
        *reinterpret_cast<short8*>(&SM[0][rt][sp * 8]) = hi;
      } else {
        __builtin_amdgcn_global_load_lds(a_p[c] + k0, (void*)lb, 16, 0, 0);
      }
      __builtin_amdgcn_global_load_lds(b_p[c] + k0, (void*)(lb + 16384), 16, 0, 0);
      __builtin_amdgcn_global_load_lds(b_p[c] + K + k0, (void*)(lb + 32768), 16, 0, 0);
    }
    __syncthreads();
    #pragma unroll
    for (int kf = 0; kf < 2; ++kf) {
      bf16x8 av[4], bh[4], bl[4];
      #pragma unroll
      for (int mi = 0; mi < 4; ++mi) {
        int R = wm * 64 + mi * 16 + l15;
        int sph = (kf * 4 + l4) ^ (R & 7);
        av[mi] = *reinterpret_cast<const bf16x8*>(&SM[0][R][sph * 8]);
      }
      #pragma unroll
      for (int ni = 0; ni < 4; ++ni) {
        int R = wn * 64 + ni * 16 + l15;
        int sph = (kf * 4 + l4) ^ (R & 7);
        bh[ni] = *reinterpret_cast<const bf16x8*>(&SM[1][R][sph * 8]);
        bl[ni] = *reinterpret_cast<const bf16x8*>(&SM[2][R][sph * 8]);
      }
      #pragma unroll
      for (int mi = 0; mi < 4; ++mi)
        #pragma unroll
        for (int ni = 0; ni < 4; ++ni) {
          acc[mi][ni] = __builtin_amdgcn_mfma_f32_16x16x32_bf16(av[mi], bh[ni], acc[mi][ni], 0, 0, 0);
          acc[mi][ni] = __builtin_amdgcn_mfma_f32_16x16x32_bf16(av[mi], bl[ni], acc[mi][ni], 0, 0, 0);
        }
    }
    __syncthreads();
  }

  if (COUT == 2) {
    int obj = (m_base + m0) >> 10;
    #pragma unroll
    for (int ni = 0; ni < 4; ++ni) {
      int n = n0 + wn * 64 + ni * 16 + l15;
      float v = acc[0][ni][0];
      #pragma unroll
      for (int mi = 0; mi < 4; ++mi)
        #pragma unroll
        for (int i = 0; i < 4; ++i)
          v = fmaxf(v, acc[mi][ni][i]);
      v = fmaxf(v + bias[n], 0.0f);
      v = fmaxf(v, __shfl_xor(v, 16));
      v = fmaxf(v, __shfl_xor(v, 32));
      if (l4 == 0)
        atomicMax(&Omax[(size_t)obj * 512 + n], __float_as_uint(v));
    }
  } else if (COUT == 1) {
    // bounce: bf16 [128][128] w/ 16B-slot XOR swizzle -> coalesced short8
    unsigned short* Bp = (unsigned short*)smb;
    #pragma unroll
    for (int mi = 0; mi < 4; ++mi)
      #pragma unroll
      for (int i = 0; i < 4; ++i) {
        int row = wm * 64 + mi * 16 + l4 * 4 + i;
        #pragma unroll
        for (int ni = 0; ni < 4; ++ni) {
          int col = wn * 64 + ni * 16 + l15;
          int off = row * 128 + (((col >> 3) ^ (row & 7)) << 3) + (col & 7);
          Bp[off] = f2bf(fmaxf(acc[mi][ni][i] + bias[n0 + col], 0.f));
        }
      }
    __syncthreads();
    unsigned short* Cp = (unsigned short*)Cdst;
    #pragma unroll
    for (int s = 0; s < 8; ++s) {
      int p = tid * 8 + s;
      int row = p >> 4, ls = p & 15;
      short8 v = *reinterpret_cast<const short8*>(&Bp[row * 128 + ((ls ^ (row & 7)) << 3)]);
      *reinterpret_cast<short8*>(Cp + (size_t)(m0 + row) * ldc + n0 + ls * 8) = v;
    }
  } else {
    // bounce: two 64-row halves of f32 [64][128] -> coalesced f32x4
    float* Bf = (float*)smb;
    float* Cf = (float*)Cdst;
    #pragma unroll
    for (int h = 0; h < 2; ++h) {
      if (wm == h) {
        #pragma unroll
        for (int mi = 0; mi < 4; ++mi)
          #pragma unroll
          for (int i = 0; i < 4; ++i) {
            int lr = mi * 16 + l4 * 4 + i;
            #pragma unroll
            for (int ni = 0; ni < 4; ++ni) {
              int col = wn * 64 + ni * 16 + l15;
              int off = lr * 128 + (((col >> 2) ^ (lr & 7)) << 2) + (col & 3);
              Bf[off] = acc[mi][ni][i] + bias[n0 + col];
            }
          }
      }
      __syncthreads();
      #pragma unroll
      for (int s = 0; s < 8; ++s) {
        int p = tid * 8 + s;
        int row = p >> 5, ls = p & 31;
        f32x4 v = *reinterpret_cast<const f32x4*>(&Bf[row * 128 + ((ls ^ (row & 7)) << 2)]);
        *reinterpret_cast<f32x4*>(Cf + (size_t)(m0 + h * 64 + row) * ldc + n0 + ls * 4) = v;
      }
      __syncthreads();
    }
  }
}

// ---------------------------------------------------------------------------
// Per-point MLPs (f32 exact), outputs relu'd single-plane bf16:
//   sparse: (x,y,z) -> 32 -> 64   -> s2 [pt][64]
//   dense:  6 -> 64 -> 128        -> h2 [pt][128]
// ---------------------------------------------------------------------------
__global__ __launch_bounds__(256)
void points_kernel(const float* __restrict__ obj6,
                   const float* __restrict__ sW0, const float* __restrict__ sb0,
                   const float* __restrict__ sW1, const float* __restrict__ sb1,
                   const float* __restrict__ dW0, const float* __restrict__ db0,
                   const float* __restrict__ dW1, const float* __restrict__ db1,
                   unsigned short* __restrict__ s2,
                   unsigned short* __restrict__ h2)
{
  __shared__ float sw0[96], sbb0[32], sw1[2048], sbb1[64];
  __shared__ float dw0[384], dbb0[64], dw1[8192], dbb1[128];
  int tid = threadIdx.x;
  for (int i = tid; i < 96; i += 256) sw0[i] = sW0[i];
  if (tid < 32) sbb0[tid] = sb0[tid];
  for (int i = tid; i < 2048; i += 256) sw1[i] = sW1[i];
  if (tid < 64) sbb1[tid] = sb1[tid];
  for (int i = tid; i < 384; i += 256) dw0[i] = dW0[i];
  if (tid < 64) dbb0[tid] = db0[tid];
  for (int i = tid; i < 8192; i += 256) dw1[i] = dW1[i];
  if (tid < 128) dbb1[tid] = db1[tid];
  __syncthreads();

  int pt = blockIdx.x * 256 + tid;
  const float* in = obj6 + (size_t)pt * 6;
  float c0 = in[0], c1 = in[1], c2 = in[2], c3 = in[3], c4 = in[4], c5 = in[5];

  {  // sparse (xyz only)
    float h1[32];
    #pragma unroll
    for (int j = 0; j < 32; ++j)
      h1[j] = fmaxf(c0 * sw0[j] + c1 * sw0[32 + j] + c2 * sw0[64 + j] + sbb0[j], 0.f);
    unsigned short* orow = s2 + (size_t)pt * 64;
    #pragma unroll
    for (int j8 = 0; j8 < 8; ++j8) {
      float a[8];
      #pragma unroll
      for (int e = 0; e < 8; ++e) a[e] = sbb1[j8 * 8 + e];
      #pragma unroll
      for (int i = 0; i < 32; ++i) {
        float hv = h1[i];
        #pragma unroll
        for (int e = 0; e < 8; ++e) a[e] += hv * sw1[i * 64 + j8 * 8 + e];
      }
      short8 o;
      #pragma unroll
      for (int e = 0; e < 8; ++e) o[e] = (short)f2bf(fmaxf(a[e], 0.f));
      *reinterpret_cast<short8*>(orow + j8 * 8) = o;
    }
  }

  {  // dense (all 6 dims)
    float h1[64];
    #pragma unroll
    for (int j = 0; j < 64; ++j) {
      float a = dbb0[j] + c0 * dw0[j] + c1 * dw0[64 + j] + c2 * dw0[128 + j]
              + c3 * dw0[192 + j] + c4 * dw0[256 + j] + c5 * dw0[320 + j];
      h1[j] = fmaxf(a, 0.f);
    }
    unsigned short* orow = h2 + (size_t)pt * 128;
    #pragma unroll
    for (int ch = 0; ch < 4; ++ch) {
      float a[32];
      #pragma unroll
      for (int e = 0; e < 32; ++e) a[e] = dbb1[ch * 32 + e];
      #pragma unroll 8
      for (int i = 0; i < 64; ++i) {
        float hv = h1[i];
        #pragma unroll
        for (int e = 0; e < 32; ++e) a[e] += hv * dw1[i * 128 + ch * 32 + e];
      }
      #pragma unroll
      for (int e8 = 0; e8 < 4; ++e8) {
        short8 o;
        #pragma unroll
        for (int e = 0; e < 8; ++e) o[e] = (short)f2bf(fmaxf(a[e8 * 8 + e], 0.f));
        *reinterpret_cast<short8*>(orow + ch * 32 + e8 * 8) = o;
      }
    }
  }
}

// ---------------------------------------------------------------------------
// [K,N] f32 -> planes rowpair [N][2K] bf16 (hi row || lo row)
__global__ void transpose_split(const float* __restrict__ W, unsigned short* __restrict__ Wt,
                                int K, int N)
{
  int id = blockIdx.x * 256 + threadIdx.x;
  if (id >= K * N) return;
  int k = id / N, n = id - k * N;
  unsigned short h, l;
  split2(W[id], h, l);
  Wt[(size_t)n * 2 * K + k] = h;
  Wt[(size_t)n * 2 * K + K + k] = l;
}

__global__ void zero_kernel(unsigned int* __restrict__ p, int n)
{
  int id = blockIdx.x * 256 + threadIdx.x;
  if (id < n) p[id] = 0u;
}

// pnmax f32 (indexed o=b*52+n) -> pn bf16 plane [(n*32+b)][512]
__global__ void pn_pack_kernel(const float* __restrict__ pnf, unsigned short* __restrict__ pnp)
{
  int id = blockIdx.x * 256 + threadIdx.x;  // 851968
  int o = id >> 9, c = id & 511;
  int b = o / 52, n = o - b * 52;
  pnp[((size_t)(n * 32 + b) << 9) + c] = f2bf(pnf[id]);
}

// t1[r][c] = relu(G1[(i*32+b)][c] + G2[(j*32+b)][c] + bias[c]), r=(i*52+j)*32+b
__global__ __launch_bounds__(256)
void rel_combine_kernel(const float* __restrict__ G1, const float* __restrict__ G2,
                        const float* __restrict__ bias, unsigned short* __restrict__ t1)
{
  int t = blockIdx.x * 256 + threadIdx.x;    // 86528*64 threads, 8 ch each
  int r = t >> 6, c8 = (t & 63) << 3;
  int b = r & 31;
  int pair = r >> 5;
  int i = pair / 52;
  int j = pair - i * 52;
  const float* g1 = G1 + ((size_t)(i * 32 + b) << 9) + c8;
  const float* g2 = G2 + ((size_t)(j * 32 + b) << 9) + c8;
  short8 o;
  #pragma unroll
  for (int e = 0; e < 8; ++e)
    o[e] = (short)f2bf(fmaxf(g1[e] + g2[e] + bias[c8 + e], 0.f));
  *reinterpret_cast<short8*>(t1 + (size_t)r * 512 + c8) = o;
}

// ---------------------------------------------------------------------------
// Object MLP (f32 exact): 512 -> 128 -> 256 -> 607, block per row r=n*32+b.
// ---------------------------------------------------------------------------
__global__ __launch_bounds__(256)
void objmlp_kernel(const float* __restrict__ obj,
                   const float* __restrict__ W0, const float* __restrict__ b0,
                   const float* __restrict__ W1, const float* __restrict__ b1,
                   const float* __restrict__ W2, const float* __restrict__ b2,
                   float* __restrict__ out)
{
  __shared__ float x[512];
  __shared__ float h1[128];
  __shared__ float h2[256];
  int tid = threadIdx.x;
  int r = blockIdx.x;          // r = n*32 + b
  int n = r >> 5, b = r & 31;
  int o = b * 52 + n;          // obj buffer indexed o = b*52 + n
  const float* xs = obj + (size_t)o * 512;
  x[tid] = xs[tid];
  x[tid + 256] = xs[tid + 256];
  __syncthreads();
  if (tid < 128) {
    float a = b0[tid];
    #pragma unroll 8
    for (int k = 0; k < 512; ++k) a += x[k] * W0[k * 128 + tid];
    h1[tid] = fmaxf(a, 0.f);
  }
  __syncthreads();
  {
    float a = b1[tid];
    #pragma unroll 8
    for (int k = 0; k < 128; ++k) a += h1[k] * W1[k * 256 + tid];
    h2[tid] = fmaxf(a, 0.f);
  }
  __syncthreads();
  for (int j = tid; j < 607; j += 256) {
    float a = b2[j];
    #pragma unroll 8
    for (int k = 0; k < 256; ++k) a += h2[k] * W2[k * 607 + j];
    out[(size_t)r * 607 + j] = a;
  }
}

// ---------------------------------------------------------------------------
extern "C" void kernel_launch(void* const* d_in, const int* in_sizes, int n_in,
                              void* d_out, int out_size, void* d_ws, size_t ws_size,
                              hipStream_t stream)
{
  const float* objects = (const float*)d_in[1];
  const float* de_W0 = (const float*)d_in[3];  const float* de_b0 = (const float*)d_in[4];
  const float* de_W1 = (const float*)d_in[5];  const float* de_b1 = (const float*)d_in[6];
  const float* de_W2 = (const float*)d_in[7];  const float* de_b2 = (const float*)d_in[8];
  const float* de_W3 = (const float*)d_in[9];  const float* de_b3 = (const float*)d_in[10];
  const float* de_W4 = (const float*)d_in[11]; const float* de_b4 = (const float*)d_in[12];
  const float* se_W0 = (const float*)d_in[13]; const float* se_b0 = (const float*)d_in[14];
  const float* se_W1 = (const float*)d_in[15]; const float* se_b1 = (const float*)d_in[16];
  const float* se_W2 = (const float*)d_in[17]; const float* se_b2 = (const float*)d_in[18];
  const float* om_W0 = (const float*)d_in[19]; const float* om_b0 = (const float*)d_in[20];
  const float* om_W1 = (const float*)d_in[21]; const float* om_b1 = (const float*)d_in[22];
  const float* om_W2 = (const float*)d_in[23]; const float* om_b2 = (const float*)d_in[24];
  const float* r1_W = (const float*)d_in[25];  const float* r1_b = (const float*)d_in[26];
  const float* r2_W = (const float*)d_in[27];  const float* r2_b = (const float*)d_in[28];
  const float* m1_W = (const float*)d_in[29];  const float* m1_b = (const float*)d_in[30];
  const float* m2_W = (const float*)d_in[31];  const float* m2_b = (const float*)d_in[32];
  (void)in_sizes; (void)n_in; (void)out_size;

  // ---- d_out is FLOAT32 (reference output dtype) ----
  float* outf = (float*)d_out;
  float* out_obj = outf;                          // [52,32,607]
  float* out_rel = outf + 1010048;                // [52,52,32,512]
  float* out_multi = out_rel + 44302336;

  // ---- workspace: weight planes + G1/G2 + t2 chunks ----
  char* ws = (char*)d_ws;
  size_t off = 0;
  auto alloc = [&](size_t bytes) -> void* {
    void* p = ws + off;
    off += (bytes + 255) & ~(size_t)255;
    return p;
  };
  unsigned short* wt_se2 = (unsigned short*)alloc((size_t)512 * 128 * 2);
  unsigned short* wt_de2 = (unsigned short*)alloc((size_t)256 * 256 * 2);
  unsigned short* wt_de3 = (unsigned short*)alloc((size_t)512 * 512 * 2);
  unsigned short* wt_de4 = (unsigned short*)alloc((size_t)512 * 1024 * 2);
  unsigned short* wt_g1  = (unsigned short*)alloc((size_t)512 * 1024 * 2);  // r1 top
  unsigned short* wt_g2  = (unsigned short*)alloc((size_t)512 * 1024 * 2);  // r1 bot
  unsigned short* wt_r2  = (unsigned short*)alloc((size_t)512 * 1024 * 2);
  unsigned short* wt_m1  = (unsigned short*)alloc((size_t)512 * 1024 * 2);
  unsigned short* wt_m2  = (unsigned short*)alloc((size_t)512 * 1024 * 2);
  float* G1 = (float*)alloc((size_t)851968 * 4);
  float* G2 = (float*)alloc((size_t)851968 * 4);
  size_t avail = (ws_size > off + 256) ? (ws_size - off - 256) : 0;
  int Tc = (int)(avail / 131072);        // t2 tiles: 128 rows x 512 bf16
  if (Tc < 1) Tc = 1;
  if (Tc > 676) Tc = 676;
  unsigned short* t2 = (unsigned short*)alloc((size_t)Tc * 131072);

  // ---- arena inside d_out (rel region 177.2 MB + multi region) ----
  char* arena = (char*)out_rel;
  unsigned int* pnmax   = (unsigned int*)(arena);              // 3.4 MB
  float*        obj_f32 = (float*)(arena + 3407872);           // 3.4 MB
  unsigned short* pn_p  = (unsigned short*)(arena + 6815744);  // [1664][512] 1.7MB
  char* cbuf = arena + 8519680;
  const size_t PC = 65536;                                     // pts/chunk, 26
  unsigned short* s2_c = (unsigned short*)(cbuf);                    //  8.4 MB
  unsigned short* h2_c = (unsigned short*)(cbuf + PC * 128);         // 16.8 MB
  unsigned short* h3_c = (unsigned short*)(cbuf + PC * 384);         // 33.6 MB
  unsigned short* h4_c = (unsigned short*)(cbuf + PC * 896);         // 67.1 MB
  unsigned short* t1   = (unsigned short*)out_multi;  // [86528][512] bf16 88.6MB

  // zero atomic-max accumulators (pnmax + obj_f32, adjacent)
  zero_kernel<<<(2 * 851968) / 256, 256, 0, stream>>>(pnmax, 2 * 851968);

  // weight plane transposes ([K,N] f32 -> [N][2K] bf16 hi||lo)
  auto tlaunch = [&](const float* W, unsigned short* Dst, int K, int N) {
    int n = K * N;
    transpose_split<<<(n + 255) / 256, 256, 0, stream>>>(W, Dst, K, N);
  };
  tlaunch(se_W2, wt_se2, 64, 512);
  tlaunch(de_W2, wt_de2, 128, 256);
  tlaunch(de_W3, wt_de3, 256, 512);
  tlaunch(de_W4, wt_de4, 512, 512);
  tlaunch(r1_W,            wt_g1, 512, 512);   // top 512 rows of r1_W
  tlaunch(r1_W + 512 * 512, wt_g2, 512, 512);  // bottom 512 rows
  tlaunch(r2_W,  wt_r2, 512, 512);
  tlaunch(m1_W,  wt_m1, 512, 512);
  tlaunch(m2_W,  wt_m2, 512, 512);

  // ---- point-cloud chains: 26 chunks x 64 objects (65,536 pts, 512 m-tiles) ----
  for (int c = 0; c < 26; ++c) {
    int base = c * (int)PC;
    points_kernel<<<PC / 256, 256, 0, stream>>>(
        objects + (size_t)base * 6,
        se_W0, se_b0, se_W1, se_b1, de_W0, de_b0, de_W1, de_b1, s2_c, h2_c);
    gemm3<0, 2><<<4 * (PC / 128), 256, 0, stream>>>(
        s2_c, wt_se2, se_b2, nullptr, pnmax, PC, 64, 512, 4, 1, base);
    gemm3<0, 1><<<2 * (PC / 128), 256, 0, stream>>>(
        h2_c, wt_de2, de_b2, h3_c, nullptr, PC, 128, 256, 2, 1, 0);
    gemm3<0, 1><<<4 * (PC / 128), 256, 0, stream>>>(
        h3_c, wt_de3, de_b3, h4_c, nullptr, PC, 256, 512, 4, 1, 0);
    gemm3<0, 2><<<4 * (PC / 128), 256, 0, stream>>>(
        h4_c, wt_de4, de_b4, nullptr, (unsigned int*)obj_f32, PC, 512, 512, 4, 1, base);
  }

  // pn plane from pnmax; object MLP (before r2 clobbers rel region)
  pn_pack_kernel<<<851968 / 256, 256, 0, stream>>>((const float*)pnmax, pn_p);
  objmlp_kernel<<<1664, 256, 0, stream>>>(obj_f32, om_W0, om_b0, om_W1, om_b1,
                                          om_W2, om_b2, out_obj);

  // ---- relation chain ----
  // r1 factorized: G1 = pn@W_top, G2 = pn@W_bot (M=1664, 13 tiles), f32 out.
  // zero bias via pointer to zeroed pnmax region? Use r1_b only in combine:
  // pass bias pointer of zeros -> use G-bias = 0 by passing om-style zero:
  // simplest: bias = (const float*)pnmax is NOT zero anymore (holds pn maxes).
  // Use a dedicated zero vector: reuse zero_kernel on G1 tail? Instead pass
  // r1_b to G1 and zeros to G2: need a zero buffer -> zero first 512 f32 of G2
  // before? G2 written by GEMM. Allocate tiny zero vec in ws: reuse t2 head
  // zeroed. (t2 unused until m1; zero 512 floats there.)
  zero_kernel<<<2, 256, 0, stream>>>((unsigned int*)t2, 512);
  gemm3<0, 0><<<13 * 4, 256, 0, stream>>>(
      pn_p, wt_g1, (const float*)t2, G1, nullptr, 1664, 512, 512, 4, 0, 0);
  gemm3<0, 0><<<13 * 4, 256, 0, stream>>>(
      pn_p, wt_g2, (const float*)t2, G2, nullptr, 1664, 512, 512, 4, 0, 0);
  rel_combine_kernel<<<86528 * 64 / 256, 256, 0, stream>>>(G1, G2, r1_b, t1);
  // r2: t1 -> rel finals f32 (clobbers arena scratch - all dead)
  gemm3<0, 0><<<4 * 676, 256, 0, stream>>>(
      t1, wt_r2, r2_b, out_rel, nullptr, 86528, 512, 512, 4, 0, 0);
  // m1/m2 chunked through t2 (t1 dead after r2)
  for (int tb = 0; tb < 676; tb += Tc) {
    int tiles = (676 - tb < Tc) ? (676 - tb) : Tc;
    int rows = tiles * 128;
    size_t rb = (size_t)tb * 128 * 512;
    gemm3<1, 1><<<4 * tiles, 256, 0, stream>>>(
        out_rel + rb, wt_m1, m1_b, t2, nullptr, rows, 512, 512, 4, 0, 0);
    gemm3<0, 0><<<4 * tiles, 256, 0, stream>>>(
        t2, wt_m2, m2_b, out_multi + rb, nullptr, rows, 512, 512, 4, 0, 0);
  }
}

// Round 8
// 4774.429 us; speedup vs baseline: 1.8405x; 1.2825x over previous
//
#include <hip/hip_runtime.h>
#include <stdint.h>

typedef __attribute__((ext_vector_type(8))) __bf16 bf16x8;
typedef __attribute__((ext_vector_type(4))) float f32x4;
typedef __attribute__((ext_vector_type(8))) short short8;

__device__ __forceinline__ unsigned short f2bf(float f) {
  unsigned int u = __float_as_uint(f);
  u += 0x7FFFu + ((u >> 16) & 1u);
  return (unsigned short)(u >> 16);
}
__device__ __forceinline__ float bf2f(unsigned short h) {
  return __uint_as_float((unsigned int)h << 16);
}
__device__ __forceinline__ void split2(float v, unsigned short& h, unsigned short& l) {
  h = f2bf(v);
  l = f2bf(v - bf2f(h));
}

// slot swizzle (proven 0-conflict at 8 slots): phys slot p holds logical
// (p&8) | ((p&7) ^ (row&7)); involution, applied on source addr + on reads.

// ---------------------------------------------------------------------------
// gemm3: split-2 GEMM (W = hi+lo planes, 2 MFMAs), BK=64, SM[3][128][64]=48KB.
// A bf16 plane [M][K]. W [N][2K]. COUT: 0=f32 raw; 1=relu bf16 plane;
// 2=maxout->atomicMax; 3=dual (f32 raw Cdst + relu bf16 Cdst2).
// ---------------------------------------------------------------------------
template<int COUT>
__global__ __launch_bounds__(256)
void gemm3(const unsigned short* __restrict__ A,
           const unsigned short* __restrict__ Wt,
           const float* __restrict__ bias,
           void* __restrict__ Cdst, void* __restrict__ Cdst2,
           unsigned int* __restrict__ Omax,
           int M, int K, int ldc, int ntn, int swz8, int m_base)
{
  __shared__ __align__(16) short SM[3][128][64];

  int bid = blockIdx.x;
  int mt, nt;
  if (swz8) {
    int xcd = bid & 7;
    int slot = bid >> 3;
    nt = slot % ntn;
    mt = (slot / ntn) * 8 + xcd;
  } else {
    mt = bid / ntn;
    nt = bid - mt * ntn;
  }
  const int m0 = mt * 128, n0 = nt * 128;
  const int tid = threadIdx.x;
  const int lane = tid & 63;
  const int wave = tid >> 6;
  const int wm = wave >> 1, wn = wave & 1;
  const int l15 = lane & 15, l4 = lane >> 4;

  const int rr = tid >> 3;          // row in 32-group
  const int sp = tid & 7;
  const int sl = sp ^ (rr & 7);
  const int slE = sl * 8;

  const unsigned short* a_p[4];
  const unsigned short* b_p[4];
  #pragma unroll
  for (int c = 0; c < 4; ++c) {
    int rt = c * 32 + rr;
    a_p[c] = A + (size_t)(m0 + rt) * K + slE;
    b_p[c] = Wt + (size_t)(n0 + rt) * 2 * K + slE;
  }

  f32x4 acc[4][4];
  #pragma unroll
  for (int a = 0; a < 4; ++a)
    #pragma unroll
    for (int b = 0; b < 4; ++b)
      acc[a][b] = (f32x4){0.f, 0.f, 0.f, 0.f};

  char* const smb = (char*)&SM[0][0][0];

  for (int k0 = 0; k0 < K; k0 += 64) {
    #pragma unroll
    for (int c = 0; c < 4; ++c) {
      char* lb = smb + c * 4096 + (tid & 192) * 16;
      __builtin_amdgcn_global_load_lds(a_p[c] + k0, (void*)lb, 16, 0, 0);
      __builtin_amdgcn_global_load_lds(b_p[c] + k0, (void*)(lb + 16384), 16, 0, 0);
      __builtin_amdgcn_global_load_lds(b_p[c] + K + k0, (void*)(lb + 32768), 16, 0, 0);
    }
    __syncthreads();
    #pragma unroll
    for (int kf = 0; kf < 2; ++kf) {
      bf16x8 av[4], bh[4], bl[4];
      #pragma unroll
      for (int mi = 0; mi < 4; ++mi) {
        int R = wm * 64 + mi * 16 + l15;
        int sph = (kf * 4 + l4) ^ (R & 7);
        av[mi] = *reinterpret_cast<const bf16x8*>(&SM[0][R][sph * 8]);
      }
      #pragma unroll
      for (int ni = 0; ni < 4; ++ni) {
        int R = wn * 64 + ni * 16 + l15;
        int sph = (kf * 4 + l4) ^ (R & 7);
        bh[ni] = *reinterpret_cast<const bf16x8*>(&SM[1][R][sph * 8]);
        bl[ni] = *reinterpret_cast<const bf16x8*>(&SM[2][R][sph * 8]);
      }
      #pragma unroll
      for (int mi = 0; mi < 4; ++mi)
        #pragma unroll
        for (int ni = 0; ni < 4; ++ni) {
          acc[mi][ni] = __builtin_amdgcn_mfma_f32_16x16x32_bf16(av[mi], bh[ni], acc[mi][ni], 0, 0, 0);
          acc[mi][ni] = __builtin_amdgcn_mfma_f32_16x16x32_bf16(av[mi], bl[ni], acc[mi][ni], 0, 0, 0);
        }
    }
    __syncthreads();
  }

  if (COUT == 2) {
    int obj = (m_base + m0) >> 10;
    #pragma unroll
    for (int ni = 0; ni < 4; ++ni) {
      int n = n0 + wn * 64 + ni * 16 + l15;
      float v = acc[0][ni][0];
      #pragma unroll
      for (int mi = 0; mi < 4; ++mi)
        #pragma unroll
        for (int i = 0; i < 4; ++i)
          v = fmaxf(v, acc[mi][ni][i]);
      v = fmaxf(v + bias[n], 0.0f);
      v = fmaxf(v, __shfl_xor(v, 16));
      v = fmaxf(v, __shfl_xor(v, 32));
      if (l4 == 0)
        atomicMax(&Omax[(size_t)obj * 512 + n], __float_as_uint(v));
    }
    return;
  }
  if (COUT == 0 || COUT == 3) {
    float* Bf = (float*)smb;
    float* Cf = (float*)Cdst;
    #pragma unroll
    for (int h = 0; h < 2; ++h) {
      if (wm == h) {
        #pragma unroll
        for (int mi = 0; mi < 4; ++mi)
          #pragma unroll
          for (int i = 0; i < 4; ++i) {
            int lr = mi * 16 + l4 * 4 + i;
            #pragma unroll
            for (int ni = 0; ni < 4; ++ni) {
              int col = wn * 64 + ni * 16 + l15;
              int off = lr * 128 + (((col >> 2) ^ (lr & 7)) << 2) + (col & 3);
              Bf[off] = acc[mi][ni][i] + bias[n0 + col];
            }
          }
      }
      __syncthreads();
      #pragma unroll
      for (int s = 0; s < 8; ++s) {
        int p = tid * 8 + s;
        int row = p >> 5, ls = p & 31;
        f32x4 v = *reinterpret_cast<const f32x4*>(&Bf[row * 128 + ((ls ^ (row & 7)) << 2)]);
        *reinterpret_cast<f32x4*>(Cf + (size_t)(m0 + h * 64 + row) * ldc + n0 + ls * 4) = v;
      }
      __syncthreads();
    }
  }
  if (COUT == 1 || COUT == 3) {
    unsigned short* Bp = (unsigned short*)smb;
    unsigned short* Cp = (unsigned short*)(COUT == 3 ? Cdst2 : Cdst);
    #pragma unroll
    for (int mi = 0; mi < 4; ++mi)
      #pragma unroll
      for (int i = 0; i < 4; ++i) {
        int row = wm * 64 + mi * 16 + l4 * 4 + i;
        #pragma unroll
        for (int ni = 0; ni < 4; ++ni) {
          int col = wn * 64 + ni * 16 + l15;
          int off = row * 128 + (((col >> 3) ^ (row & 7)) << 3) + (col & 7);
          Bp[off] = f2bf(fmaxf(acc[mi][ni][i] + bias[n0 + col], 0.f));
        }
      }
    __syncthreads();
    #pragma unroll
    for (int s = 0; s < 8; ++s) {
      int p = tid * 8 + s;
      int row = p >> 4, ls = p & 15;
      short8 v = *reinterpret_cast<const short8*>(&Bp[row * 128 + ((ls ^ (row & 7)) << 3)]);
      *reinterpret_cast<short8*>(Cp + (size_t)(m0 + row) * ldc + n0 + ls * 8) = v;
    }
  }
}

// ---------------------------------------------------------------------------
// gemmB: pure-bf16 GEMM (single W plane, 1 MFMA), BK=128, SM[2][128][128]=64KB.
// A bf16 plane [M][K]; W [N][K]. COUT: 1=relu bf16 plane; 2=maxout atomic.
// ---------------------------------------------------------------------------
template<int COUT>
__global__ __launch_bounds__(256)
void gemmB(const unsigned short* __restrict__ A,
           const unsigned short* __restrict__ Wt,
           const float* __restrict__ bias,
           void* __restrict__ Cdst,
           unsigned int* __restrict__ Omax,
           int M, int K, int ldc, int ntn, int swz8, int m_base)
{
  __shared__ __align__(16) short SM[2][128][128];   // 64 KiB

  int bid = blockIdx.x;
  int mt, nt;
  if (swz8) {
    int xcd = bid & 7;
    int slot = bid >> 3;
    nt = slot % ntn;
    mt = (slot / ntn) * 8 + xcd;
  } else {
    mt = bid / ntn;
    nt = bid - mt * ntn;
  }
  const int m0 = mt * 128, n0 = nt * 128;
  const int tid = threadIdx.x;
  const int lane = tid & 63;
  const int wave = tid >> 6;
  const int wm = wave >> 1, wn = wave & 1;
  const int l15 = lane & 15, l4 = lane >> 4;

  // staging: 16 slots/row; swizzle within 8-slot halves
  const int rr = tid >> 4;                         // 0..15
  const int sp16 = tid & 15;
  const int sl16 = (sp16 & 8) | ((sp16 & 7) ^ (rr & 7));
  const int slE = sl16 * 8;

  const unsigned short* a_p[8];
  const unsigned short* b_p[8];
  #pragma unroll
  for (int c = 0; c < 8; ++c) {
    int row = c * 16 + rr;
    a_p[c] = A + (size_t)(m0 + row) * K + slE;
    b_p[c] = Wt + (size_t)(n0 + row) * K + slE;
  }

  f32x4 acc[4][4];
  #pragma unroll
  for (int a = 0; a < 4; ++a)
    #pragma unroll
    for (int b = 0; b < 4; ++b)
      acc[a][b] = (f32x4){0.f, 0.f, 0.f, 0.f};

  char* const smb = (char*)&SM[0][0][0];

  for (int k0 = 0; k0 < K; k0 += 128) {
    #pragma unroll
    for (int c = 0; c < 8; ++c) {
      char* lb = smb + c * 4096 + (tid & 192) * 16;   // wave*1024
      __builtin_amdgcn_global_load_lds(a_p[c] + k0, (void*)lb, 16, 0, 0);
      __builtin_amdgcn_global_load_lds(b_p[c] + k0, (void*)(lb + 32768), 16, 0, 0);
    }
    __syncthreads();
    #pragma unroll
    for (int kf = 0; kf < 4; ++kf) {
      bf16x8 av[4], bv[4];
      int s = kf * 4 + l4;
      #pragma unroll
      for (int mi = 0; mi < 4; ++mi) {
        int R = wm * 64 + mi * 16 + l15;
        int sph = (s & 8) | ((s & 7) ^ (R & 7));
        av[mi] = *reinterpret_cast<const bf16x8*>(&SM[0][R][sph * 8]);
      }
      #pragma unroll
      for (int ni = 0; ni < 4; ++ni) {
        int R = wn * 64 + ni * 16 + l15;
        int sph = (s & 8) | ((s & 7) ^ (R & 7));
        bv[ni] = *reinterpret_cast<const bf16x8*>(&SM[1][R][sph * 8]);
      }
      #pragma unroll
      for (int mi = 0; mi < 4; ++mi)
        #pragma unroll
        for (int ni = 0; ni < 4; ++ni)
          acc[mi][ni] = __builtin_amdgcn_mfma_f32_16x16x32_bf16(av[mi], bv[ni], acc[mi][ni], 0, 0, 0);
    }
    __syncthreads();
  }

  if (COUT == 2) {
    int obj = (m_base + m0) >> 10;
    #pragma unroll
    for (int ni = 0; ni < 4; ++ni) {
      int n = n0 + wn * 64 + ni * 16 + l15;
      float v = acc[0][ni][0];
      #pragma unroll
      for (int mi = 0; mi < 4; ++mi)
        #pragma unroll
        for (int i = 0; i < 4; ++i)
          v = fmaxf(v, acc[mi][ni][i]);
      v = fmaxf(v + bias[n], 0.0f);
      v = fmaxf(v, __shfl_xor(v, 16));
      v = fmaxf(v, __shfl_xor(v, 32));
      if (l4 == 0)
        atomicMax(&Omax[(size_t)obj * 512 + n], __float_as_uint(v));
    }
  } else {
    unsigned short* Bp = (unsigned short*)smb;
    #pragma unroll
    for (int mi = 0; mi < 4; ++mi)
      #pragma unroll
      for (int i = 0; i < 4; ++i) {
        int row = wm * 64 + mi * 16 + l4 * 4 + i;
        #pragma unroll
        for (int ni = 0; ni < 4; ++ni) {
          int col = wn * 64 + ni * 16 + l15;
          int off = row * 128 + (((col >> 3) ^ (row & 7)) << 3) + (col & 7);
          Bp[off] = f2bf(fmaxf(acc[mi][ni][i] + bias[n0 + col], 0.f));
        }
      }
    __syncthreads();
    unsigned short* Cp = (unsigned short*)Cdst;
    #pragma unroll
    for (int s = 0; s < 8; ++s) {
      int p = tid * 8 + s;
      int row = p >> 4, ls = p & 15;
      short8 v = *reinterpret_cast<const short8*>(&Bp[row * 128 + ((ls ^ (row & 7)) << 3)]);
      *reinterpret_cast<short8*>(Cp + (size_t)(m0 + row) * ldc + n0 + ls * 8) = v;
    }
  }
}

// ---------------------------------------------------------------------------
// Per-point MLPs (f32 exact) -> relu'd bf16 planes: s2 [pt][64], h2 [pt][128].
// ---------------------------------------------------------------------------
__global__ __launch_bounds__(256)
void points_kernel(const float* __restrict__ obj6,
                   const float* __restrict__ sW0, const float* __restrict__ sb0,
                   const float* __restrict__ sW1, const float* __restrict__ sb1,
                   const float* __restrict__ dW0, const float* __restrict__ db0,
                   const float* __restrict__ dW1, const float* __restrict__ db1,
                   unsigned short* __restrict__ s2,
                   unsigned short* __restrict__ h2)
{
  __shared__ float sw0[96], sbb0[32], sw1[2048], sbb1[64];
  __shared__ float dw0[384], dbb0[64], dw1[8192], dbb1[128];
  int tid = threadIdx.x;
  for (int i = tid; i < 96; i += 256) sw0[i] = sW0[i];
  if (tid < 32) sbb0[tid] = sb0[tid];
  for (int i = tid; i < 2048; i += 256) sw1[i] = sW1[i];
  if (tid < 64) sbb1[tid] = sb1[tid];
  for (int i = tid; i < 384; i += 256) dw0[i] = dW0[i];
  if (tid < 64) dbb0[tid] = db0[tid];
  for (int i = tid; i < 8192; i += 256) dw1[i] = dW1[i];
  if (tid < 128) dbb1[tid] = db1[tid];
  __syncthreads();

  int pt = blockIdx.x * 256 + tid;
  const float* in = obj6 + (size_t)pt * 6;
  float c0 = in[0], c1 = in[1], c2 = in[2], c3 = in[3], c4 = in[4], c5 = in[5];

  {  // sparse (xyz only)
    float h1[32];
    #pragma unroll
    for (int j = 0; j < 32; ++j)
      h1[j] = fmaxf(c0 * sw0[j] + c1 * sw0[32 + j] + c2 * sw0[64 + j] + sbb0[j], 0.f);
    unsigned short* orow = s2 + (size_t)pt * 64;
    #pragma unroll
    for (int j8 = 0; j8 < 8; ++j8) {
      float a[8];
      #pragma unroll
      for (int e = 0; e < 8; ++e) a[e] = sbb1[j8 * 8 + e];
      #pragma unroll
      for (int i = 0; i < 32; ++i) {
        float hv = h1[i];
        #pragma unroll
        for (int e = 0; e < 8; ++e) a[e] += hv * sw1[i * 64 + j8 * 8 + e];
      }
      short8 o;
      #pragma unroll
      for (int e = 0; e < 8; ++e) o[e] = (short)f2bf(fmaxf(a[e], 0.f));
      *reinterpret_cast<short8*>(orow + j8 * 8) = o;
    }
  }

  {  // dense (all 6 dims)
    float h1[64];
    #pragma unroll
    for (int j = 0; j < 64; ++j) {
      float a = dbb0[j] + c0 * dw0[j] + c1 * dw0[64 + j] + c2 * dw0[128 + j]
              + c3 * dw0[192 + j] + c4 * dw0[256 + j] + c5 * dw0[320 + j];
      h1[j] = fmaxf(a, 0.f);
    }
    unsigned short* orow = h2 + (size_t)pt * 128;
    #pragma unroll
    for (int ch = 0; ch < 4; ++ch) {
      float a[32];
      #pragma unroll
      for (int e = 0; e < 32; ++e) a[e] = dbb1[ch * 32 + e];
      #pragma unroll 8
      for (int i = 0; i < 64; ++i) {
        float hv = h1[i];
        #pragma unroll
        for (int e = 0; e < 32; ++e) a[e] += hv * dw1[i * 128 + ch * 32 + e];
      }
      #pragma unroll
      for (int e8 = 0; e8 < 4; ++e8) {
        short8 o;
        #pragma unroll
        for (int e = 0; e < 8; ++e) o[e] = (short)f2bf(fmaxf(a[e8 * 8 + e], 0.f));
        *reinterpret_cast<short8*>(orow + ch * 32 + e8 * 8) = o;
      }
    }
  }
}

// ---------------------------------------------------------------------------
// [K,N] f32 -> [N][2K] bf16 hi||lo planes
__global__ void transpose_split(const float* __restrict__ W, unsigned short* __restrict__ Wt,
                                int K, int N)
{
  int id = blockIdx.x * 256 + threadIdx.x;
  if (id >= K * N) return;
  int k = id / N, n = id - k * N;
  unsigned short h, l;
  split2(W[id], h, l);
  Wt[(size_t)n * 2 * K + k] = h;
  Wt[(size_t)n * 2 * K + K + k] = l;
}

// [K,N] f32 -> [N][K] bf16 single plane
__global__ void transpose_cast(const float* __restrict__ W, unsigned short* __restrict__ Wt,
                               int K, int N)
{
  int id = blockIdx.x * 256 + threadIdx.x;
  if (id >= K * N) return;
  int k = id / N, n = id - k * N;
  Wt[(size_t)n * K + k] = f2bf(W[id]);
}

__global__ void zero_kernel(unsigned int* __restrict__ p, int n)
{
  int id = blockIdx.x * 256 + threadIdx.x;
  if (id < n) p[id] = 0u;
}

// pnmax f32 (o=b*52+n) -> pn bf16 plane [(n*32+b)][512]
__global__ void pn_pack_kernel(const float* __restrict__ pnf, unsigned short* __restrict__ pnp)
{
  int id = blockIdx.x * 256 + threadIdx.x;  // 851968
  int o = id >> 9, c = id & 511;
  int b = o / 52, n = o - b * 52;
  pnp[((size_t)(n * 32 + b) << 9) + c] = f2bf(pnf[id]);
}

// t1[r][c] = relu(G[(i*32+b)][c] + G[(j*32+b)][512+c] + bias[c]), r=(i*52+j)*32+b
__global__ __launch_bounds__(256)
void rel_combine_kernel(const float* __restrict__ G,
                        const float* __restrict__ bias, unsigned short* __restrict__ t1)
{
  int t = blockIdx.x * 256 + threadIdx.x;
  int r = t >> 6, c8 = (t & 63) << 3;
  int b = r & 31;
  int pair = r >> 5;
  int i = pair / 52;
  int j = pair - i * 52;
  const float* g1 = G + ((size_t)(i * 32 + b) << 10) + c8;
  const float* g2 = G + ((size_t)(j * 32 + b) << 10) + 512 + c8;
  short8 o;
  #pragma unroll
  for (int e = 0; e < 8; ++e)
    o[e] = (short)f2bf(fmaxf(g1[e] + g2[e] + bias[c8 + e], 0.f));
  *reinterpret_cast<short8*>(t1 + (size_t)r * 512 + c8) = o;
}

// ---------------------------------------------------------------------------
// Object MLP (f32 exact): 512 -> 128 -> 256 -> 607, block per row r=n*32+b.
// ---------------------------------------------------------------------------
__global__ __launch_bounds__(256)
void objmlp_kernel(const float* __restrict__ obj,
                   const float* __restrict__ W0, const float* __restrict__ b0,
                   const float* __restrict__ W1, const float* __restrict__ b1,
                   const float* __restrict__ W2, const float* __restrict__ b2,
                   float* __restrict__ out)
{
  __shared__ float x[512];
  __shared__ float h1[128];
  __shared__ float h2[256];
  int tid = threadIdx.x;
  int r = blockIdx.x;
  int n = r >> 5, b = r & 31;
  int o = b * 52 + n;
  const float* xs = obj + (size_t)o * 512;
  x[tid] = xs[tid];
  x[tid + 256] = xs[tid + 256];
  __syncthreads();
  if (tid < 128) {
    float a = b0[tid];
    #pragma unroll 8
    for (int k = 0; k < 512; ++k) a += x[k] * W0[k * 128 + tid];
    h1[tid] = fmaxf(a, 0.f);
  }
  __syncthreads();
  {
    float a = b1[tid];
    #pragma unroll 8
    for (int k = 0; k < 128; ++k) a += h1[k] * W1[k * 256 + tid];
    h2[tid] = fmaxf(a, 0.f);
  }
  __syncthreads();
  for (int j = tid; j < 607; j += 256) {
    float a = b2[j];
    #pragma unroll 8
    for (int k = 0; k < 256; ++k) a += h2[k] * W2[k * 607 + j];
    out[(size_t)r * 607 + j] = a;
  }
}

// ---------------------------------------------------------------------------
extern "C" void kernel_launch(void* const* d_in, const int* in_sizes, int n_in,
                              void* d_out, int out_size, void* d_ws, size_t ws_size,
                              hipStream_t stream)
{
  const float* objects = (const float*)d_in[1];
  const float* de_W0 = (const float*)d_in[3];  const float* de_b0 = (const float*)d_in[4];
  const float* de_W1 = (const float*)d_in[5];  const float* de_b1 = (const float*)d_in[6];
  const float* de_W2 = (const float*)d_in[7];  const float* de_b2 = (const float*)d_in[8];
  const float* de_W3 = (const float*)d_in[9];  const float* de_b3 = (const float*)d_in[10];
  const float* de_W4 = (const float*)d_in[11]; const float* de_b4 = (const float*)d_in[12];
  const float* se_W0 = (const float*)d_in[13]; const float* se_b0 = (const float*)d_in[14];
  const float* se_W1 = (const float*)d_in[15]; const float* se_b1 = (const float*)d_in[16];
  const float* se_W2 = (const float*)d_in[17]; const float* se_b2 = (const float*)d_in[18];
  const float* om_W0 = (const float*)d_in[19]; const float* om_b0 = (const float*)d_in[20];
  const float* om_W1 = (const float*)d_in[21]; const float* om_b1 = (const float*)d_in[22];
  const float* om_W2 = (const float*)d_in[23]; const float* om_b2 = (const float*)d_in[24];
  const float* r1_W = (const float*)d_in[25];  const float* r1_b = (const float*)d_in[26];
  const float* r2_W = (const float*)d_in[27];  const float* r2_b = (const float*)d_in[28];
  const float* m1_W = (const float*)d_in[29];  const float* m1_b = (const float*)d_in[30];
  const float* m2_W = (const float*)d_in[31];  const float* m2_b = (const float*)d_in[32];
  (void)in_sizes; (void)n_in; (void)out_size;

  float* outf = (float*)d_out;
  float* out_obj = outf;                          // [52,32,607]
  float* out_rel = outf + 1010048;                // [52,52,32,512]
  float* out_multi = out_rel + 44302336;

  // ---- workspace ----
  char* ws = (char*)d_ws;
  size_t off = 0;
  auto alloc = [&](size_t bytes) -> void* {
    void* p = ws + off;
    off += (bytes + 255) & ~(size_t)255;
    return p;
  };
  unsigned short* wt_se2 = (unsigned short*)alloc((size_t)512 * 128 * 2);   // split
  unsigned short* wt_de2 = (unsigned short*)alloc((size_t)256 * 128 * 2);   // plane
  unsigned short* wt_de3 = (unsigned short*)alloc((size_t)512 * 256 * 2);   // plane
  unsigned short* wt_de4 = (unsigned short*)alloc((size_t)512 * 512 * 2);   // plane
  unsigned short* wt_g   = (unsigned short*)alloc((size_t)1024 * 1024 * 2); // split N=1024
  unsigned short* wt_r2  = (unsigned short*)alloc((size_t)512 * 1024 * 2);  // split
  unsigned short* wt_m1  = (unsigned short*)alloc((size_t)512 * 1024 * 2);  // split
  unsigned short* wt_m2  = (unsigned short*)alloc((size_t)512 * 1024 * 2);  // split
  float* Gbuf = (float*)alloc((size_t)1664 * 1024 * 4);                     // 6.8 MB
  size_t avail = (ws_size > off + 256) ? (ws_size - off - 256) : 0;
  int Tc = (int)(avail / 131072);        // t2 tiles: 128 rows x 512 bf16
  if (Tc < 1) Tc = 1;
  if (Tc > 676) Tc = 676;
  unsigned short* t2 = (unsigned short*)alloc((size_t)Tc * 131072);

  // ---- arena inside d_out (rel+multi, 354,418,688 B) ----
  char* arena = (char*)out_rel;
  unsigned int* pnmax   = (unsigned int*)(arena);              // 3.4 MB
  float*        obj_f32 = (float*)(arena + 3407872);           // 3.4 MB
  unsigned short* pn_p  = (unsigned short*)(arena + 6815744);  // 1.7 MB
  char* cbuf = arena + 8519680;
  const size_t PC = 131072;                                    // 13 chunks
  unsigned short* s2_c = (unsigned short*)(cbuf);                    // 16.8 MB
  unsigned short* h2_c = (unsigned short*)(cbuf + PC * 128);         // 33.6 MB
  unsigned short* h3_c = (unsigned short*)(cbuf + PC * 384);         // 67.1 MB
  unsigned short* h4_c = (unsigned short*)(cbuf + PC * 896);         // 134.2 MB
  // relation phase (dense scratch dead by then):
  unsigned short* t1  = (unsigned short*)out_multi;                  // 88.6 MB
  unsigned short* t1b = (unsigned short*)((char*)out_multi + 88604672); // 88.6 MB

  zero_kernel<<<(2 * 851968) / 256, 256, 0, stream>>>(pnmax, 2 * 851968);

  auto tsplit = [&](const float* W, unsigned short* Dst, int K, int N) {
    int n = K * N;
    transpose_split<<<(n + 255) / 256, 256, 0, stream>>>(W, Dst, K, N);
  };
  auto tcast = [&](const float* W, unsigned short* Dst, int K, int N) {
    int n = K * N;
    transpose_cast<<<(n + 255) / 256, 256, 0, stream>>>(W, Dst, K, N);
  };
  tsplit(se_W2, wt_se2, 64, 512);
  tcast(de_W2, wt_de2, 128, 256);
  tcast(de_W3, wt_de3, 256, 512);
  tcast(de_W4, wt_de4, 512, 512);
  tsplit(r1_W,             wt_g,              512, 512);   // rows 0-511 (top)
  tsplit(r1_W + 512 * 512, wt_g + 512 * 1024, 512, 512);   // rows 512-1023 (bot)
  tsplit(r2_W,  wt_r2, 512, 512);
  tsplit(m1_W,  wt_m1, 512, 512);
  tsplit(m2_W,  wt_m2, 512, 512);

  // ---- point-cloud chains: 13 chunks x 128 objects (131,072 pts) ----
  for (int c = 0; c < 13; ++c) {
    int base = c * (int)PC;
    points_kernel<<<PC / 256, 256, 0, stream>>>(
        objects + (size_t)base * 6,
        se_W0, se_b0, se_W1, se_b1, de_W0, de_b0, de_W1, de_b1, s2_c, h2_c);
    gemm3<2><<<4 * (PC / 128), 256, 0, stream>>>(
        s2_c, wt_se2, se_b2, nullptr, nullptr, pnmax, PC, 64, 512, 4, 1, base);
    gemmB<1><<<2 * (PC / 128), 256, 0, stream>>>(
        h2_c, wt_de2, de_b2, h3_c, nullptr, PC, 128, 256, 2, 1, 0);
    gemmB<1><<<4 * (PC / 128), 256, 0, stream>>>(
        h3_c, wt_de3, de_b3, h4_c, nullptr, PC, 256, 512, 4, 1, 0);
    gemmB<2><<<4 * (PC / 128), 256, 0, stream>>>(
        h4_c, wt_de4, de_b4, nullptr, (unsigned int*)obj_f32, PC, 512, 512, 4, 1, base);
  }

  pn_pack_kernel<<<851968 / 256, 256, 0, stream>>>((const float*)pnmax, pn_p);
  objmlp_kernel<<<1664, 256, 0, stream>>>(obj_f32, om_W0, om_b0, om_W1, om_b1,
                                          om_W2, om_b2, out_obj);

  // ---- relation chain ----
  // G = pn @ [W_top | W_bot]  (M=1664, N=1024, f32 raw, zero bias from t2 head)
  zero_kernel<<<4, 256, 0, stream>>>((unsigned int*)t2, 1024);
  gemm3<0><<<13 * 8, 256, 0, stream>>>(
      pn_p, wt_g, (const float*)t2, Gbuf, nullptr, nullptr, 1664, 512, 1024, 8, 0, 0);
  rel_combine_kernel<<<86528 * 64 / 256, 256, 0, stream>>>(Gbuf, r1_b, t1);
  // r2: t1 -> rel finals f32 + t1b relu bf16 (dual out)
  gemm3<3><<<4 * 676, 256, 0, stream>>>(
      t1, wt_r2, r2_b, out_rel, t1b, nullptr, 86528, 512, 512, 4, 0, 0);
  // m1/m2 chunked through t2
  for (int tb = 0; tb < 676; tb += Tc) {
    int tiles = (676 - tb < Tc) ? (676 - tb) : Tc;
    int rows = tiles * 128;
    size_t rb = (size_t)tb * 128 * 512;
    gemm3<1><<<4 * tiles, 256, 0, stream>>>(
        t1b + rb, wt_m1, m1_b, t2, nullptr, nullptr, rows, 512, 512, 4, 0, 0);
    gemm3<0><<<4 * tiles, 256, 0, stream>>>(
        t2, wt_m2, m2_b, out_multi + rb, nullptr, nullptr, rows, 512, 512, 4, 0, 0);
  }
}

// Round 9
// 4701.363 us; speedup vs baseline: 1.8691x; 1.0155x over previous
//
#include <hip/hip_runtime.h>
#include <stdint.h>

typedef __attribute__((ext_vector_type(8))) __bf16 bf16x8;
typedef __attribute__((ext_vector_type(4))) float f32x4;
typedef __attribute__((ext_vector_type(8))) short short8;

__device__ __forceinline__ unsigned short f2bf(float f) {
  unsigned int u = __float_as_uint(f);
  u += 0x7FFFu + ((u >> 16) & 1u);
  return (unsigned short)(u >> 16);
}
__device__ __forceinline__ float bf2f(unsigned short h) {
  return __uint_as_float((unsigned int)h << 16);
}
__device__ __forceinline__ void split2(float v, unsigned short& h, unsigned short& l) {
  h = f2bf(v);
  l = f2bf(v - bf2f(h));
}

// slot swizzle (proven 0-conflict): phys slot p holds logical p^(row&7);
// involution, applied on source addr (gload_lds) + on ds reads.

// ---------------------------------------------------------------------------
// gemmP: pure-bf16 GEMM, BK=64, SM[2][128][64] = 32 KiB (m97-class occupancy:
// ~4 blocks/CU). A bf16 plane [M][K]; W plane [N][K].
// COUT: 0=f32 raw (+bias); 1=relu bf16 plane; 2=maxout->atomicMax;
//       3=dual (f32 raw Cdst + relu bf16 Cdst2).
// ---------------------------------------------------------------------------
template<int COUT>
__global__ __launch_bounds__(256)
void gemmP(const unsigned short* __restrict__ A,
           const unsigned short* __restrict__ Wt,
           const float* __restrict__ bias,
           void* __restrict__ Cdst, void* __restrict__ Cdst2,
           unsigned int* __restrict__ Omax,
           int M, int K, int ldc, int ntn, int swz8, int m_base)
{
  __shared__ __align__(16) short SM[2][128][64];   // 32 KiB

  int bid = blockIdx.x;
  int mt, nt;
  if (swz8) {
    int xcd = bid & 7;
    int slot = bid >> 3;
    nt = slot % ntn;
    mt = (slot / ntn) * 8 + xcd;
  } else {
    mt = bid / ntn;
    nt = bid - mt * ntn;
  }
  const int m0 = mt * 128, n0 = nt * 128;
  const int tid = threadIdx.x;
  const int lane = tid & 63;
  const int wave = tid >> 6;
  const int wm = wave >> 1, wn = wave & 1;
  const int l15 = lane & 15, l4 = lane >> 4;

  const int rr = tid >> 3;          // row in 32-group
  const int sp = tid & 7;
  const int sl = sp ^ (rr & 7);
  const int slE = sl * 8;

  const unsigned short* a_p[4];
  const unsigned short* b_p[4];
  #pragma unroll
  for (int c = 0; c < 4; ++c) {
    int rt = c * 32 + rr;
    a_p[c] = A + (size_t)(m0 + rt) * K + slE;
    b_p[c] = Wt + (size_t)(n0 + rt) * K + slE;
  }

  f32x4 acc[4][4];
  #pragma unroll
  for (int a = 0; a < 4; ++a)
    #pragma unroll
    for (int b = 0; b < 4; ++b)
      acc[a][b] = (f32x4){0.f, 0.f, 0.f, 0.f};

  char* const smb = (char*)&SM[0][0][0];

  for (int k0 = 0; k0 < K; k0 += 64) {
    #pragma unroll
    for (int c = 0; c < 4; ++c) {
      char* lb = smb + c * 4096 + (tid & 192) * 16;   // + wave*1024
      __builtin_amdgcn_global_load_lds(a_p[c] + k0, (void*)lb, 16, 0, 0);
      __builtin_amdgcn_global_load_lds(b_p[c] + k0, (void*)(lb + 16384), 16, 0, 0);
    }
    __syncthreads();
    #pragma unroll
    for (int kf = 0; kf < 2; ++kf) {
      bf16x8 av[4], bv[4];
      #pragma unroll
      for (int mi = 0; mi < 4; ++mi) {
        int R = wm * 64 + mi * 16 + l15;
        int sph = (kf * 4 + l4) ^ (R & 7);
        av[mi] = *reinterpret_cast<const bf16x8*>(&SM[0][R][sph * 8]);
      }
      #pragma unroll
      for (int ni = 0; ni < 4; ++ni) {
        int R = wn * 64 + ni * 16 + l15;
        int sph = (kf * 4 + l4) ^ (R & 7);
        bv[ni] = *reinterpret_cast<const bf16x8*>(&SM[1][R][sph * 8]);
      }
      #pragma unroll
      for (int mi = 0; mi < 4; ++mi)
        #pragma unroll
        for (int ni = 0; ni < 4; ++ni)
          acc[mi][ni] = __builtin_amdgcn_mfma_f32_16x16x32_bf16(av[mi], bv[ni], acc[mi][ni], 0, 0, 0);
    }
    __syncthreads();
  }

  if (COUT == 2) {
    int obj = (m_base + m0) >> 10;
    #pragma unroll
    for (int ni = 0; ni < 4; ++ni) {
      int n = n0 + wn * 64 + ni * 16 + l15;
      float v = acc[0][ni][0];
      #pragma unroll
      for (int mi = 0; mi < 4; ++mi)
        #pragma unroll
        for (int i = 0; i < 4; ++i)
          v = fmaxf(v, acc[mi][ni][i]);
      v = fmaxf(v + bias[n], 0.0f);
      v = fmaxf(v, __shfl_xor(v, 16));
      v = fmaxf(v, __shfl_xor(v, 32));
      if (l4 == 0)
        atomicMax(&Omax[(size_t)obj * 512 + n], __float_as_uint(v));
    }
    return;
  }
  if (COUT == 0 || COUT == 3) {
    // f32 bounce: [64][128] f32 = 32 KB, two halves
    float* Bf = (float*)smb;
    float* Cf = (float*)Cdst;
    #pragma unroll
    for (int h = 0; h < 2; ++h) {
      if (wm == h) {
        #pragma unroll
        for (int mi = 0; mi < 4; ++mi)
          #pragma unroll
          for (int i = 0; i < 4; ++i) {
            int lr = mi * 16 + l4 * 4 + i;
            #pragma unroll
            for (int ni = 0; ni < 4; ++ni) {
              int col = wn * 64 + ni * 16 + l15;
              int off = lr * 128 + (((col >> 2) ^ (lr & 7)) << 2) + (col & 3);
              Bf[off] = acc[mi][ni][i] + bias[n0 + col];
            }
          }
      }
      __syncthreads();
      #pragma unroll
      for (int s = 0; s < 8; ++s) {
        int p = tid * 8 + s;
        int row = p >> 5, ls = p & 31;
        f32x4 v = *reinterpret_cast<const f32x4*>(&Bf[row * 128 + ((ls ^ (row & 7)) << 2)]);
        *reinterpret_cast<f32x4*>(Cf + (size_t)(m0 + h * 64 + row) * ldc + n0 + ls * 4) = v;
      }
      __syncthreads();
    }
  }
  if (COUT == 1 || COUT == 3) {
    // bf16 bounce: [128][128] bf16 = 32 KB
    unsigned short* Bp = (unsigned short*)smb;
    unsigned short* Cp = (unsigned short*)(COUT == 3 ? Cdst2 : Cdst);
    #pragma unroll
    for (int mi = 0; mi < 4; ++mi)
      #pragma unroll
      for (int i = 0; i < 4; ++i) {
        int row = wm * 64 + mi * 16 + l4 * 4 + i;
        #pragma unroll
        for (int ni = 0; ni < 4; ++ni) {
          int col = wn * 64 + ni * 16 + l15;
          int off = row * 128 + (((col >> 3) ^ (row & 7)) << 3) + (col & 7);
          Bp[off] = f2bf(fmaxf(acc[mi][ni][i] + bias[n0 + col], 0.f));
        }
      }
    __syncthreads();
    #pragma unroll
    for (int s = 0; s < 8; ++s) {
      int p = tid * 8 + s;
      int row = p >> 4, ls = p & 15;
      short8 v = *reinterpret_cast<const short8*>(&Bp[row * 128 + ((ls ^ (row & 7)) << 3)]);
      *reinterpret_cast<short8*>(Cp + (size_t)(m0 + row) * ldc + n0 + ls * 8) = v;
    }
  }
}

// ---------------------------------------------------------------------------
// gemm3: split-2 GEMM (W hi+lo planes, 2 MFMAs), BK=64, SM[3][128][64]=48KB.
// Used for se2 maxout (K=64) and the tiny G factor GEMM (f32-grade W).
// COUT: 0=f32 raw; 2=maxout->atomicMax.
// ---------------------------------------------------------------------------
template<int COUT>
__global__ __launch_bounds__(256)
void gemm3(const unsigned short* __restrict__ A,
           const unsigned short* __restrict__ Wt,
           const float* __restrict__ bias,
           void* __restrict__ Cdst,
           unsigned int* __restrict__ Omax,
           int M, int K, int ldc, int ntn, int swz8, int m_base)
{
  __shared__ __align__(16) short SM[3][128][64];

  int bid = blockIdx.x;
  int mt, nt;
  if (swz8) {
    int xcd = bid & 7;
    int slot = bid >> 3;
    nt = slot % ntn;
    mt = (slot / ntn) * 8 + xcd;
  } else {
    mt = bid / ntn;
    nt = bid - mt * ntn;
  }
  const int m0 = mt * 128, n0 = nt * 128;
  const int tid = threadIdx.x;
  const int lane = tid & 63;
  const int wave = tid >> 6;
  const int wm = wave >> 1, wn = wave & 1;
  const int l15 = lane & 15, l4 = lane >> 4;

  const int rr = tid >> 3;
  const int sp = tid & 7;
  const int sl = sp ^ (rr & 7);
  const int slE = sl * 8;

  const unsigned short* a_p[4];
  const unsigned short* b_p[4];
  #pragma unroll
  for (int c = 0; c < 4; ++c) {
    int rt = c * 32 + rr;
    a_p[c] = A + (size_t)(m0 + rt) * K + slE;
    b_p[c] = Wt + (size_t)(n0 + rt) * 2 * K + slE;
  }

  f32x4 acc[4][4];
  #pragma unroll
  for (int a = 0; a < 4; ++a)
    #pragma unroll
    for (int b = 0; b < 4; ++b)
      acc[a][b] = (f32x4){0.f, 0.f, 0.f, 0.f};

  char* const smb = (char*)&SM[0][0][0];

  for (int k0 = 0; k0 < K; k0 += 64) {
    #pragma unroll
    for (int c = 0; c < 4; ++c) {
      char* lb = smb + c * 4096 + (tid & 192) * 16;
      __builtin_amdgcn_global_load_lds(a_p[c] + k0, (void*)lb, 16, 0, 0);
      __builtin_amdgcn_global_load_lds(b_p[c] + k0, (void*)(lb + 16384), 16, 0, 0);
      __builtin_amdgcn_global_load_lds(b_p[c] + K + k0, (void*)(lb + 32768), 16, 0, 0);
    }
    __syncthreads();
    #pragma unroll
    for (int kf = 0; kf < 2; ++kf) {
      bf16x8 av[4], bh[4], bl[4];
      #pragma unroll
      for (int mi = 0; mi < 4; ++mi) {
        int R = wm * 64 + mi * 16 + l15;
        int sph = (kf * 4 + l4) ^ (R & 7);
        av[mi] = *reinterpret_cast<const bf16x8*>(&SM[0][R][sph * 8]);
      }
      #pragma unroll
      for (int ni = 0; ni < 4; ++ni) {
        int R = wn * 64 + ni * 16 + l15;
        int sph = (kf * 4 + l4) ^ (R & 7);
        bh[ni] = *reinterpret_cast<const bf16x8*>(&SM[1][R][sph * 8]);
        bl[ni] = *reinterpret_cast<const bf16x8*>(&SM[2][R][sph * 8]);
      }
      #pragma unroll
      for (int mi = 0; mi < 4; ++mi)
        #pragma unroll
        for (int ni = 0; ni < 4; ++ni) {
          acc[mi][ni] = __builtin_amdgcn_mfma_f32_16x16x32_bf16(av[mi], bh[ni], acc[mi][ni], 0, 0, 0);
          acc[mi][ni] = __builtin_amdgcn_mfma_f32_16x16x32_bf16(av[mi], bl[ni], acc[mi][ni], 0, 0, 0);
        }
    }
    __syncthreads();
  }

  if (COUT == 2) {
    int obj = (m_base + m0) >> 10;
    #pragma unroll
    for (int ni = 0; ni < 4; ++ni) {
      int n = n0 + wn * 64 + ni * 16 + l15;
      float v = acc[0][ni][0];
      #pragma unroll
      for (int mi = 0; mi < 4; ++mi)
        #pragma unroll
        for (int i = 0; i < 4; ++i)
          v = fmaxf(v, acc[mi][ni][i]);
      v = fmaxf(v + bias[n], 0.0f);
      v = fmaxf(v, __shfl_xor(v, 16));
      v = fmaxf(v, __shfl_xor(v, 32));
      if (l4 == 0)
        atomicMax(&Omax[(size_t)obj * 512 + n], __float_as_uint(v));
    }
  } else {
    float* Bf = (float*)smb;
    float* Cf = (float*)Cdst;
    #pragma unroll
    for (int h = 0; h < 2; ++h) {
      if (wm == h) {
        #pragma unroll
        for (int mi = 0; mi < 4; ++mi)
          #pragma unroll
          for (int i = 0; i < 4; ++i) {
            int lr = mi * 16 + l4 * 4 + i;
            #pragma unroll
            for (int ni = 0; ni < 4; ++ni) {
              int col = wn * 64 + ni * 16 + l15;
              int off = lr * 128 + (((col >> 2) ^ (lr & 7)) << 2) + (col & 3);
              Bf[off] = acc[mi][ni][i] + bias[n0 + col];
            }
          }
      }
      __syncthreads();
      #pragma unroll
      for (int s = 0; s < 8; ++s) {
        int p = tid * 8 + s;
        int row = p >> 5, ls = p & 31;
        f32x4 v = *reinterpret_cast<const f32x4*>(&Bf[row * 128 + ((ls ^ (row & 7)) << 2)]);
        *reinterpret_cast<f32x4*>(Cf + (size_t)(m0 + h * 64 + row) * ldc + n0 + ls * 4) = v;
      }
      __syncthreads();
    }
  }
}

// ---------------------------------------------------------------------------
// Per-point MLPs (f32 exact) -> relu'd bf16 planes: s2 [pt][64], h2 [pt][128].
// ---------------------------------------------------------------------------
__global__ __launch_bounds__(256)
void points_kernel(const float* __restrict__ obj6,
                   const float* __restrict__ sW0, const float* __restrict__ sb0,
                   const float* __restrict__ sW1, const float* __restrict__ sb1,
                   const float* __restrict__ dW0, const float* __restrict__ db0,
                   const float* __restrict__ dW1, const float* __restrict__ db1,
                   unsigned short* __restrict__ s2,
                   unsigned short* __restrict__ h2)
{
  __shared__ float sw0[96], sbb0[32], sw1[2048], sbb1[64];
  __shared__ float dw0[384], dbb0[64], dw1[8192], dbb1[128];
  int tid = threadIdx.x;
  for (int i = tid; i < 96; i += 256) sw0[i] = sW0[i];
  if (tid < 32) sbb0[tid] = sb0[tid];
  for (int i = tid; i < 2048; i += 256) sw1[i] = sW1[i];
  if (tid < 64) sbb1[tid] = sb1[tid];
  for (int i = tid; i < 384; i += 256) dw0[i] = dW0[i];
  if (tid < 64) dbb0[tid] = db0[tid];
  for (int i = tid; i < 8192; i += 256) dw1[i] = dW1[i];
  if (tid < 128) dbb1[tid] = db1[tid];
  __syncthreads();

  int pt = blockIdx.x * 256 + tid;
  const float* in = obj6 + (size_t)pt * 6;
  float c0 = in[0], c1 = in[1], c2 = in[2], c3 = in[3], c4 = in[4], c5 = in[5];

  {  // sparse (xyz only)
    float h1[32];
    #pragma unroll
    for (int j = 0; j < 32; ++j)
      h1[j] = fmaxf(c0 * sw0[j] + c1 * sw0[32 + j] + c2 * sw0[64 + j] + sbb0[j], 0.f);
    unsigned short* orow = s2 + (size_t)pt * 64;
    #pragma unroll
    for (int j8 = 0; j8 < 8; ++j8) {
      float a[8];
      #pragma unroll
      for (int e = 0; e < 8; ++e) a[e] = sbb1[j8 * 8 + e];
      #pragma unroll
      for (int i = 0; i < 32; ++i) {
        float hv = h1[i];
        #pragma unroll
        for (int e = 0; e < 8; ++e) a[e] += hv * sw1[i * 64 + j8 * 8 + e];
      }
      short8 o;
      #pragma unroll
      for (int e = 0; e < 8; ++e) o[e] = (short)f2bf(fmaxf(a[e], 0.f));
      *reinterpret_cast<short8*>(orow + j8 * 8) = o;
    }
  }

  {  // dense (all 6 dims)
    float h1[64];
    #pragma unroll
    for (int j = 0; j < 64; ++j) {
      float a = dbb0[j] + c0 * dw0[j] + c1 * dw0[64 + j] + c2 * dw0[128 + j]
              + c3 * dw0[192 + j] + c4 * dw0[256 + j] + c5 * dw0[320 + j];
      h1[j] = fmaxf(a, 0.f);
    }
    unsigned short* orow = h2 + (size_t)pt * 128;
    #pragma unroll
    for (int ch = 0; ch < 4; ++ch) {
      float a[32];
      #pragma unroll
      for (int e = 0; e < 32; ++e) a[e] = dbb1[ch * 32 + e];
      #pragma unroll 8
      for (int i = 0; i < 64; ++i) {
        float hv = h1[i];
        #pragma unroll
        for (int e = 0; e < 32; ++e) a[e] += hv * dw1[i * 128 + ch * 32 + e];
      }
      #pragma unroll
      for (int e8 = 0; e8 < 4; ++e8) {
        short8 o;
        #pragma unroll
        for (int e = 0; e < 8; ++e) o[e] = (short)f2bf(fmaxf(a[e8 * 8 + e], 0.f));
        *reinterpret_cast<short8*>(orow + ch * 32 + e8 * 8) = o;
      }
    }
  }
}

// ---------------------------------------------------------------------------
// [K,N] f32 -> [N][2K] bf16 hi||lo planes
__global__ void transpose_split(const float* __restrict__ W, unsigned short* __restrict__ Wt,
                                int K, int N)
{
  int id = blockIdx.x * 256 + threadIdx.x;
  if (id >= K * N) return;
  int k = id / N, n = id - k * N;
  unsigned short h, l;
  split2(W[id], h, l);
  Wt[(size_t)n * 2 * K + k] = h;
  Wt[(size_t)n * 2 * K + K + k] = l;
}

// [K,N] f32 -> [N][K] bf16 single plane
__global__ void transpose_cast(const float* __restrict__ W, unsigned short* __restrict__ Wt,
                               int K, int N)
{
  int id = blockIdx.x * 256 + threadIdx.x;
  if (id >= K * N) return;
  int k = id / N, n = id - k * N;
  Wt[(size_t)n * K + k] = f2bf(W[id]);
}

__global__ void zero_kernel(unsigned int* __restrict__ p, int n)
{
  int id = blockIdx.x * 256 + threadIdx.x;
  if (id < n) p[id] = 0u;
}

// pnmax f32 (o=b*52+n) -> pn bf16 plane [(n*32+b)][512]
__global__ void pn_pack_kernel(const float* __restrict__ pnf, unsigned short* __restrict__ pnp)
{
  int id = blockIdx.x * 256 + threadIdx.x;  // 851968
  int o = id >> 9, c = id & 511;
  int b = o / 52, n = o - b * 52;
  pnp[((size_t)(n * 32 + b) << 9) + c] = f2bf(pnf[id]);
}

// t1[r][c] = relu(G[(i*32+b)][c] + G[(j*32+b)][512+c] + bias[c]), r=(i*52+j)*32+b
__global__ __launch_bounds__(256)
void rel_combine_kernel(const float* __restrict__ G,
                        const float* __restrict__ bias, unsigned short* __restrict__ t1)
{
  int t = blockIdx.x * 256 + threadIdx.x;
  int r = t >> 6, c8 = (t & 63) << 3;
  int b = r & 31;
  int pair = r >> 5;
  int i = pair / 52;
  int j = pair - i * 52;
  const float* g1 = G + ((size_t)(i * 32 + b) << 10) + c8;
  const float* g2 = G + ((size_t)(j * 32 + b) << 10) + 512 + c8;
  short8 o;
  #pragma unroll
  for (int e = 0; e < 8; ++e)
    o[e] = (short)f2bf(fmaxf(g1[e] + g2[e] + bias[c8 + e], 0.f));
  *reinterpret_cast<short8*>(t1 + (size_t)r * 512 + c8) = o;
}

// ---------------------------------------------------------------------------
// Object MLP (f32 exact): 512 -> 128 -> 256 -> 607, block per row r=n*32+b.
// ---------------------------------------------------------------------------
__global__ __launch_bounds__(256)
void objmlp_kernel(const float* __restrict__ obj,
                   const float* __restrict__ W0, const float* __restrict__ b0,
                   const float* __restrict__ W1, const float* __restrict__ b1,
                   const float* __restrict__ W2, const float* __restrict__ b2,
                   float* __restrict__ out)
{
  __shared__ float x[512];
  __shared__ float h1[128];
  __shared__ float h2[256];
  int tid = threadIdx.x;
  int r = blockIdx.x;
  int n = r >> 5, b = r & 31;
  int o = b * 52 + n;
  const float* xs = obj + (size_t)o * 512;
  x[tid] = xs[tid];
  x[tid + 256] = xs[tid + 256];
  __syncthreads();
  if (tid < 128) {
    float a = b0[tid];
    #pragma unroll 8
    for (int k = 0; k < 512; ++k) a += x[k] * W0[k * 128 + tid];
    h1[tid] = fmaxf(a, 0.f);
  }
  __syncthreads();
  {
    float a = b1[tid];
    #pragma unroll 8
    for (int k = 0; k < 128; ++k) a += h1[k] * W1[k * 256 + tid];
    h2[tid] = fmaxf(a, 0.f);
  }
  __syncthreads();
  for (int j = tid; j < 607; j += 256) {
    float a = b2[j];
    #pragma unroll 8
    for (int k = 0; k < 256; ++k) a += h2[k] * W2[k * 607 + j];
    out[(size_t)r * 607 + j] = a;
  }
}

// ---------------------------------------------------------------------------
extern "C" void kernel_launch(void* const* d_in, const int* in_sizes, int n_in,
                              void* d_out, int out_size, void* d_ws, size_t ws_size,
                              hipStream_t stream)
{
  const float* objects = (const float*)d_in[1];
  const float* de_W0 = (const float*)d_in[3];  const float* de_b0 = (const float*)d_in[4];
  const float* de_W1 = (const float*)d_in[5];  const float* de_b1 = (const float*)d_in[6];
  const float* de_W2 = (const float*)d_in[7];  const float* de_b2 = (const float*)d_in[8];
  const float* de_W3 = (const float*)d_in[9];  const float* de_b3 = (const float*)d_in[10];
  const float* de_W4 = (const float*)d_in[11]; const float* de_b4 = (const float*)d_in[12];
  const float* se_W0 = (const float*)d_in[13]; const float* se_b0 = (const float*)d_in[14];
  const float* se_W1 = (const float*)d_in[15]; const float* se_b1 = (const float*)d_in[16];
  const float* se_W2 = (const float*)d_in[17]; const float* se_b2 = (const float*)d_in[18];
  const float* om_W0 = (const float*)d_in[19]; const float* om_b0 = (const float*)d_in[20];
  const float* om_W1 = (const float*)d_in[21]; const float* om_b1 = (const float*)d_in[22];
  const float* om_W2 = (const float*)d_in[23]; const float* om_b2 = (const float*)d_in[24];
  const float* r1_W = (const float*)d_in[25];  const float* r1_b = (const float*)d_in[26];
  const float* r2_W = (const float*)d_in[27];  const float* r2_b = (const float*)d_in[28];
  const float* m1_W = (const float*)d_in[29];  const float* m1_b = (const float*)d_in[30];
  const float* m2_W = (const float*)d_in[31];  const float* m2_b = (const float*)d_in[32];
  (void)in_sizes; (void)n_in; (void)out_size;

  float* outf = (float*)d_out;
  float* out_obj = outf;                          // [52,32,607]
  float* out_rel = outf + 1010048;                // [52,52,32,512]
  float* out_multi = out_rel + 44302336;

  // ---- workspace ----
  char* ws = (char*)d_ws;
  size_t off = 0;
  auto alloc = [&](size_t bytes) -> void* {
    void* p = ws + off;
    off += (bytes + 255) & ~(size_t)255;
    return p;
  };
  unsigned short* wt_se2 = (unsigned short*)alloc((size_t)512 * 128 * 2);   // split
  unsigned short* wt_de2 = (unsigned short*)alloc((size_t)256 * 128 * 2);   // plane
  unsigned short* wt_de3 = (unsigned short*)alloc((size_t)512 * 256 * 2);   // plane
  unsigned short* wt_de4 = (unsigned short*)alloc((size_t)512 * 512 * 2);   // plane
  unsigned short* wt_g   = (unsigned short*)alloc((size_t)1024 * 1024 * 2); // split N=1024
  unsigned short* wt_r2  = (unsigned short*)alloc((size_t)512 * 512 * 2);   // plane
  unsigned short* wt_m1  = (unsigned short*)alloc((size_t)512 * 512 * 2);   // plane
  unsigned short* wt_m2  = (unsigned short*)alloc((size_t)512 * 512 * 2);   // plane
  float* Gbuf = (float*)alloc((size_t)1664 * 1024 * 4);                     // 6.8 MB
  size_t avail = (ws_size > off + 256) ? (ws_size - off - 256) : 0;
  int Tc = (int)(avail / 131072);        // t2 tiles: 128 rows x 512 bf16
  if (Tc < 1) Tc = 1;
  if (Tc > 676) Tc = 676;
  unsigned short* t2 = (unsigned short*)alloc((size_t)Tc * 131072);

  // ---- arena inside d_out (rel+multi, 354,418,688 B) ----
  char* arena = (char*)out_rel;
  unsigned int* pnmax   = (unsigned int*)(arena);              // 3.4 MB
  float*        obj_f32 = (float*)(arena + 3407872);           // 3.4 MB
  unsigned short* pn_p  = (unsigned short*)(arena + 6815744);  // 1.7 MB
  char* cbuf = arena + 8519680;
  const size_t PC = 131072;                                    // 13 chunks
  unsigned short* s2_c = (unsigned short*)(cbuf);                    // 16.8 MB
  unsigned short* h2_c = (unsigned short*)(cbuf + PC * 128);         // 33.6 MB
  unsigned short* h3_c = (unsigned short*)(cbuf + PC * 384);         // 67.1 MB
  unsigned short* h4_c = (unsigned short*)(cbuf + PC * 896);         // 134.2 MB
  // relation phase (dense scratch dead by then):
  unsigned short* t1  = (unsigned short*)out_multi;                  // 88.6 MB
  unsigned short* t1b = (unsigned short*)((char*)out_multi + 88604672); // 88.6 MB

  zero_kernel<<<(2 * 851968) / 256, 256, 0, stream>>>(pnmax, 2 * 851968);

  auto tsplit = [&](const float* W, unsigned short* Dst, int K, int N) {
    int n = K * N;
    transpose_split<<<(n + 255) / 256, 256, 0, stream>>>(W, Dst, K, N);
  };
  auto tcast = [&](const float* W, unsigned short* Dst, int K, int N) {
    int n = K * N;
    transpose_cast<<<(n + 255) / 256, 256, 0, stream>>>(W, Dst, K, N);
  };
  tsplit(se_W2, wt_se2, 64, 512);
  tcast(de_W2, wt_de2, 128, 256);
  tcast(de_W3, wt_de3, 256, 512);
  tcast(de_W4, wt_de4, 512, 512);
  tsplit(r1_W,             wt_g,              512, 512);   // rows 0-511 (top)
  tsplit(r1_W + 512 * 512, wt_g + 512 * 1024, 512, 512);   // rows 512-1023 (bot)
  tcast(r2_W,  wt_r2, 512, 512);
  tcast(m1_W,  wt_m1, 512, 512);
  tcast(m2_W,  wt_m2, 512, 512);

  // ---- point-cloud chains: 13 chunks x 128 objects (131,072 pts) ----
  for (int c = 0; c < 13; ++c) {
    int base = c * (int)PC;
    points_kernel<<<PC / 256, 256, 0, stream>>>(
        objects + (size_t)base * 6,
        se_W0, se_b0, se_W1, se_b1, de_W0, de_b0, de_W1, de_b1, s2_c, h2_c);
    gemm3<2><<<4 * (PC / 128), 256, 0, stream>>>(
        s2_c, wt_se2, se_b2, nullptr, pnmax, PC, 64, 512, 4, 1, base);
    gemmP<1><<<2 * (PC / 128), 256, 0, stream>>>(
        h2_c, wt_de2, de_b2, h3_c, nullptr, nullptr, PC, 128, 256, 2, 1, 0);
    gemmP<1><<<4 * (PC / 128), 256, 0, stream>>>(
        h3_c, wt_de3, de_b3, h4_c, nullptr, nullptr, PC, 256, 512, 4, 1, 0);
    gemmP<2><<<4 * (PC / 128), 256, 0, stream>>>(
        h4_c, wt_de4, de_b4, nullptr, nullptr, (unsigned int*)obj_f32, PC, 512, 512, 4, 1, base);
  }

  pn_pack_kernel<<<851968 / 256, 256, 0, stream>>>((const float*)pnmax, pn_p);
  objmlp_kernel<<<1664, 256, 0, stream>>>(obj_f32, om_W0, om_b0, om_W1, om_b1,
                                          om_W2, om_b2, out_obj);

  // ---- relation chain ----
  // G = pn @ [W_top | W_bot]  (M=1664, N=1024, f32 raw, zero bias from t2 head)
  zero_kernel<<<4, 256, 0, stream>>>((unsigned int*)t2, 1024);
  gemm3<0><<<13 * 8, 256, 0, stream>>>(
      pn_p, wt_g, (const float*)t2, Gbuf, nullptr, 1664, 512, 1024, 8, 0, 0);
  rel_combine_kernel<<<86528 * 64 / 256, 256, 0, stream>>>(Gbuf, r1_b, t1);
  // r2: t1 -> rel finals f32 + t1b relu bf16 (dual out)
  gemmP<3><<<4 * 676, 256, 0, stream>>>(
      t1, wt_r2, r2_b, out_rel, t1b, nullptr, 86528, 512, 512, 4, 0, 0);
  // m1/m2 chunked through t2
  for (int tb = 0; tb < 676; tb += Tc) {
    int tiles = (676 - tb < Tc) ? (676 - tb) : Tc;
    int rows = tiles * 128;
    size_t rb = (size_t)tb * 128 * 512;
    gemmP<1><<<4 * tiles, 256, 0, stream>>>(
        t1b + rb, wt_m1, m1_b, t2, nullptr, nullptr, rows, 512, 512, 4, 0, 0);
    gemmP<0><<<4 * tiles, 256, 0, stream>>>(
        t2, wt_m2, m2_b, out_multi + rb, nullptr, nullptr, rows, 512, 512, 4, 0, 0);
  }
}

// Round 10
// 3933.118 us; speedup vs baseline: 2.2342x; 1.1953x over previous
//
#include <hip/hip_runtime.h>
#include <stdint.h>

typedef __attribute__((ext_vector_type(8))) __bf16 bf16x8;
typedef __attribute__((ext_vector_type(4))) float f32x4;
typedef __attribute__((ext_vector_type(8))) short short8;

__device__ __forceinline__ unsigned short f2bf(float f) {
  unsigned int u = __float_as_uint(f);
  u += 0x7FFFu + ((u >> 16) & 1u);
  return (unsigned short)(u >> 16);
}
__device__ __forceinline__ float bf2f(unsigned short h) {
  return __uint_as_float((unsigned int)h << 16);
}
__device__ __forceinline__ void split2(float v, unsigned short& h, unsigned short& l) {
  h = f2bf(v);
  l = f2bf(v - bf2f(h));
}

// ---------------------------------------------------------------------------
// gemmX: 256x256 tile, BK=64, 512 threads (8 waves 2Mx4N), per-wave 128x64.
// 2 K-tile LDS double-buffer (128 KiB dynamic). Iteration kt: burst-stage
// kt+1 into buf[cur^1] (dead since last barrier), 4 phases {ds_read+16 MFMA},
// one __syncthreads (vmcnt(0) drain) per K-tile. XOR slot swizzle both sides.
// COUT: 0=f32 raw; 1=relu bf16 plane; 2=maxout->atomicMax; 3=dual f32+bf16.
// ---------------------------------------------------------------------------
template<int COUT>
__global__ __launch_bounds__(512, 2)
void gemmX(const unsigned short* __restrict__ A,
           const unsigned short* __restrict__ Wt,
           const float* __restrict__ bias,
           void* __restrict__ Cdst, void* __restrict__ Cdst2,
           unsigned int* __restrict__ Omax,
           int M, int K, int ldc, int ntn, int swz8, int m_base)
{
  extern __shared__ __align__(16) char smem[];   // 131072 B
  short* Ab0 = (short*)smem;                     // [256][64]
  short* Bb0 = (short*)(smem + 32768);
  short* Ab1 = (short*)(smem + 65536);
  short* Bb1 = (short*)(smem + 98304);

  int bid = blockIdx.x;
  int mt, nt;
  if (swz8) {                       // requires Mtiles % 8 == 0
    int xcd = bid & 7;
    int slot = bid >> 3;
    nt = slot % ntn;
    mt = (slot / ntn) * 8 + xcd;
  } else {
    mt = bid / ntn;
    nt = bid - mt * ntn;
  }
  const int m0 = mt * 256, n0 = nt * 256;
  const int tid = threadIdx.x;
  const int lane = tid & 63;
  const int w = tid >> 6;           // wave 0..7
  const int wm = w >> 2, wn = w & 3;
  const int l15 = lane & 15, l4 = lane >> 4;
  const int lr = lane >> 3;                    // 0..7
  const int kswz = ((lane & 7) ^ lr) * 8;      // source-side swizzle (elems)

  const unsigned short* a_s[4];
  const unsigned short* b_s[4];
  #pragma unroll
  for (int i = 0; i < 4; ++i) {
    int row = i * 64 + w * 8 + lr;
    a_s[i] = A + (size_t)(m0 + row) * K + kswz;
    b_s[i] = Wt + (size_t)(n0 + row) * K + kswz;
  }

  f32x4 acc[8][4];
  #pragma unroll
  for (int a = 0; a < 8; ++a)
    #pragma unroll
    for (int b = 0; b < 4; ++b)
      acc[a][b] = (f32x4){0.f, 0.f, 0.f, 0.f};

  auto STAGE = [&](int kt, short* Ad, short* Bd) {
    int koff = kt * 64;
    #pragma unroll
    for (int i = 0; i < 4; ++i) {
      int rows = i * 64 + w * 8;
      __builtin_amdgcn_global_load_lds(a_s[i] + koff, (void*)(Ad + rows * 64), 16, 0, 0);
      __builtin_amdgcn_global_load_lds(b_s[i] + koff, (void*)(Bd + rows * 64), 16, 0, 0);
    }
  };

  STAGE(0, Ab0, Bb0);
  __syncthreads();                  // vmcnt(0): buf0 landed

  const int NT = K >> 6;
  for (int kt = 0; kt < NT; ++kt) {
    int cur = kt & 1;
    short* Ac = cur ? Ab1 : Ab0;
    short* Bc = cur ? Bb1 : Bb0;
    if (kt + 1 < NT) STAGE(kt + 1, cur ? Ab0 : Ab1, cur ? Bb0 : Bb1);
    #pragma unroll
    for (int ks = 0; ks < 2; ++ks) {
      bf16x8 bv[4];
      #pragma unroll
      for (int ni = 0; ni < 4; ++ni) {
        int R = wn * 64 + ni * 16 + l15;
        int ph = (ks * 4 + l4) ^ (R & 7);
        bv[ni] = *reinterpret_cast<const bf16x8*>(&Bc[R * 64 + ph * 8]);
      }
      #pragma unroll
      for (int mh = 0; mh < 2; ++mh) {
        bf16x8 av[4];
        #pragma unroll
        for (int m4 = 0; m4 < 4; ++m4) {
          int R = wm * 128 + (mh * 4 + m4) * 16 + l15;
          int ph = (ks * 4 + l4) ^ (R & 7);
          av[m4] = *reinterpret_cast<const bf16x8*>(&Ac[R * 64 + ph * 8]);
        }
        __builtin_amdgcn_s_setprio(1);
        #pragma unroll
        for (int m4 = 0; m4 < 4; ++m4)
          #pragma unroll
          for (int ni = 0; ni < 4; ++ni)
            acc[mh * 4 + m4][ni] =
                __builtin_amdgcn_mfma_f32_16x16x32_bf16(av[m4], bv[ni], acc[mh * 4 + m4][ni], 0, 0, 0);
        __builtin_amdgcn_s_setprio(0);
      }
    }
    __syncthreads();                // vmcnt(0) drains kt+1's loads; frees buf
  }

  if (COUT == 2) {
    int obj = (m_base + m0) >> 10;  // 256 rows within one 1024-pt object
    #pragma unroll
    for (int ni = 0; ni < 4; ++ni) {
      int n = n0 + wn * 64 + ni * 16 + l15;
      float v = acc[0][ni][0];
      #pragma unroll
      for (int mi = 0; mi < 8; ++mi)
        #pragma unroll
        for (int i = 0; i < 4; ++i)
          v = fmaxf(v, acc[mi][ni][i]);
      v = fmaxf(v + bias[n], 0.0f);
      v = fmaxf(v, __shfl_xor(v, 16));
      v = fmaxf(v, __shfl_xor(v, 32));
      if (l4 == 0)
        atomicMax(&Omax[(size_t)obj * 512 + n], __float_as_uint(v));
    }
    return;
  }
  if (COUT == 0 || COUT == 3) {
    // f32 bounce: [128][256] f32 = 128 KB, two wm half-passes
    float* Bf = (float*)smem;
    float* Cf = (float*)Cdst;
    #pragma unroll
    for (int h = 0; h < 2; ++h) {
      if (wm == h) {
        #pragma unroll
        for (int mi = 0; mi < 8; ++mi)
          #pragma unroll
          for (int i = 0; i < 4; ++i) {
            int row = mi * 16 + l4 * 4 + i;
            #pragma unroll
            for (int ni = 0; ni < 4; ++ni) {
              int col = wn * 64 + ni * 16 + l15;
              int sl = col >> 2;
              int ph = (sl & 56) | ((sl & 7) ^ (row & 7));
              Bf[row * 256 + ph * 4 + (col & 3)] = acc[mi][ni][i] + bias[n0 + col];
            }
          }
      }
      __syncthreads();
      #pragma unroll
      for (int s = 0; s < 16; ++s) {
        int p = s * 512 + tid;
        int row = p >> 6, sl = p & 63;
        int ph = (sl & 56) | ((sl & 7) ^ (row & 7));
        f32x4 v = *reinterpret_cast<const f32x4*>(&Bf[row * 256 + ph * 4]);
        *reinterpret_cast<f32x4*>(Cf + (size_t)(m0 + h * 128 + row) * ldc + n0 + sl * 4) = v;
      }
      __syncthreads();
    }
  }
  if (COUT == 1 || COUT == 3) {
    // bf16 bounce: [256][256] bf16 = 128 KB, one pass
    unsigned short* Bp = (unsigned short*)smem;
    unsigned short* Cp = (unsigned short*)(COUT == 3 ? Cdst2 : Cdst);
    #pragma unroll
    for (int mi = 0; mi < 8; ++mi)
      #pragma unroll
      for (int i = 0; i < 4; ++i) {
        int row = wm * 128 + mi * 16 + l4 * 4 + i;
        #pragma unroll
        for (int ni = 0; ni < 4; ++ni) {
          int col = wn * 64 + ni * 16 + l15;
          int sl = col >> 3;
          int ph = (sl & 24) | ((sl & 7) ^ (row & 7));
          Bp[row * 256 + ph * 8 + (col & 7)] = f2bf(fmaxf(acc[mi][ni][i] + bias[n0 + col], 0.f));
        }
      }
    __syncthreads();
    #pragma unroll
    for (int s = 0; s < 16; ++s) {
      int p = s * 512 + tid;
      int row = p >> 5, sl = p & 31;
      int ph = (sl & 24) | ((sl & 7) ^ (row & 7));
      short8 v = *reinterpret_cast<const short8*>(&Bp[row * 256 + ph * 8]);
      *reinterpret_cast<short8*>(Cp + (size_t)(m0 + row) * ldc + n0 + sl * 8) = v;
    }
  }
}

// ---------------------------------------------------------------------------
// gemm3: split-2 GEMM (W hi+lo planes), BK=64, SM[3][128][64]=48KB.
// Used for se2 maxout (K=64) and the G factor GEMM (f32-grade W).
// COUT: 0=f32 raw; 2=maxout->atomicMax.
// ---------------------------------------------------------------------------
template<int COUT>
__global__ __launch_bounds__(256)
void gemm3(const unsigned short* __restrict__ A,
           const unsigned short* __restrict__ Wt,
           const float* __restrict__ bias,
           void* __restrict__ Cdst,
           unsigned int* __restrict__ Omax,
           int M, int K, int ldc, int ntn, int swz8, int m_base)
{
  __shared__ __align__(16) short SM[3][128][64];

  int bid = blockIdx.x;
  int mt, nt;
  if (swz8) {
    int xcd = bid & 7;
    int slot = bid >> 3;
    nt = slot % ntn;
    mt = (slot / ntn) * 8 + xcd;
  } else {
    mt = bid / ntn;
    nt = bid - mt * ntn;
  }
  const int m0 = mt * 128, n0 = nt * 128;
  const int tid = threadIdx.x;
  const int lane = tid & 63;
  const int wave = tid >> 6;
  const int wm = wave >> 1, wn = wave & 1;
  const int l15 = lane & 15, l4 = lane >> 4;

  const int rr = tid >> 3;
  const int sp = tid & 7;
  const int sl = sp ^ (rr & 7);
  const int slE = sl * 8;

  const unsigned short* a_p[4];
  const unsigned short* b_p[4];
  #pragma unroll
  for (int c = 0; c < 4; ++c) {
    int rt = c * 32 + rr;
    a_p[c] = A + (size_t)(m0 + rt) * K + slE;
    b_p[c] = Wt + (size_t)(n0 + rt) * 2 * K + slE;
  }

  f32x4 acc[4][4];
  #pragma unroll
  for (int a = 0; a < 4; ++a)
    #pragma unroll
    for (int b = 0; b < 4; ++b)
      acc[a][b] = (f32x4){0.f, 0.f, 0.f, 0.f};

  char* const smb = (char*)&SM[0][0][0];

  for (int k0 = 0; k0 < K; k0 += 64) {
    #pragma unroll
    for (int c = 0; c < 4; ++c) {
      char* lb = smb + c * 4096 + (tid & 192) * 16;
      __builtin_amdgcn_global_load_lds(a_p[c] + k0, (void*)lb, 16, 0, 0);
      __builtin_amdgcn_global_load_lds(b_p[c] + k0, (void*)(lb + 16384), 16, 0, 0);
      __builtin_amdgcn_global_load_lds(b_p[c] + K + k0, (void*)(lb + 32768), 16, 0, 0);
    }
    __syncthreads();
    #pragma unroll
    for (int kf = 0; kf < 2; ++kf) {
      bf16x8 av[4], bh[4], bl[4];
      #pragma unroll
      for (int mi = 0; mi < 4; ++mi) {
        int R = wm * 64 + mi * 16 + l15;
        int sph = (kf * 4 + l4) ^ (R & 7);
        av[mi] = *reinterpret_cast<const bf16x8*>(&SM[0][R][sph * 8]);
      }
      #pragma unroll
      for (int ni = 0; ni < 4; ++ni) {
        int R = wn * 64 + ni * 16 + l15;
        int sph = (kf * 4 + l4) ^ (R & 7);
        bh[ni] = *reinterpret_cast<const bf16x8*>(&SM[1][R][sph * 8]);
        bl[ni] = *reinterpret_cast<const bf16x8*>(&SM[2][R][sph * 8]);
      }
      #pragma unroll
      for (int mi = 0; mi < 4; ++mi)
        #pragma unroll
        for (int ni = 0; ni < 4; ++ni) {
          acc[mi][ni] = __builtin_amdgcn_mfma_f32_16x16x32_bf16(av[mi], bh[ni], acc[mi][ni], 0, 0, 0);
          acc[mi][ni] = __builtin_amdgcn_mfma_f32_16x16x32_bf16(av[mi], bl[ni], acc[mi][ni], 0, 0, 0);
        }
    }
    __syncthreads();
  }

  if (COUT == 2) {
    int obj = (m_base + m0) >> 10;
    #pragma unroll
    for (int ni = 0; ni < 4; ++ni) {
      int n = n0 + wn * 64 + ni * 16 + l15;
      float v = acc[0][ni][0];
      #pragma unroll
      for (int mi = 0; mi < 4; ++mi)
        #pragma unroll
        for (int i = 0; i < 4; ++i)
          v = fmaxf(v, acc[mi][ni][i]);
      v = fmaxf(v + bias[n], 0.0f);
      v = fmaxf(v, __shfl_xor(v, 16));
      v = fmaxf(v, __shfl_xor(v, 32));
      if (l4 == 0)
        atomicMax(&Omax[(size_t)obj * 512 + n], __float_as_uint(v));
    }
  } else {
    float* Bf = (float*)smb;
    float* Cf = (float*)Cdst;
    #pragma unroll
    for (int h = 0; h < 2; ++h) {
      if (wm == h) {
        #pragma unroll
        for (int mi = 0; mi < 4; ++mi)
          #pragma unroll
          for (int i = 0; i < 4; ++i) {
            int lr2 = mi * 16 + l4 * 4 + i;
            #pragma unroll
            for (int ni = 0; ni < 4; ++ni) {
              int col = wn * 64 + ni * 16 + l15;
              int off = lr2 * 128 + (((col >> 2) ^ (lr2 & 7)) << 2) + (col & 3);
              Bf[off] = acc[mi][ni][i] + bias[n0 + col];
            }
          }
      }
      __syncthreads();
      #pragma unroll
      for (int s = 0; s < 8; ++s) {
        int p = tid * 8 + s;
        int row = p >> 5, ls = p & 31;
        f32x4 v = *reinterpret_cast<const f32x4*>(&Bf[row * 128 + ((ls ^ (row & 7)) << 2)]);
        *reinterpret_cast<f32x4*>(Cf + (size_t)(m0 + h * 64 + row) * ldc + n0 + ls * 4) = v;
      }
      __syncthreads();
    }
  }
}

// ---------------------------------------------------------------------------
// Per-point MLPs (f32 exact) -> relu'd bf16 planes: s2 [pt][64], h2 [pt][128].
// ---------------------------------------------------------------------------
__global__ __launch_bounds__(256)
void points_kernel(const float* __restrict__ obj6,
                   const float* __restrict__ sW0, const float* __restrict__ sb0,
                   const float* __restrict__ sW1, const float* __restrict__ sb1,
                   const float* __restrict__ dW0, const float* __restrict__ db0,
                   const float* __restrict__ dW1, const float* __restrict__ db1,
                   unsigned short* __restrict__ s2,
                   unsigned short* __restrict__ h2)
{
  __shared__ float sw0[96], sbb0[32], sw1[2048], sbb1[64];
  __shared__ float dw0[384], dbb0[64], dw1[8192], dbb1[128];
  int tid = threadIdx.x;
  for (int i = tid; i < 96; i += 256) sw0[i] = sW0[i];
  if (tid < 32) sbb0[tid] = sb0[tid];
  for (int i = tid; i < 2048; i += 256) sw1[i] = sW1[i];
  if (tid < 64) sbb1[tid] = sb1[tid];
  for (int i = tid; i < 384; i += 256) dw0[i] = dW0[i];
  if (tid < 64) dbb0[tid] = db0[tid];
  for (int i = tid; i < 8192; i += 256) dw1[i] = dW1[i];
  if (tid < 128) dbb1[tid] = db1[tid];
  __syncthreads();

  int pt = blockIdx.x * 256 + tid;
  const float* in = obj6 + (size_t)pt * 6;
  float c0 = in[0], c1 = in[1], c2 = in[2], c3 = in[3], c4 = in[4], c5 = in[5];

  {  // sparse (xyz only)
    float h1[32];
    #pragma unroll
    for (int j = 0; j < 32; ++j)
      h1[j] = fmaxf(c0 * sw0[j] + c1 * sw0[32 + j] + c2 * sw0[64 + j] + sbb0[j], 0.f);
    unsigned short* orow = s2 + (size_t)pt * 64;
    #pragma unroll
    for (int j8 = 0; j8 < 8; ++j8) {
      float a[8];
      #pragma unroll
      for (int e = 0; e < 8; ++e) a[e] = sbb1[j8 * 8 + e];
      #pragma unroll
      for (int i = 0; i < 32; ++i) {
        float hv = h1[i];
        #pragma unroll
        for (int e = 0; e < 8; ++e) a[e] += hv * sw1[i * 64 + j8 * 8 + e];
      }
      short8 o;
      #pragma unroll
      for (int e = 0; e < 8; ++e) o[e] = (short)f2bf(fmaxf(a[e], 0.f));
      *reinterpret_cast<short8*>(orow + j8 * 8) = o;
    }
  }

  {  // dense (all 6 dims)
    float h1[64];
    #pragma unroll
    for (int j = 0; j < 64; ++j) {
      float a = dbb0[j] + c0 * dw0[j] + c1 * dw0[64 + j] + c2 * dw0[128 + j]
              + c3 * dw0[192 + j] + c4 * dw0[256 + j] + c5 * dw0[320 + j];
      h1[j] = fmaxf(a, 0.f);
    }
    unsigned short* orow = h2 + (size_t)pt * 128;
    #pragma unroll
    for (int ch = 0; ch < 4; ++ch) {
      float a[32];
      #pragma unroll
      for (int e = 0; e < 32; ++e) a[e] = dbb1[ch * 32 + e];
      #pragma unroll 8
      for (int i = 0; i < 64; ++i) {
        float hv = h1[i];
        #pragma unroll
        for (int e = 0; e < 32; ++e) a[e] += hv * dw1[i * 128 + ch * 32 + e];
      }
      #pragma unroll
      for (int e8 = 0; e8 < 4; ++e8) {
        short8 o;
        #pragma unroll
        for (int e = 0; e < 8; ++e) o[e] = (short)f2bf(fmaxf(a[e8 * 8 + e], 0.f));
        *reinterpret_cast<short8*>(orow + ch * 32 + e8 * 8) = o;
      }
    }
  }
}

// ---------------------------------------------------------------------------
__global__ void transpose_split(const float* __restrict__ W, unsigned short* __restrict__ Wt,
                                int K, int N)
{
  int id = blockIdx.x * 256 + threadIdx.x;
  if (id >= K * N) return;
  int k = id / N, n = id - k * N;
  unsigned short h, l;
  split2(W[id], h, l);
  Wt[(size_t)n * 2 * K + k] = h;
  Wt[(size_t)n * 2 * K + K + k] = l;
}

__global__ void transpose_cast(const float* __restrict__ W, unsigned short* __restrict__ Wt,
                               int K, int N)
{
  int id = blockIdx.x * 256 + threadIdx.x;
  if (id >= K * N) return;
  int k = id / N, n = id - k * N;
  Wt[(size_t)n * K + k] = f2bf(W[id]);
}

__global__ void zero_kernel(unsigned int* __restrict__ p, int n)
{
  int id = blockIdx.x * 256 + threadIdx.x;
  if (id < n) p[id] = 0u;
}

__global__ void pn_pack_kernel(const float* __restrict__ pnf, unsigned short* __restrict__ pnp)
{
  int id = blockIdx.x * 256 + threadIdx.x;  // 851968
  int o = id >> 9, c = id & 511;
  int b = o / 52, n = o - b * 52;
  pnp[((size_t)(n * 32 + b) << 9) + c] = f2bf(pnf[id]);
}

// t1[r][c] = relu(G[(i*32+b)][c] + G[(j*32+b)][512+c] + bias[c]), r=(i*52+j)*32+b
__global__ __launch_bounds__(256)
void rel_combine_kernel(const float* __restrict__ G,
                        const float* __restrict__ bias, unsigned short* __restrict__ t1)
{
  int t = blockIdx.x * 256 + threadIdx.x;
  int r = t >> 6, c8 = (t & 63) << 3;
  int b = r & 31;
  int pair = r >> 5;
  int i = pair / 52;
  int j = pair - i * 52;
  const float* g1 = G + ((size_t)(i * 32 + b) << 10) + c8;
  const float* g2 = G + ((size_t)(j * 32 + b) << 10) + 512 + c8;
  short8 o;
  #pragma unroll
  for (int e = 0; e < 8; ++e)
    o[e] = (short)f2bf(fmaxf(g1[e] + g2[e] + bias[c8 + e], 0.f));
  *reinterpret_cast<short8*>(t1 + (size_t)r * 512 + c8) = o;
}

// ---------------------------------------------------------------------------
__global__ __launch_bounds__(256)
void objmlp_kernel(const float* __restrict__ obj,
                   const float* __restrict__ W0, const float* __restrict__ b0,
                   const float* __restrict__ W1, const float* __restrict__ b1,
                   const float* __restrict__ W2, const float* __restrict__ b2,
                   float* __restrict__ out)
{
  __shared__ float x[512];
  __shared__ float h1[128];
  __shared__ float h2[256];
  int tid = threadIdx.x;
  int r = blockIdx.x;
  int n = r >> 5, b = r & 31;
  int o = b * 52 + n;
  const float* xs = obj + (size_t)o * 512;
  x[tid] = xs[tid];
  x[tid + 256] = xs[tid + 256];
  __syncthreads();
  if (tid < 128) {
    float a = b0[tid];
    #pragma unroll 8
    for (int k = 0; k < 512; ++k) a += x[k] * W0[k * 128 + tid];
    h1[tid] = fmaxf(a, 0.f);
  }
  __syncthreads();
  {
    float a = b1[tid];
    #pragma unroll 8
    for (int k = 0; k < 128; ++k) a += h1[k] * W1[k * 256 + tid];
    h2[tid] = fmaxf(a, 0.f);
  }
  __syncthreads();
  for (int j = tid; j < 607; j += 256) {
    float a = b2[j];
    #pragma unroll 8
    for (int k = 0; k < 256; ++k) a += h2[k] * W2[k * 607 + j];
    out[(size_t)r * 607 + j] = a;
  }
}

// ---------------------------------------------------------------------------
extern "C" void kernel_launch(void* const* d_in, const int* in_sizes, int n_in,
                              void* d_out, int out_size, void* d_ws, size_t ws_size,
                              hipStream_t stream)
{
  const float* objects = (const float*)d_in[1];
  const float* de_W0 = (const float*)d_in[3];  const float* de_b0 = (const float*)d_in[4];
  const float* de_W1 = (const float*)d_in[5];  const float* de_b1 = (const float*)d_in[6];
  const float* de_W2 = (const float*)d_in[7];  const float* de_b2 = (const float*)d_in[8];
  const float* de_W3 = (const float*)d_in[9];  const float* de_b3 = (const float*)d_in[10];
  const float* de_W4 = (const float*)d_in[11]; const float* de_b4 = (const float*)d_in[12];
  const float* se_W0 = (const float*)d_in[13]; const float* se_b0 = (const float*)d_in[14];
  const float* se_W1 = (const float*)d_in[15]; const float* se_b1 = (const float*)d_in[16];
  const float* se_W2 = (const float*)d_in[17]; const float* se_b2 = (const float*)d_in[18];
  const float* om_W0 = (const float*)d_in[19]; const float* om_b0 = (const float*)d_in[20];
  const float* om_W1 = (const float*)d_in[21]; const float* om_b1 = (const float*)d_in[22];
  const float* om_W2 = (const float*)d_in[23]; const float* om_b2 = (const float*)d_in[24];
  const float* r1_W = (const float*)d_in[25];  const float* r1_b = (const float*)d_in[26];
  const float* r2_W = (const float*)d_in[27];  const float* r2_b = (const float*)d_in[28];
  const float* m1_W = (const float*)d_in[29];  const float* m1_b = (const float*)d_in[30];
  const float* m2_W = (const float*)d_in[31];  const float* m2_b = (const float*)d_in[32];
  (void)in_sizes; (void)n_in; (void)out_size;

  // allow 128 KiB dynamic LDS for gemmX (defensive; ignore errors)
  (void)hipFuncSetAttribute(reinterpret_cast<const void*>(&gemmX<0>),
                            hipFuncAttributeMaxDynamicSharedMemorySize, 131072);
  (void)hipFuncSetAttribute(reinterpret_cast<const void*>(&gemmX<1>),
                            hipFuncAttributeMaxDynamicSharedMemorySize, 131072);
  (void)hipFuncSetAttribute(reinterpret_cast<const void*>(&gemmX<2>),
                            hipFuncAttributeMaxDynamicSharedMemorySize, 131072);
  (void)hipFuncSetAttribute(reinterpret_cast<const void*>(&gemmX<3>),
                            hipFuncAttributeMaxDynamicSharedMemorySize, 131072);

  float* outf = (float*)d_out;
  float* out_obj = outf;                          // [52,32,607]
  float* out_rel = outf + 1010048;                // [52,52,32,512]
  float* out_multi = out_rel + 44302336;

  // ---- workspace ----
  char* ws = (char*)d_ws;
  size_t off = 0;
  auto alloc = [&](size_t bytes) -> void* {
    void* p = ws + off;
    off += (bytes + 255) & ~(size_t)255;
    return p;
  };
  unsigned short* wt_se2 = (unsigned short*)alloc((size_t)512 * 128 * 2);   // split
  unsigned short* wt_de2 = (unsigned short*)alloc((size_t)256 * 128 * 2);   // plane
  unsigned short* wt_de3 = (unsigned short*)alloc((size_t)512 * 256 * 2);   // plane
  unsigned short* wt_de4 = (unsigned short*)alloc((size_t)512 * 512 * 2);   // plane
  unsigned short* wt_g   = (unsigned short*)alloc((size_t)1024 * 1024 * 2); // split N=1024
  unsigned short* wt_r2  = (unsigned short*)alloc((size_t)512 * 512 * 2);   // plane
  unsigned short* wt_m1  = (unsigned short*)alloc((size_t)512 * 512 * 2);   // plane
  unsigned short* wt_m2  = (unsigned short*)alloc((size_t)512 * 512 * 2);   // plane
  float* Gbuf = (float*)alloc((size_t)1664 * 1024 * 4);                     // 6.8 MB
  size_t avail = (ws_size > off + 256) ? (ws_size - off - 256) : 0;
  int Tc = (int)(avail / 262144);        // t2 tiles: 256 rows x 512 bf16
  if (Tc < 1) Tc = 1;
  if (Tc > 338) Tc = 338;
  unsigned short* t2 = (unsigned short*)alloc((size_t)Tc * 262144);

  // ---- arena inside d_out (rel+multi, 354,418,688 B) ----
  char* arena = (char*)out_rel;
  unsigned int* pnmax   = (unsigned int*)(arena);              // 3.4 MB
  float*        obj_f32 = (float*)(arena + 3407872);           // 3.4 MB
  unsigned short* pn_p  = (unsigned short*)(arena + 6815744);  // 1.7 MB
  char* cbuf = arena + 8519680;
  const size_t PC = 131072;                                    // 13 chunks
  unsigned short* s2_c = (unsigned short*)(cbuf);                    // 16.8 MB
  unsigned short* h2_c = (unsigned short*)(cbuf + PC * 128);         // 33.6 MB
  unsigned short* h3_c = (unsigned short*)(cbuf + PC * 384);         // 67.1 MB
  unsigned short* h4_c = (unsigned short*)(cbuf + PC * 896);         // 134.2 MB
  unsigned short* t1  = (unsigned short*)out_multi;                  // 88.6 MB
  unsigned short* t1b = (unsigned short*)((char*)out_multi + 88604672); // 88.6 MB

  zero_kernel<<<(2 * 851968) / 256, 256, 0, stream>>>(pnmax, 2 * 851968);

  auto tsplit = [&](const float* W, unsigned short* Dst, int K, int N) {
    int n = K * N;
    transpose_split<<<(n + 255) / 256, 256, 0, stream>>>(W, Dst, K, N);
  };
  auto tcast = [&](const float* W, unsigned short* Dst, int K, int N) {
    int n = K * N;
    transpose_cast<<<(n + 255) / 256, 256, 0, stream>>>(W, Dst, K, N);
  };
  tsplit(se_W2, wt_se2, 64, 512);
  tcast(de_W2, wt_de2, 128, 256);
  tcast(de_W3, wt_de3, 256, 512);
  tcast(de_W4, wt_de4, 512, 512);
  tsplit(r1_W,             wt_g,              512, 512);
  tsplit(r1_W + 512 * 512, wt_g + 512 * 1024, 512, 512);
  tcast(r2_W,  wt_r2, 512, 512);
  tcast(m1_W,  wt_m1, 512, 512);
  tcast(m2_W,  wt_m2, 512, 512);

  // ---- point-cloud chains: 13 chunks x 128 objects (131,072 pts) ----
  for (int c = 0; c < 13; ++c) {
    int base = c * (int)PC;
    points_kernel<<<PC / 256, 256, 0, stream>>>(
        objects + (size_t)base * 6,
        se_W0, se_b0, se_W1, se_b1, de_W0, de_b0, de_W1, de_b1, s2_c, h2_c);
    gemm3<2><<<4 * (PC / 128), 256, 0, stream>>>(
        s2_c, wt_se2, se_b2, nullptr, pnmax, PC, 64, 512, 4, 1, base);
    gemmX<1><<<1 * (PC / 256), 512, 131072, stream>>>(
        h2_c, wt_de2, de_b2, h3_c, nullptr, nullptr, PC, 128, 256, 1, 1, 0);
    gemmX<1><<<2 * (PC / 256), 512, 131072, stream>>>(
        h3_c, wt_de3, de_b3, h4_c, nullptr, nullptr, PC, 256, 512, 2, 1, 0);
    gemmX<2><<<2 * (PC / 256), 512, 131072, stream>>>(
        h4_c, wt_de4, de_b4, nullptr, nullptr, (unsigned int*)obj_f32, PC, 512, 512, 2, 1, base);
  }

  pn_pack_kernel<<<851968 / 256, 256, 0, stream>>>((const float*)pnmax, pn_p);
  objmlp_kernel<<<1664, 256, 0, stream>>>(obj_f32, om_W0, om_b0, om_W1, om_b1,
                                          om_W2, om_b2, out_obj);

  // ---- relation chain ----
  zero_kernel<<<4, 256, 0, stream>>>((unsigned int*)t2, 1024);
  gemm3<0><<<13 * 8, 256, 0, stream>>>(
      pn_p, wt_g, (const float*)t2, Gbuf, nullptr, 1664, 512, 1024, 8, 0, 0);
  rel_combine_kernel<<<86528 * 64 / 256, 256, 0, stream>>>(Gbuf, r1_b, t1);
  // r2: t1 -> rel finals f32 + t1b relu bf16 (dual out); M=86528=338*256
  gemmX<3><<<338 * 2, 512, 131072, stream>>>(
      t1, wt_r2, r2_b, out_rel, t1b, nullptr, 86528, 512, 512, 2, 0, 0);
  // m1/m2 chunked through t2 (256-row tiles)
  for (int tb = 0; tb < 338; tb += Tc) {
    int tiles = (338 - tb < Tc) ? (338 - tb) : Tc;
    int rows = tiles * 256;
    size_t rb = (size_t)tb * 256 * 512;
    gemmX<1><<<tiles * 2, 512, 131072, stream>>>(
        t1b + rb, wt_m1, m1_b, t2, nullptr, nullptr, rows, 512, 512, 2, 0, 0);
    gemmX<0><<<tiles * 2, 512, 131072, stream>>>(
        t2, wt_m2, m2_b, out_multi + rb, nullptr, nullptr, rows, 512, 512, 2, 0, 0);
  }
}

// Round 11
// 3881.126 us; speedup vs baseline: 2.2641x; 1.0134x over previous
//
#include <hip/hip_runtime.h>
#include <stdint.h>

typedef __attribute__((ext_vector_type(8))) __bf16 bf16x8;
typedef __attribute__((ext_vector_type(4))) float f32x4;
typedef __attribute__((ext_vector_type(8))) short short8;

__device__ __forceinline__ unsigned short f2bf(float f) {
  unsigned int u = __float_as_uint(f);
  u += 0x7FFFu + ((u >> 16) & 1u);
  return (unsigned short)(u >> 16);
}
__device__ __forceinline__ float bf2f(unsigned short h) {
  return __uint_as_float((unsigned int)h << 16);
}
__device__ __forceinline__ void split2(float v, unsigned short& h, unsigned short& l) {
  h = f2bf(v);
  l = f2bf(v - bf2f(h));
}

#define WAITVM0 asm volatile("s_waitcnt vmcnt(0)" ::: "memory")
#define WAITVM4 asm volatile("s_waitcnt vmcnt(4)" ::: "memory")
#define WAITVM8 asm volatile("s_waitcnt vmcnt(8)" ::: "memory")

// ---------------------------------------------------------------------------
// gemmX: 256x256 tile, BK=32, 512 threads (8 waves 2Mx4N), per-wave 128x64.
// 4-buffer K-tile ring (4 x 32KB = 128KB dynamic LDS). Tile k top:
//   vmcnt(4*beyond) [counted, 0 only at last tile] ; s_barrier ; ds_reads(k)
//   ; STAGE(k+3) ; 32 MFMA (setprio-wrapped).
// LDS rows are 64B (32 shorts); read swizzle phys_slot = l4 ^ ((row>>1)&3)
// (2-way bank alias = free), inverse applied on staging source address.
// COUT: 0=f32 raw; 1=relu bf16 plane; 2=maxout->atomicMax; 3=dual f32+bf16.
// ---------------------------------------------------------------------------
template<int COUT, int K>
__global__ __launch_bounds__(512, 1)
void gemmX(const unsigned short* __restrict__ A,
           const unsigned short* __restrict__ Wt,
           const float* __restrict__ bias,
           void* __restrict__ Cdst, void* __restrict__ Cdst2,
           unsigned int* __restrict__ Omax,
           int M, int ldc, int ntn, int swz8, int m_base)
{
  extern __shared__ __align__(16) char smem[];   // 131072 B

  int bid = blockIdx.x;
  int mt, nt;
  if (swz8) {                       // requires Mtiles % 8 == 0
    int xcd = bid & 7;
    int slot = bid >> 3;
    nt = slot % ntn;
    mt = (slot / ntn) * 8 + xcd;
  } else {
    mt = bid / ntn;
    nt = bid - mt * ntn;
  }
  const int m0 = mt * 256, n0 = nt * 256;
  const int tid = threadIdx.x;
  const int lane = tid & 63;
  const int w = tid >> 6;           // wave 0..7
  const int wm = w >> 2, wn = w & 3;
  const int l15 = lane & 15, l4 = lane >> 4;

  // staging: per tile 2 A-ops + 2 B-ops per thread; op o covers 16 rows.
  const unsigned short* aSrc[2];
  const unsigned short* bSrc[2];
  #pragma unroll
  for (int o = 0; o < 2; ++o) {
    int ar = w * 32 + o * 16 + (lane >> 2);          // row within tile
    int sc = ((lane & 3) ^ ((ar >> 1) & 3)) * 8;     // inverse slot swizzle
    aSrc[o] = A + (size_t)(m0 + ar) * K + sc;
    bSrc[o] = Wt + (size_t)(n0 + ar) * K + sc;
  }

  f32x4 acc[8][4];
  #pragma unroll
  for (int a = 0; a < 8; ++a)
    #pragma unroll
    for (int b = 0; b < 4; ++b)
      acc[a][b] = (f32x4){0.f, 0.f, 0.f, 0.f};

  constexpr int NT = K / 32;

  auto STAGE = [&](int kt) {
    short* Ab = (short*)(smem + (size_t)(kt & 3) * 32768);
    short* Bb = Ab + 8192;
    int koff = kt * 32;
    #pragma unroll
    for (int o = 0; o < 2; ++o) {
      int rows = w * 32 + o * 16;
      __builtin_amdgcn_global_load_lds(aSrc[o] + koff, (void*)(Ab + rows * 32), 16, 0, 0);
      __builtin_amdgcn_global_load_lds(bSrc[o] + koff, (void*)(Bb + rows * 32), 16, 0, 0);
    }
  };

  // prologue: stage up to 3 tiles
  STAGE(0);
  if (NT > 1) STAGE(1);
  if (NT > 2) STAGE(2);

  #pragma unroll
  for (int kt = 0; kt < NT; ++kt) {
    const int beyond = (NT - 1 - kt < 2) ? (NT - 1 - kt) : 2;
    if (beyond == 0)      { WAITVM0; }
    else if (beyond == 1) { WAITVM4; }
    else                  { WAITVM8; }
    __builtin_amdgcn_sched_barrier(0);
    __builtin_amdgcn_s_barrier();
    __builtin_amdgcn_sched_barrier(0);

    short* Ab = (short*)(smem + (size_t)(kt & 3) * 32768);
    short* Bb = Ab + 8192;

    bf16x8 aF[8], bF[4];
    #pragma unroll
    for (int n = 0; n < 4; ++n) {
      int R = wn * 64 + n * 16 + l15;
      int ph = l4 ^ ((R >> 1) & 3);
      bF[n] = *reinterpret_cast<const bf16x8*>(Bb + R * 32 + ph * 8);
    }
    #pragma unroll
    for (int m = 0; m < 8; ++m) {
      int R = wm * 128 + m * 16 + l15;
      int ph = l4 ^ ((R >> 1) & 3);
      aF[m] = *reinterpret_cast<const bf16x8*>(Ab + R * 32 + ph * 8);
    }

    if (kt + 3 <= NT - 1) STAGE(kt + 3);

    __builtin_amdgcn_s_setprio(1);
    #pragma unroll
    for (int m = 0; m < 8; ++m)
      #pragma unroll
      for (int n = 0; n < 4; ++n)
        acc[m][n] = __builtin_amdgcn_mfma_f32_16x16x32_bf16(aF[m], bF[n], acc[m][n], 0, 0, 0);
    __builtin_amdgcn_s_setprio(0);
  }

  __syncthreads();   // full drain + fence before LDS is reused by epilogues

  if (COUT == 2) {
    int obj = (m_base + m0) >> 10;  // 256 rows within one 1024-pt object
    #pragma unroll
    for (int ni = 0; ni < 4; ++ni) {
      int n = n0 + wn * 64 + ni * 16 + l15;
      float v = acc[0][ni][0];
      #pragma unroll
      for (int mi = 0; mi < 8; ++mi)
        #pragma unroll
        for (int i = 0; i < 4; ++i)
          v = fmaxf(v, acc[mi][ni][i]);
      v = fmaxf(v + bias[n], 0.0f);
      v = fmaxf(v, __shfl_xor(v, 16));
      v = fmaxf(v, __shfl_xor(v, 32));
      if (l4 == 0)
        atomicMax(&Omax[(size_t)obj * 512 + n], __float_as_uint(v));
    }
    return;
  }
  if (COUT == 0 || COUT == 3) {
    // f32 bounce: [128][256] f32 = 128 KB, two wm half-passes
    float* Bf = (float*)smem;
    float* Cf = (float*)Cdst;
    #pragma unroll
    for (int h = 0; h < 2; ++h) {
      if (wm == h) {
        #pragma unroll
        for (int mi = 0; mi < 8; ++mi)
          #pragma unroll
          for (int i = 0; i < 4; ++i) {
            int row = mi * 16 + l4 * 4 + i;
            #pragma unroll
            for (int ni = 0; ni < 4; ++ni) {
              int col = wn * 64 + ni * 16 + l15;
              int sl = col >> 2;
              int ph = (sl & 56) | ((sl & 7) ^ (row & 7));
              Bf[row * 256 + ph * 4 + (col & 3)] = acc[mi][ni][i] + bias[n0 + col];
            }
          }
      }
      __syncthreads();
      #pragma unroll
      for (int s = 0; s < 16; ++s) {
        int p = s * 512 + tid;
        int row = p >> 6, sl = p & 63;
        int ph = (sl & 56) | ((sl & 7) ^ (row & 7));
        f32x4 v = *reinterpret_cast<const f32x4*>(&Bf[row * 256 + ph * 4]);
        *reinterpret_cast<f32x4*>(Cf + (size_t)(m0 + h * 128 + row) * ldc + n0 + sl * 4) = v;
      }
      __syncthreads();
    }
  }
  if (COUT == 1 || COUT == 3) {
    // bf16 bounce: [256][256] bf16 = 128 KB, one pass
    unsigned short* Bp = (unsigned short*)smem;
    unsigned short* Cp = (unsigned short*)(COUT == 3 ? Cdst2 : Cdst);
    #pragma unroll
    for (int mi = 0; mi < 8; ++mi)
      #pragma unroll
      for (int i = 0; i < 4; ++i) {
        int row = wm * 128 + mi * 16 + l4 * 4 + i;
        #pragma unroll
        for (int ni = 0; ni < 4; ++ni) {
          int col = wn * 64 + ni * 16 + l15;
          int sl = col >> 3;
          int ph = (sl & 24) | ((sl & 7) ^ (row & 7));
          Bp[row * 256 + ph * 8 + (col & 7)] = f2bf(fmaxf(acc[mi][ni][i] + bias[n0 + col], 0.f));
        }
      }
    __syncthreads();
    #pragma unroll
    for (int s = 0; s < 16; ++s) {
      int p = s * 512 + tid;
      int row = p >> 5, sl = p & 31;
      int ph = (sl & 24) | ((sl & 7) ^ (row & 7));
      short8 v = *reinterpret_cast<const short8*>(&Bp[row * 256 + ph * 8]);
      *reinterpret_cast<short8*>(Cp + (size_t)(m0 + row) * ldc + n0 + sl * 8) = v;
    }
  }
}

// ---------------------------------------------------------------------------
// gemm3: split-2 GEMM (W hi+lo planes), BK=64, SM[3][128][64]=48KB.
// Used only for the G factor GEMM (f32-grade W, COUT=0 f32 out).
// ---------------------------------------------------------------------------
__global__ __launch_bounds__(256)
void gemm3(const unsigned short* __restrict__ A,
           const unsigned short* __restrict__ Wt,
           const float* __restrict__ bias,
           void* __restrict__ Cdst,
           int M, int K, int ldc, int ntn)
{
  __shared__ __align__(16) short SM[3][128][64];

  int bid = blockIdx.x;
  int mt = bid / ntn, nt = bid - mt * ntn;
  const int m0 = mt * 128, n0 = nt * 128;
  const int tid = threadIdx.x;
  const int lane = tid & 63;
  const int wave = tid >> 6;
  const int wm = wave >> 1, wn = wave & 1;
  const int l15 = lane & 15, l4 = lane >> 4;

  const int rr = tid >> 3;
  const int sp = tid & 7;
  const int sl = sp ^ (rr & 7);
  const int slE = sl * 8;

  const unsigned short* a_p[4];
  const unsigned short* b_p[4];
  #pragma unroll
  for (int c = 0; c < 4; ++c) {
    int rt = c * 32 + rr;
    a_p[c] = A + (size_t)(m0 + rt) * K + slE;
    b_p[c] = Wt + (size_t)(n0 + rt) * 2 * K + slE;
  }

  f32x4 acc[4][4];
  #pragma unroll
  for (int a = 0; a < 4; ++a)
    #pragma unroll
    for (int b = 0; b < 4; ++b)
      acc[a][b] = (f32x4){0.f, 0.f, 0.f, 0.f};

  char* const smb = (char*)&SM[0][0][0];

  for (int k0 = 0; k0 < K; k0 += 64) {
    #pragma unroll
    for (int c = 0; c < 4; ++c) {
      char* lb = smb + c * 4096 + (tid & 192) * 16;
      __builtin_amdgcn_global_load_lds(a_p[c] + k0, (void*)lb, 16, 0, 0);
      __builtin_amdgcn_global_load_lds(b_p[c] + k0, (void*)(lb + 16384), 16, 0, 0);
      __builtin_amdgcn_global_load_lds(b_p[c] + K + k0, (void*)(lb + 32768), 16, 0, 0);
    }
    __syncthreads();
    #pragma unroll
    for (int kf = 0; kf < 2; ++kf) {
      bf16x8 av[4], bh[4], bl[4];
      #pragma unroll
      for (int mi = 0; mi < 4; ++mi) {
        int R = wm * 64 + mi * 16 + l15;
        int sph = (kf * 4 + l4) ^ (R & 7);
        av[mi] = *reinterpret_cast<const bf16x8*>(&SM[0][R][sph * 8]);
      }
      #pragma unroll
      for (int ni = 0; ni < 4; ++ni) {
        int R = wn * 64 + ni * 16 + l15;
        int sph = (kf * 4 + l4) ^ (R & 7);
        bh[ni] = *reinterpret_cast<const bf16x8*>(&SM[1][R][sph * 8]);
        bl[ni] = *reinterpret_cast<const bf16x8*>(&SM[2][R][sph * 8]);
      }
      #pragma unroll
      for (int mi = 0; mi < 4; ++mi)
        #pragma unroll
        for (int ni = 0; ni < 4; ++ni) {
          acc[mi][ni] = __builtin_amdgcn_mfma_f32_16x16x32_bf16(av[mi], bh[ni], acc[mi][ni], 0, 0, 0);
          acc[mi][ni] = __builtin_amdgcn_mfma_f32_16x16x32_bf16(av[mi], bl[ni], acc[mi][ni], 0, 0, 0);
        }
    }
    __syncthreads();
  }

  float* Bf = (float*)smb;
  float* Cf = (float*)Cdst;
  #pragma unroll
  for (int h = 0; h < 2; ++h) {
    if (wm == h) {
      #pragma unroll
      for (int mi = 0; mi < 4; ++mi)
        #pragma unroll
        for (int i = 0; i < 4; ++i) {
          int lr2 = mi * 16 + l4 * 4 + i;
          #pragma unroll
          for (int ni = 0; ni < 4; ++ni) {
            int col = wn * 64 + ni * 16 + l15;
            int off = lr2 * 128 + (((col >> 2) ^ (lr2 & 7)) << 2) + (col & 3);
            Bf[off] = acc[mi][ni][i] + bias[n0 + col];
          }
        }
    }
    __syncthreads();
    #pragma unroll
    for (int s = 0; s < 8; ++s) {
      int p = tid * 8 + s;
      int row = p >> 5, ls = p & 31;
      f32x4 v = *reinterpret_cast<const f32x4*>(&Bf[row * 128 + ((ls ^ (row & 7)) << 2)]);
      *reinterpret_cast<f32x4*>(Cf + (size_t)(m0 + h * 64 + row) * ldc + n0 + ls * 4) = v;
    }
    __syncthreads();
  }
}

// ---------------------------------------------------------------------------
// Per-point MLPs (f32 exact) -> relu'd bf16 planes: s2 [pt][64], h2 [pt][128].
// ---------------------------------------------------------------------------
__global__ __launch_bounds__(256)
void points_kernel(const float* __restrict__ obj6,
                   const float* __restrict__ sW0, const float* __restrict__ sb0,
                   const float* __restrict__ sW1, const float* __restrict__ sb1,
                   const float* __restrict__ dW0, const float* __restrict__ db0,
                   const float* __restrict__ dW1, const float* __restrict__ db1,
                   unsigned short* __restrict__ s2,
                   unsigned short* __restrict__ h2)
{
  __shared__ float sw0[96], sbb0[32], sw1[2048], sbb1[64];
  __shared__ float dw0[384], dbb0[64], dw1[8192], dbb1[128];
  int tid = threadIdx.x;
  for (int i = tid; i < 96; i += 256) sw0[i] = sW0[i];
  if (tid < 32) sbb0[tid] = sb0[tid];
  for (int i = tid; i < 2048; i += 256) sw1[i] = sW1[i];
  if (tid < 64) sbb1[tid] = sb1[tid];
  for (int i = tid; i < 384; i += 256) dw0[i] = dW0[i];
  if (tid < 64) dbb0[tid] = db0[tid];
  for (int i = tid; i < 8192; i += 256) dw1[i] = dW1[i];
  if (tid < 128) dbb1[tid] = db1[tid];
  __syncthreads();

  int pt = blockIdx.x * 256 + tid;
  const float* in = obj6 + (size_t)pt * 6;
  float c0 = in[0], c1 = in[1], c2 = in[2], c3 = in[3], c4 = in[4], c5 = in[5];

  {  // sparse (xyz only)
    float h1[32];
    #pragma unroll
    for (int j = 0; j < 32; ++j)
      h1[j] = fmaxf(c0 * sw0[j] + c1 * sw0[32 + j] + c2 * sw0[64 + j] + sbb0[j], 0.f);
    unsigned short* orow = s2 + (size_t)pt * 64;
    #pragma unroll
    for (int j8 = 0; j8 < 8; ++j8) {
      float a[8];
      #pragma unroll
      for (int e = 0; e < 8; ++e) a[e] = sbb1[j8 * 8 + e];
      #pragma unroll
      for (int i = 0; i < 32; ++i) {
        float hv = h1[i];
        #pragma unroll
        for (int e = 0; e < 8; ++e) a[e] += hv * sw1[i * 64 + j8 * 8 + e];
      }
      short8 o;
      #pragma unroll
      for (int e = 0; e < 8; ++e) o[e] = (short)f2bf(fmaxf(a[e], 0.f));
      *reinterpret_cast<short8*>(orow + j8 * 8) = o;
    }
  }

  {  // dense (all 6 dims)
    float h1[64];
    #pragma unroll
    for (int j = 0; j < 64; ++j) {
      float a = dbb0[j] + c0 * dw0[j] + c1 * dw0[64 + j] + c2 * dw0[128 + j]
              + c3 * dw0[192 + j] + c4 * dw0[256 + j] + c5 * dw0[320 + j];
      h1[j] = fmaxf(a, 0.f);
    }
    unsigned short* orow = h2 + (size_t)pt * 128;
    #pragma unroll
    for (int ch = 0; ch < 4; ++ch) {
      float a[32];
      #pragma unroll
      for (int e = 0; e < 32; ++e) a[e] = dbb1[ch * 32 + e];
      #pragma unroll 8
      for (int i = 0; i < 64; ++i) {
        float hv = h1[i];
        #pragma unroll
        for (int e = 0; e < 32; ++e) a[e] += hv * dw1[i * 128 + ch * 32 + e];
      }
      #pragma unroll
      for (int e8 = 0; e8 < 4; ++e8) {
        short8 o;
        #pragma unroll
        for (int e = 0; e < 8; ++e) o[e] = (short)f2bf(fmaxf(a[e8 * 8 + e], 0.f));
        *reinterpret_cast<short8*>(orow + ch * 32 + e8 * 8) = o;
      }
    }
  }
}

// ---------------------------------------------------------------------------
__global__ void transpose_split(const float* __restrict__ W, unsigned short* __restrict__ Wt,
                                int K, int N)
{
  int id = blockIdx.x * 256 + threadIdx.x;
  if (id >= K * N) return;
  int k = id / N, n = id - k * N;
  unsigned short h, l;
  split2(W[id], h, l);
  Wt[(size_t)n * 2 * K + k] = h;
  Wt[(size_t)n * 2 * K + K + k] = l;
}

__global__ void transpose_cast(const float* __restrict__ W, unsigned short* __restrict__ Wt,
                               int K, int N)
{
  int id = blockIdx.x * 256 + threadIdx.x;
  if (id >= K * N) return;
  int k = id / N, n = id - k * N;
  Wt[(size_t)n * K + k] = f2bf(W[id]);
}

__global__ void zero_kernel(unsigned int* __restrict__ p, int n)
{
  int id = blockIdx.x * 256 + threadIdx.x;
  if (id < n) p[id] = 0u;
}

__global__ void pn_pack_kernel(const float* __restrict__ pnf, unsigned short* __restrict__ pnp)
{
  int id = blockIdx.x * 256 + threadIdx.x;  // 851968
  int o = id >> 9, c = id & 511;
  int b = o / 52, n = o - b * 52;
  pnp[((size_t)(n * 32 + b) << 9) + c] = f2bf(pnf[id]);
}

// t1[r][c] = relu(G[(i*32+b)][c] + G[(j*32+b)][512+c] + bias[c]), r=(i*52+j)*32+b
__global__ __launch_bounds__(256)
void rel_combine_kernel(const float* __restrict__ G,
                        const float* __restrict__ bias, unsigned short* __restrict__ t1)
{
  int t = blockIdx.x * 256 + threadIdx.x;
  int r = t >> 6, c8 = (t & 63) << 3;
  int b = r & 31;
  int pair = r >> 5;
  int i = pair / 52;
  int j = pair - i * 52;
  const float* g1 = G + ((size_t)(i * 32 + b) << 10) + c8;
  const float* g2 = G + ((size_t)(j * 32 + b) << 10) + 512 + c8;
  short8 o;
  #pragma unroll
  for (int e = 0; e < 8; ++e)
    o[e] = (short)f2bf(fmaxf(g1[e] + g2[e] + bias[c8 + e], 0.f));
  *reinterpret_cast<short8*>(t1 + (size_t)r * 512 + c8) = o;
}

// ---------------------------------------------------------------------------
__global__ __launch_bounds__(256)
void objmlp_kernel(const float* __restrict__ obj,
                   const float* __restrict__ W0, const float* __restrict__ b0,
                   const float* __restrict__ W1, const float* __restrict__ b1,
                   const float* __restrict__ W2, const float* __restrict__ b2,
                   float* __restrict__ out)
{
  __shared__ float x[512];
  __shared__ float h1[128];
  __shared__ float h2[256];
  int tid = threadIdx.x;
  int r = blockIdx.x;
  int n = r >> 5, b = r & 31;
  int o = b * 52 + n;
  const float* xs = obj + (size_t)o * 512;
  x[tid] = xs[tid];
  x[tid + 256] = xs[tid + 256];
  __syncthreads();
  if (tid < 128) {
    float a = b0[tid];
    #pragma unroll 8
    for (int k = 0; k < 512; ++k) a += x[k] * W0[k * 128 + tid];
    h1[tid] = fmaxf(a, 0.f);
  }
  __syncthreads();
  {
    float a = b1[tid];
    #pragma unroll 8
    for (int k = 0; k < 128; ++k) a += h1[k] * W1[k * 256 + tid];
    h2[tid] = fmaxf(a, 0.f);
  }
  __syncthreads();
  for (int j = tid; j < 607; j += 256) {
    float a = b2[j];
    #pragma unroll 8
    for (int k = 0; k < 256; ++k) a += h2[k] * W2[k * 607 + j];
    out[(size_t)r * 607 + j] = a;
  }
}

// ---------------------------------------------------------------------------
extern "C" void kernel_launch(void* const* d_in, const int* in_sizes, int n_in,
                              void* d_out, int out_size, void* d_ws, size_t ws_size,
                              hipStream_t stream)
{
  const float* objects = (const float*)d_in[1];
  const float* de_W0 = (const float*)d_in[3];  const float* de_b0 = (const float*)d_in[4];
  const float* de_W1 = (const float*)d_in[5];  const float* de_b1 = (const float*)d_in[6];
  const float* de_W2 = (const float*)d_in[7];  const float* de_b2 = (const float*)d_in[8];
  const float* de_W3 = (const float*)d_in[9];  const float* de_b3 = (const float*)d_in[10];
  const float* de_W4 = (const float*)d_in[11]; const float* de_b4 = (const float*)d_in[12];
  const float* se_W0 = (const float*)d_in[13]; const float* se_b0 = (const float*)d_in[14];
  const float* se_W1 = (const float*)d_in[15]; const float* se_b1 = (const float*)d_in[16];
  const float* se_W2 = (const float*)d_in[17]; const float* se_b2 = (const float*)d_in[18];
  const float* om_W0 = (const float*)d_in[19]; const float* om_b0 = (const float*)d_in[20];
  const float* om_W1 = (const float*)d_in[21]; const float* om_b1 = (const float*)d_in[22];
  const float* om_W2 = (const float*)d_in[23]; const float* om_b2 = (const float*)d_in[24];
  const float* r1_W = (const float*)d_in[25];  const float* r1_b = (const float*)d_in[26];
  const float* r2_W = (const float*)d_in[27];  const float* r2_b = (const float*)d_in[28];
  const float* m1_W = (const float*)d_in[29];  const float* m1_b = (const float*)d_in[30];
  const float* m2_W = (const float*)d_in[31];  const float* m2_b = (const float*)d_in[32];
  (void)in_sizes; (void)n_in; (void)out_size;

  (void)hipFuncSetAttribute(reinterpret_cast<const void*>(&gemmX<1, 128>),
                            hipFuncAttributeMaxDynamicSharedMemorySize, 131072);
  (void)hipFuncSetAttribute(reinterpret_cast<const void*>(&gemmX<1, 256>),
                            hipFuncAttributeMaxDynamicSharedMemorySize, 131072);
  (void)hipFuncSetAttribute(reinterpret_cast<const void*>(&gemmX<2, 512>),
                            hipFuncAttributeMaxDynamicSharedMemorySize, 131072);
  (void)hipFuncSetAttribute(reinterpret_cast<const void*>(&gemmX<2, 64>),
                            hipFuncAttributeMaxDynamicSharedMemorySize, 131072);
  (void)hipFuncSetAttribute(reinterpret_cast<const void*>(&gemmX<3, 512>),
                            hipFuncAttributeMaxDynamicSharedMemorySize, 131072);
  (void)hipFuncSetAttribute(reinterpret_cast<const void*>(&gemmX<1, 512>),
                            hipFuncAttributeMaxDynamicSharedMemorySize, 131072);
  (void)hipFuncSetAttribute(reinterpret_cast<const void*>(&gemmX<0, 512>),
                            hipFuncAttributeMaxDynamicSharedMemorySize, 131072);

  float* outf = (float*)d_out;
  float* out_obj = outf;                          // [52,32,607]
  float* out_rel = outf + 1010048;                // [52,52,32,512]
  float* out_multi = out_rel + 44302336;

  // ---- workspace ----
  char* ws = (char*)d_ws;
  size_t off = 0;
  auto alloc = [&](size_t bytes) -> void* {
    void* p = ws + off;
    off += (bytes + 255) & ~(size_t)255;
    return p;
  };
  unsigned short* wt_se2 = (unsigned short*)alloc((size_t)512 * 64 * 2);    // plane
  unsigned short* wt_de2 = (unsigned short*)alloc((size_t)256 * 128 * 2);   // plane
  unsigned short* wt_de3 = (unsigned short*)alloc((size_t)512 * 256 * 2);   // plane
  unsigned short* wt_de4 = (unsigned short*)alloc((size_t)512 * 512 * 2);   // plane
  unsigned short* wt_g   = (unsigned short*)alloc((size_t)1024 * 1024 * 2); // split N=1024
  unsigned short* wt_r2  = (unsigned short*)alloc((size_t)512 * 512 * 2);   // plane
  unsigned short* wt_m1  = (unsigned short*)alloc((size_t)512 * 512 * 2);   // plane
  unsigned short* wt_m2  = (unsigned short*)alloc((size_t)512 * 512 * 2);   // plane
  float* Gbuf = (float*)alloc((size_t)1664 * 1024 * 4);                     // 6.8 MB
  size_t avail = (ws_size > off + 256) ? (ws_size - off - 256) : 0;
  int Tc = (int)(avail / 262144);        // t2 tiles: 256 rows x 512 bf16
  if (Tc < 1) Tc = 1;
  if (Tc > 338) Tc = 338;
  unsigned short* t2 = (unsigned short*)alloc((size_t)Tc * 262144);

  // ---- arena inside d_out (rel+multi, 354,418,688 B) ----
  char* arena = (char*)out_rel;
  unsigned int* pnmax   = (unsigned int*)(arena);              // 3.4 MB
  float*        obj_f32 = (float*)(arena + 3407872);           // 3.4 MB
  unsigned short* pn_p  = (unsigned short*)(arena + 6815744);  // 1.7 MB
  char* cbuf = arena + 8519680;
  const size_t PC = 131072;                                    // 13 chunks
  unsigned short* s2_c = (unsigned short*)(cbuf);                    // 16.8 MB
  unsigned short* h2_c = (unsigned short*)(cbuf + PC * 128);         // 33.6 MB
  unsigned short* h3_c = (unsigned short*)(cbuf + PC * 384);         // 67.1 MB
  unsigned short* h4_c = (unsigned short*)(cbuf + PC * 896);         // 134.2 MB
  unsigned short* t1  = (unsigned short*)out_multi;                  // 88.6 MB
  unsigned short* t1b = (unsigned short*)((char*)out_multi + 88604672); // 88.6 MB

  zero_kernel<<<(2 * 851968) / 256, 256, 0, stream>>>(pnmax, 2 * 851968);

  auto tsplit = [&](const float* W, unsigned short* Dst, int K, int N) {
    int n = K * N;
    transpose_split<<<(n + 255) / 256, 256, 0, stream>>>(W, Dst, K, N);
  };
  auto tcast = [&](const float* W, unsigned short* Dst, int K, int N) {
    int n = K * N;
    transpose_cast<<<(n + 255) / 256, 256, 0, stream>>>(W, Dst, K, N);
  };
  tcast(se_W2, wt_se2, 64, 512);
  tcast(de_W2, wt_de2, 128, 256);
  tcast(de_W3, wt_de3, 256, 512);
  tcast(de_W4, wt_de4, 512, 512);
  tsplit(r1_W,             wt_g,              512, 512);
  tsplit(r1_W + 512 * 512, wt_g + 512 * 1024, 512, 512);
  tcast(r2_W,  wt_r2, 512, 512);
  tcast(m1_W,  wt_m1, 512, 512);
  tcast(m2_W,  wt_m2, 512, 512);

  // ---- point-cloud chains: 13 chunks x 128 objects (131,072 pts) ----
  for (int c = 0; c < 13; ++c) {
    int base = c * (int)PC;
    points_kernel<<<PC / 256, 256, 0, stream>>>(
        objects + (size_t)base * 6,
        se_W0, se_b0, se_W1, se_b1, de_W0, de_b0, de_W1, de_b1, s2_c, h2_c);
    gemmX<2, 64><<<2 * (PC / 256), 512, 131072, stream>>>(
        s2_c, wt_se2, se_b2, nullptr, nullptr, pnmax, PC, 512, 2, 1, base);
    gemmX<1, 128><<<1 * (PC / 256), 512, 131072, stream>>>(
        h2_c, wt_de2, de_b2, h3_c, nullptr, nullptr, PC, 256, 1, 1, 0);
    gemmX<1, 256><<<2 * (PC / 256), 512, 131072, stream>>>(
        h3_c, wt_de3, de_b3, h4_c, nullptr, nullptr, PC, 512, 2, 1, 0);
    gemmX<2, 512><<<2 * (PC / 256), 512, 131072, stream>>>(
        h4_c, wt_de4, de_b4, nullptr, nullptr, (unsigned int*)obj_f32, PC, 512, 2, 1, base);
  }

  pn_pack_kernel<<<851968 / 256, 256, 0, stream>>>((const float*)pnmax, pn_p);
  objmlp_kernel<<<1664, 256, 0, stream>>>(obj_f32, om_W0, om_b0, om_W1, om_b1,
                                          om_W2, om_b2, out_obj);

  // ---- relation chain ----
  // G = pn @ [W_top | W_bot]  (M=1664, N=1024, split-2 W, f32 out; zero bias)
  zero_kernel<<<4, 256, 0, stream>>>((unsigned int*)t2, 1024);
  gemm3<<<13 * 8, 256, 0, stream>>>(
      pn_p, wt_g, (const float*)t2, Gbuf, 1664, 512, 1024, 8);
  rel_combine_kernel<<<86528 * 64 / 256, 256, 0, stream>>>(Gbuf, r1_b, t1);
  // r2: t1 -> rel finals f32 + t1b relu bf16 (dual out); M=86528=338*256
  gemmX<3, 512><<<338 * 2, 512, 131072, stream>>>(
      t1, wt_r2, r2_b, out_rel, t1b, nullptr, 86528, 512, 2, 0, 0);
  // m1/m2 chunked through t2 (256-row tiles)
  for (int tb = 0; tb < 338; tb += Tc) {
    int tiles = (338 - tb < Tc) ? (338 - tb) : Tc;
    int rows = tiles * 256;
    size_t rb = (size_t)tb * 256 * 512;
    gemmX<1, 512><<<tiles * 2, 512, 131072, stream>>>(
        t1b + rb, wt_m1, m1_b, t2, nullptr, nullptr, rows, 512, 2, 0, 0);
    gemmX<0, 512><<<tiles * 2, 512, 131072, stream>>>(
        t2, wt_m2, m2_b, out_multi + rb, nullptr, nullptr, rows, 512, 2, 0, 0);
  }
}

// Round 12
// 3598.198 us; speedup vs baseline: 2.4421x; 1.0786x over previous
//
#include <hip/hip_runtime.h>
#include <stdint.h>

typedef __attribute__((ext_vector_type(8))) __bf16 bf16x8;
typedef __attribute__((ext_vector_type(4))) float f32x4;
typedef __attribute__((ext_vector_type(8))) short short8;

__device__ __forceinline__ unsigned short f2bf(float f) {
  unsigned int u = __float_as_uint(f);
  u += 0x7FFFu + ((u >> 16) & 1u);
  return (unsigned short)(u >> 16);
}
__device__ __forceinline__ float bf2f(unsigned short h) {
  return __uint_as_float((unsigned int)h << 16);
}
__device__ __forceinline__ void split2(float v, unsigned short& h, unsigned short& l) {
  h = f2bf(v);
  l = f2bf(v - bf2f(h));
}

#define WAITVM0 asm volatile("s_waitcnt vmcnt(0)" ::: "memory")
#define WAITVM4 asm volatile("s_waitcnt vmcnt(4)" ::: "memory")
#define WAITVM5 asm volatile("s_waitcnt vmcnt(5)" ::: "memory")
#define WAITVM8 asm volatile("s_waitcnt vmcnt(8)" ::: "memory")
#define LGKM0   asm volatile("s_waitcnt lgkmcnt(0)" ::: "memory")
#define SCHED0  __builtin_amdgcn_sched_barrier(0)

// ---------------------------------------------------------------------------
// gemmF: fused multi-layer GEMM chain. Block = 512 thr (8 waves 1x8),
// M_b = 128 rows, N = 512. Inter-layer activation C lives in LDS "Cbuf"
// (16 segments x [128][32] bf16, slot-swizzled = A-fragment layout).
// VAR 0 (dense): phase1 de3 (K=256, A=h3 global, ring-3) -> C; phase2 de4
//   (K=512, A=Cbuf, per-wave B) -> maxout atomic.
// VAR 1 (rel): phase1 r2 (K=512, A synthesized from G on the fly) -> f32
//   out1 + C; phase2 m1 -> C'; phase3 m2 -> f32 out3.
// ---------------------------------------------------------------------------
template<int VAR>
__global__ __launch_bounds__(512, 1)
void gemmF(const unsigned short* __restrict__ Ag,
           const float* __restrict__ G, const float* __restrict__ gb,
           const unsigned short* __restrict__ W1t, const float* __restrict__ b1,
           const unsigned short* __restrict__ W2t, const float* __restrict__ b2,
           const unsigned short* __restrict__ W3t, const float* __restrict__ b3,
           float* __restrict__ out1, float* __restrict__ out3,
           unsigned int* __restrict__ Omax, int m_base)
{
  extern __shared__ __align__(16) char smem[];   // 163840 B
  short* SS = (short*)smem;
  const int tid = threadIdx.x, lane = tid & 63, w = tid >> 6;
  const int l15 = lane & 15, l4 = lane >> 4;
  const int m0 = blockIdx.x * 128;
  constexpr int K1 = VAR ? 512 : 256;
  constexpr int NT1 = K1 / 32;

  f32x4 acc[8][4];
  #pragma unroll
  for (int a = 0; a < 8; ++a)
    #pragma unroll
    for (int b = 0; b < 4; ++b)
      acc[a][b] = (f32x4){0.f, 0.f, 0.f, 0.f};

  auto MFMA32 = [&](bf16x8* aF, bf16x8* bF) {
    __builtin_amdgcn_s_setprio(1);
    #pragma unroll
    for (int m = 0; m < 8; ++m)
      #pragma unroll
      for (int n = 0; n < 4; ++n)
        acc[m][n] = __builtin_amdgcn_mfma_f32_16x16x32_bf16(aF[m], bF[n], acc[m][n], 0, 0, 0);
    __builtin_amdgcn_s_setprio(0);
  };

  // scatter relu(acc+bias) into Cbuf (A-fragment layout, 16 segs x [128][32])
  auto scatterC = [&](const float* bias) {
    float bv[4];
    #pragma unroll
    for (int ni = 0; ni < 4; ++ni) bv[ni] = bias[w * 64 + ni * 16 + l15];
    #pragma unroll
    for (int mi = 0; mi < 8; ++mi)
      #pragma unroll
      for (int i = 0; i < 4; ++i) {
        int row = mi * 16 + l4 * 4 + i;
        #pragma unroll
        for (int ni = 0; ni < 4; ++ni) {
          int col = w * 64 + ni * 16 + l15;
          int c5 = col & 31;
          int ph = (c5 >> 3) ^ ((row >> 1) & 3);
          SS[(col >> 5) * 4096 + row * 32 + ph * 8 + (col & 7)] =
              (short)f2bf(fmaxf(acc[mi][i >> 2][0] * 0.f + acc[mi][ni][i] + bv[ni], 0.f));
        }
      }
  };

  // coalesced f32 store of acc+bias (no relu) via LDS bounce, 2 halves
  auto bounceOut = [&](float* dst, const float* bias) {
    float* Bf = (float*)smem;
    #pragma unroll
    for (int h = 0; h < 2; ++h) {
      if ((w >> 2) == h) {
        #pragma unroll
        for (int mi = 0; mi < 8; ++mi)
          #pragma unroll
          for (int i = 0; i < 4; ++i) {
            int row = mi * 16 + l4 * 4 + i;
            #pragma unroll
            for (int ni = 0; ni < 4; ++ni) {
              int colh = (w & 3) * 64 + ni * 16 + l15;
              int sl = colh >> 2;
              int ph = (sl & 56) | ((sl & 7) ^ (row & 7));
              Bf[row * 256 + ph * 4 + (colh & 3)] =
                  acc[mi][ni][i] + bias[w * 64 + ni * 16 + l15];
            }
          }
      }
      __syncthreads();
      #pragma unroll
      for (int s = 0; s < 16; ++s) {
        int p = s * 512 + tid;
        int row = p >> 6, sl = p & 63;
        int ph = (sl & 56) | ((sl & 7) ^ (row & 7));
        f32x4 v = *reinterpret_cast<const f32x4*>(&Bf[row * 256 + ph * 4]);
        *reinterpret_cast<f32x4*>(dst + (size_t)(m0 + row) * 512 + h * 256 + sl * 4) = v;
      }
      __syncthreads();
    }
  };

  // K=512 layer with A from Cbuf, per-wave single-buffered B (no barriers)
  auto ldsA_loop = [&](const unsigned short* Wt) {
    #pragma unroll
    for (int a = 0; a < 8; ++a)
      #pragma unroll
      for (int b = 0; b < 4; ++b)
        acc[a][b] = (f32x4){0.f, 0.f, 0.f, 0.f};
    short* myB = SS + 65536 + w * 2048;
    const unsigned short* bS[4];
    #pragma unroll
    for (int o = 0; o < 4; ++o) {
      int br = w * 64 + o * 16 + (lane >> 2);
      bS[o] = Wt + (size_t)br * 512 + (((lane & 3) ^ ((br >> 1) & 3)) * 8);
    }
    #pragma unroll
    for (int kt = 0; kt < 16; ++kt) {
      LGKM0; SCHED0;                      // prior myB ds_reads retired
      #pragma unroll
      for (int o = 0; o < 4; ++o)
        __builtin_amdgcn_global_load_lds(bS[o] + kt * 32, (void*)(myB + o * 512), 16, 0, 0);
      bf16x8 aF[8], bF[4];
      #pragma unroll
      for (int m = 0; m < 8; ++m) {       // A reads overlap B's L2 latency
        int R = m * 16 + l15;
        int ph = l4 ^ ((R >> 1) & 3);
        aF[m] = *reinterpret_cast<const bf16x8*>(SS + kt * 4096 + R * 32 + ph * 8);
      }
      WAITVM0; SCHED0;
      #pragma unroll
      for (int n = 0; n < 4; ++n) {
        int Rl = n * 16 + l15;
        int ph = l4 ^ ((Rl >> 1) & 3);
        bF[n] = *reinterpret_cast<const bf16x8*>(myB + Rl * 32 + ph * 8);
      }
      MFMA32(aF, bF);
    }
  };

  // ------------------- phase 1: A from global / synthesized -------------------
  const int arow = w * 16 + (lane >> 2);
  const unsigned short* aS = nullptr;
  const float *g1p = nullptr, *g2p = nullptr, *gbp = nullptr;
  if constexpr (VAR == 0) {
    aS = Ag + (size_t)(m0 + arow) * K1 + (((lane & 3) ^ ((arow >> 1) & 3)) * 8);
  } else {
    int r = m0 + arow;
    int b = r & 31, pr = r >> 5;
    int i = pr / 52, j = pr - i * 52;
    g1p = G + (size_t)(i * 32 + b) * 1024 + (lane & 3) * 8;
    g2p = G + (size_t)(j * 32 + b) * 1024 + 512 + (lane & 3) * 8;
    gbp = gb + (lane & 3) * 8;
  }
  const unsigned short* bS1[4];
  #pragma unroll
  for (int o = 0; o < 4; ++o) {
    int br = w * 64 + o * 16 + (lane >> 2);
    bS1[o] = W1t + (size_t)br * K1 + (((lane & 3) ^ ((br >> 1) & 3)) * 8);
  }
  auto stage1 = [&](int kt) {
    short* S = SS + (kt % 3) * 20480;
    if constexpr (VAR == 0) {
      __builtin_amdgcn_global_load_lds(aS + kt * 32, (void*)(S + w * 512), 16, 0, 0);
    } else {
      f32x4 q0 = *reinterpret_cast<const f32x4*>(g1p + kt * 32);
      f32x4 q1 = *reinterpret_cast<const f32x4*>(g1p + kt * 32 + 4);
      f32x4 p0 = *reinterpret_cast<const f32x4*>(g2p + kt * 32);
      f32x4 p1 = *reinterpret_cast<const f32x4*>(g2p + kt * 32 + 4);
      f32x4 c0 = *reinterpret_cast<const f32x4*>(gbp + kt * 32);
      f32x4 c1 = *reinterpret_cast<const f32x4*>(gbp + kt * 32 + 4);
      short8 hv;
      #pragma unroll
      for (int e = 0; e < 4; ++e) {
        hv[e]     = (short)f2bf(fmaxf(q0[e] + p0[e] + c0[e], 0.f));
        hv[4 + e] = (short)f2bf(fmaxf(q1[e] + p1[e] + c1[e], 0.f));
      }
      *reinterpret_cast<short8*>(S + arow * 32 + (((lane & 3) ^ ((arow >> 1) & 3)) * 8)) = hv;
    }
    #pragma unroll
    for (int o = 0; o < 4; ++o)
      __builtin_amdgcn_global_load_lds(bS1[o] + kt * 32,
                                       (void*)(S + 4096 + (w * 64 + o * 16) * 32), 16, 0, 0);
  };

  stage1(0);
  stage1(1);
  #pragma unroll
  for (int kt = 0; kt < NT1; ++kt) {
    LGKM0;
    if (kt < NT1 - 1) { if (VAR) { WAITVM4; } else { WAITVM5; } }
    else { WAITVM0; }
    SCHED0;
    __builtin_amdgcn_s_barrier();
    SCHED0;
    short* S = SS + (kt % 3) * 20480;
    bf16x8 aF[8], bF[4];
    #pragma unroll
    for (int n = 0; n < 4; ++n) {
      int R = w * 64 + n * 16 + l15;
      int ph = l4 ^ ((R >> 1) & 3);
      bF[n] = *reinterpret_cast<const bf16x8*>(S + 4096 + R * 32 + ph * 8);
    }
    #pragma unroll
    for (int m = 0; m < 8; ++m) {
      int R = m * 16 + l15;
      int ph = l4 ^ ((R >> 1) & 3);
      aF[m] = *reinterpret_cast<const bf16x8*>(S + R * 32 + ph * 8);
    }
    if (kt + 2 < NT1) stage1(kt + 2);
    MFMA32(aF, bF);
  }
  __syncthreads();

  if constexpr (VAR == 1) bounceOut(out1, b1);   // rel finals (raw +bias)
  scatterC(b1);                                  // C = relu(acc + b1)
  __syncthreads();

  // ------------------- phase 2 -------------------
  ldsA_loop(W2t);

  if constexpr (VAR == 0) {
    // fused maxout (de4): 128 rows within one object
    int obj = (m_base + m0) >> 10;
    #pragma unroll
    for (int ni = 0; ni < 4; ++ni) {
      int n = w * 64 + ni * 16 + l15;
      float v = acc[0][ni][0];
      #pragma unroll
      for (int mi = 0; mi < 8; ++mi)
        #pragma unroll
        for (int i = 0; i < 4; ++i)
          v = fmaxf(v, acc[mi][ni][i]);
      v = fmaxf(v + b2[n], 0.0f);
      v = fmaxf(v, __shfl_xor(v, 16));
      v = fmaxf(v, __shfl_xor(v, 32));
      if (l4 == 0)
        atomicMax(&Omax[(size_t)obj * 512 + n], __float_as_uint(v));
    }
    return;
  } else {
    __syncthreads();
    scatterC(b2);                                // C' = relu(m1 + b2)
    __syncthreads();
    ldsA_loop(W3t);                              // m2
    __syncthreads();
    bounceOut(out3, b3);                         // multi finals
  }
}

// ---------------------------------------------------------------------------
// gemmX: 256x256 tile, BK=32, 4-buffer ring, counted vmcnt (round-10 design).
// Used for se2 (K=64, maxout) and de2 (K=128, bf16-plane out).
// ---------------------------------------------------------------------------
template<int COUT, int K>
__global__ __launch_bounds__(512, 1)
void gemmX(const unsigned short* __restrict__ A,
           const unsigned short* __restrict__ Wt,
           const float* __restrict__ bias,
           void* __restrict__ Cdst,
           unsigned int* __restrict__ Omax,
           int ldc, int ntn, int swz8, int m_base)
{
  extern __shared__ __align__(16) char smem[];   // 131072 B

  int bid = blockIdx.x;
  int mt, nt;
  if (swz8) {
    int xcd = bid & 7;
    int slot = bid >> 3;
    nt = slot % ntn;
    mt = (slot / ntn) * 8 + xcd;
  } else {
    mt = bid / ntn;
    nt = bid - mt * ntn;
  }
  const int m0 = mt * 256, n0 = nt * 256;
  const int tid = threadIdx.x;
  const int lane = tid & 63;
  const int w = tid >> 6;
  const int wm = w >> 2, wn = w & 3;
  const int l15 = lane & 15, l4 = lane >> 4;

  const unsigned short* aSrc[2];
  const unsigned short* bSrc[2];
  #pragma unroll
  for (int o = 0; o < 2; ++o) {
    int ar = w * 32 + o * 16 + (lane >> 2);
    int sc = ((lane & 3) ^ ((ar >> 1) & 3)) * 8;
    aSrc[o] = A + (size_t)(m0 + ar) * K + sc;
    bSrc[o] = Wt + (size_t)(n0 + ar) * K + sc;
  }

  f32x4 acc[8][4];
  #pragma unroll
  for (int a = 0; a < 8; ++a)
    #pragma unroll
    for (int b = 0; b < 4; ++b)
      acc[a][b] = (f32x4){0.f, 0.f, 0.f, 0.f};

  constexpr int NT = K / 32;

  auto STAGE = [&](int kt) {
    short* Ab = (short*)(smem + (size_t)(kt & 3) * 32768);
    short* Bb = Ab + 8192;
    int koff = kt * 32;
    #pragma unroll
    for (int o = 0; o < 2; ++o) {
      int rows = w * 32 + o * 16;
      __builtin_amdgcn_global_load_lds(aSrc[o] + koff, (void*)(Ab + rows * 32), 16, 0, 0);
      __builtin_amdgcn_global_load_lds(bSrc[o] + koff, (void*)(Bb + rows * 32), 16, 0, 0);
    }
  };

  STAGE(0);
  if (NT > 1) STAGE(1);
  if (NT > 2) STAGE(2);

  #pragma unroll
  for (int kt = 0; kt < NT; ++kt) {
    const int beyond = (NT - 1 - kt < 2) ? (NT - 1 - kt) : 2;
    if (beyond == 0)      { WAITVM0; }
    else if (beyond == 1) { WAITVM4; }
    else                  { WAITVM8; }
    SCHED0;
    __builtin_amdgcn_s_barrier();
    SCHED0;

    short* Ab = (short*)(smem + (size_t)(kt & 3) * 32768);
    short* Bb = Ab + 8192;

    bf16x8 aF[8], bF[4];
    #pragma unroll
    for (int n = 0; n < 4; ++n) {
      int R = wn * 64 + n * 16 + l15;
      int ph = l4 ^ ((R >> 1) & 3);
      bF[n] = *reinterpret_cast<const bf16x8*>(&Bb[R * 32 + ph * 8]);
    }
    #pragma unroll
    for (int m = 0; m < 8; ++m) {
      int R = wm * 128 + m * 16 + l15;
      int ph = l4 ^ ((R >> 1) & 3);
      aF[m] = *reinterpret_cast<const bf16x8*>(&Ab[R * 32 + ph * 8]);
    }

    if (kt + 3 <= NT - 1) STAGE(kt + 3);

    __builtin_amdgcn_s_setprio(1);
    #pragma unroll
    for (int m = 0; m < 8; ++m)
      #pragma unroll
      for (int n = 0; n < 4; ++n)
        acc[m][n] = __builtin_amdgcn_mfma_f32_16x16x32_bf16(aF[m], bF[n], acc[m][n], 0, 0, 0);
    __builtin_amdgcn_s_setprio(0);
  }

  __syncthreads();

  if (COUT == 2) {
    int obj = (m_base + m0) >> 10;
    #pragma unroll
    for (int ni = 0; ni < 4; ++ni) {
      int n = n0 + wn * 64 + ni * 16 + l15;
      float v = acc[0][ni][0];
      #pragma unroll
      for (int mi = 0; mi < 8; ++mi)
        #pragma unroll
        for (int i = 0; i < 4; ++i)
          v = fmaxf(v, acc[mi][ni][i]);
      v = fmaxf(v + bias[n], 0.0f);
      v = fmaxf(v, __shfl_xor(v, 16));
      v = fmaxf(v, __shfl_xor(v, 32));
      if (l4 == 0)
        atomicMax(&Omax[(size_t)obj * 512 + n], __float_as_uint(v));
    }
    return;
  }
  // COUT==1: relu bf16 plane via [256][256] bounce
  unsigned short* Bp = (unsigned short*)smem;
  unsigned short* Cp = (unsigned short*)Cdst;
  #pragma unroll
  for (int mi = 0; mi < 8; ++mi)
    #pragma unroll
    for (int i = 0; i < 4; ++i) {
      int row = wm * 128 + mi * 16 + l4 * 4 + i;
      #pragma unroll
      for (int ni = 0; ni < 4; ++ni) {
        int col = wn * 64 + ni * 16 + l15;
        int sl = col >> 3;
        int ph = (sl & 24) | ((sl & 7) ^ (row & 7));
        Bp[row * 256 + ph * 8 + (col & 7)] = f2bf(fmaxf(acc[mi][ni][i] + bias[n0 + col], 0.f));
      }
    }
  __syncthreads();
  #pragma unroll
  for (int s = 0; s < 16; ++s) {
    int p = s * 512 + tid;
    int row = p >> 5, sl = p & 31;
    int ph = (sl & 24) | ((sl & 7) ^ (row & 7));
    short8 v = *reinterpret_cast<const short8*>(&Bp[row * 256 + ph * 8]);
    *reinterpret_cast<short8*>(Cp + (size_t)(m0 + row) * ldc + n0 + sl * 8) = v;
  }
}

// ---------------------------------------------------------------------------
// gemm3: split-2 GEMM (W hi+lo planes), BK=64. Only for the G factor GEMM.
// ---------------------------------------------------------------------------
__global__ __launch_bounds__(256)
void gemm3(const unsigned short* __restrict__ A,
           const unsigned short* __restrict__ Wt,
           const float* __restrict__ bias,
           void* __restrict__ Cdst,
           int M, int K, int ldc, int ntn)
{
  __shared__ __align__(16) short SM[3][128][64];

  int bid = blockIdx.x;
  int mt = bid / ntn, nt = bid - mt * ntn;
  const int m0 = mt * 128, n0 = nt * 128;
  const int tid = threadIdx.x;
  const int lane = tid & 63;
  const int wave = tid >> 6;
  const int wm = wave >> 1, wn = wave & 1;
  const int l15 = lane & 15, l4 = lane >> 4;

  const int rr = tid >> 3;
  const int sp = tid & 7;
  const int sl = sp ^ (rr & 7);
  const int slE = sl * 8;

  const unsigned short* a_p[4];
  const unsigned short* b_p[4];
  #pragma unroll
  for (int c = 0; c < 4; ++c) {
    int rt = c * 32 + rr;
    a_p[c] = A + (size_t)(m0 + rt) * K + slE;
    b_p[c] = Wt + (size_t)(n0 + rt) * 2 * K + slE;
  }

  f32x4 acc[4][4];
  #pragma unroll
  for (int a = 0; a < 4; ++a)
    #pragma unroll
    for (int b = 0; b < 4; ++b)
      acc[a][b] = (f32x4){0.f, 0.f, 0.f, 0.f};

  char* const smb = (char*)&SM[0][0][0];

  for (int k0 = 0; k0 < K; k0 += 64) {
    #pragma unroll
    for (int c = 0; c < 4; ++c) {
      char* lb = smb + c * 4096 + (tid & 192) * 16;
      __builtin_amdgcn_global_load_lds(a_p[c] + k0, (void*)lb, 16, 0, 0);
      __builtin_amdgcn_global_load_lds(b_p[c] + k0, (void*)(lb + 16384), 16, 0, 0);
      __builtin_amdgcn_global_load_lds(b_p[c] + K + k0, (void*)(lb + 32768), 16, 0, 0);
    }
    __syncthreads();
    #pragma unroll
    for (int kf = 0; kf < 2; ++kf) {
      bf16x8 av[4], bh[4], bl[4];
      #pragma unroll
      for (int mi = 0; mi < 4; ++mi) {
        int R = wm * 64 + mi * 16 + l15;
        int sph = (kf * 4 + l4) ^ (R & 7);
        av[mi] = *reinterpret_cast<const bf16x8*>(&SM[0][R][sph * 8]);
      }
      #pragma unroll
      for (int ni = 0; ni < 4; ++ni) {
        int R = wn * 64 + ni * 16 + l15;
        int sph = (kf * 4 + l4) ^ (R & 7);
        bh[ni] = *reinterpret_cast<const bf16x8*>(&SM[1][R][sph * 8]);
        bl[ni] = *reinterpret_cast<const bf16x8*>(&SM[2][R][sph * 8]);
      }
      #pragma unroll
      for (int mi = 0; mi < 4; ++mi)
        #pragma unroll
        for (int ni = 0; ni < 4; ++ni) {
          acc[mi][ni] = __builtin_amdgcn_mfma_f32_16x16x32_bf16(av[mi], bh[ni], acc[mi][ni], 0, 0, 0);
          acc[mi][ni] = __builtin_amdgcn_mfma_f32_16x16x32_bf16(av[mi], bl[ni], acc[mi][ni], 0, 0, 0);
        }
    }
    __syncthreads();
  }

  float* Bf = (float*)smb;
  float* Cf = (float*)Cdst;
  #pragma unroll
  for (int h = 0; h < 2; ++h) {
    if (wm == h) {
      #pragma unroll
      for (int mi = 0; mi < 4; ++mi)
        #pragma unroll
        for (int i = 0; i < 4; ++i) {
          int lr2 = mi * 16 + l4 * 4 + i;
          #pragma unroll
          for (int ni = 0; ni < 4; ++ni) {
            int col = wn * 64 + ni * 16 + l15;
            int off = lr2 * 128 + (((col >> 2) ^ (lr2 & 7)) << 2) + (col & 3);
            Bf[off] = acc[mi][ni][i] + bias[n0 + col];
          }
        }
    }
    __syncthreads();
    #pragma unroll
    for (int s = 0; s < 8; ++s) {
      int p = tid * 8 + s;
      int row = p >> 5, ls = p & 31;
      f32x4 v = *reinterpret_cast<const f32x4*>(&Bf[row * 128 + ((ls ^ (row & 7)) << 2)]);
      *reinterpret_cast<f32x4*>(Cf + (size_t)(m0 + h * 64 + row) * ldc + n0 + ls * 4) = v;
    }
    __syncthreads();
  }
}

// ---------------------------------------------------------------------------
// Per-point MLPs (f32 exact) -> relu'd bf16 planes: s2 [pt][64], h2 [pt][128].
// ---------------------------------------------------------------------------
__global__ __launch_bounds__(256)
void points_kernel(const float* __restrict__ obj6,
                   const float* __restrict__ sW0, const float* __restrict__ sb0,
                   const float* __restrict__ sW1, const float* __restrict__ sb1,
                   const float* __restrict__ dW0, const float* __restrict__ db0,
                   const float* __restrict__ dW1, const float* __restrict__ db1,
                   unsigned short* __restrict__ s2,
                   unsigned short* __restrict__ h2)
{
  __shared__ float sw0[96], sbb0[32], sw1[2048], sbb1[64];
  __shared__ float dw0[384], dbb0[64], dw1[8192], dbb1[128];
  int tid = threadIdx.x;
  for (int i = tid; i < 96; i += 256) sw0[i] = sW0[i];
  if (tid < 32) sbb0[tid] = sb0[tid];
  for (int i = tid; i < 2048; i += 256) sw1[i] = sW1[i];
  if (tid < 64) sbb1[tid] = sb1[tid];
  for (int i = tid; i < 384; i += 256) dw0[i] = dW0[i];
  if (tid < 64) dbb0[tid] = db0[tid];
  for (int i = tid; i < 8192; i += 256) dw1[i] = dW1[i];
  if (tid < 128) dbb1[tid] = db1[tid];
  __syncthreads();

  int pt = blockIdx.x * 256 + tid;
  const float* in = obj6 + (size_t)pt * 6;
  float c0 = in[0], c1 = in[1], c2 = in[2], c3 = in[3], c4 = in[4], c5 = in[5];

  {  // sparse (xyz only)
    float h1[32];
    #pragma unroll
    for (int j = 0; j < 32; ++j)
      h1[j] = fmaxf(c0 * sw0[j] + c1 * sw0[32 + j] + c2 * sw0[64 + j] + sbb0[j], 0.f);
    unsigned short* orow = s2 + (size_t)pt * 64;
    #pragma unroll
    for (int j8 = 0; j8 < 8; ++j8) {
      float a[8];
      #pragma unroll
      for (int e = 0; e < 8; ++e) a[e] = sbb1[j8 * 8 + e];
      #pragma unroll
      for (int i = 0; i < 32; ++i) {
        float hv = h1[i];
        #pragma unroll
        for (int e = 0; e < 8; ++e) a[e] += hv * sw1[i * 64 + j8 * 8 + e];
      }
      short8 o;
      #pragma unroll
      for (int e = 0; e < 8; ++e) o[e] = (short)f2bf(fmaxf(a[e], 0.f));
      *reinterpret_cast<short8*>(orow + j8 * 8) = o;
    }
  }

  {  // dense (all 6 dims)
    float h1[64];
    #pragma unroll
    for (int j = 0; j < 64; ++j) {
      float a = dbb0[j] + c0 * dw0[j] + c1 * dw0[64 + j] + c2 * dw0[128 + j]
              + c3 * dw0[192 + j] + c4 * dw0[256 + j] + c5 * dw0[320 + j];
      h1[j] = fmaxf(a, 0.f);
    }
    unsigned short* orow = h2 + (size_t)pt * 128;
    #pragma unroll
    for (int ch = 0; ch < 4; ++ch) {
      float a[32];
      #pragma unroll
      for (int e = 0; e < 32; ++e) a[e] = dbb1[ch * 32 + e];
      #pragma unroll 8
      for (int i = 0; i < 64; ++i) {
        float hv = h1[i];
        #pragma unroll
        for (int e = 0; e < 32; ++e) a[e] += hv * dw1[i * 128 + ch * 32 + e];
      }
      #pragma unroll
      for (int e8 = 0; e8 < 4; ++e8) {
        short8 o;
        #pragma unroll
        for (int e = 0; e < 8; ++e) o[e] = (short)f2bf(fmaxf(a[e8 * 8 + e], 0.f));
        *reinterpret_cast<short8*>(orow + ch * 32 + e8 * 8) = o;
      }
    }
  }
}

// ---------------------------------------------------------------------------
__global__ void transpose_split(const float* __restrict__ W, unsigned short* __restrict__ Wt,
                                int K, int N)
{
  int id = blockIdx.x * 256 + threadIdx.x;
  if (id >= K * N) return;
  int k = id / N, n = id - k * N;
  unsigned short h, l;
  split2(W[id], h, l);
  Wt[(size_t)n * 2 * K + k] = h;
  Wt[(size_t)n * 2 * K + K + k] = l;
}

__global__ void transpose_cast(const float* __restrict__ W, unsigned short* __restrict__ Wt,
                               int K, int N)
{
  int id = blockIdx.x * 256 + threadIdx.x;
  if (id >= K * N) return;
  int k = id / N, n = id - k * N;
  Wt[(size_t)n * K + k] = f2bf(W[id]);
}

__global__ void zero_kernel(unsigned int* __restrict__ p, int n)
{
  int id = blockIdx.x * 256 + threadIdx.x;
  if (id < n) p[id] = 0u;
}

__global__ void pn_pack_kernel(const float* __restrict__ pnf, unsigned short* __restrict__ pnp)
{
  int id = blockIdx.x * 256 + threadIdx.x;  // 851968
  int o = id >> 9, c = id & 511;
  int b = o / 52, n = o - b * 52;
  pnp[((size_t)(n * 32 + b) << 9) + c] = f2bf(pnf[id]);
}

// ---------------------------------------------------------------------------
__global__ __launch_bounds__(256)
void objmlp_kernel(const float* __restrict__ obj,
                   const float* __restrict__ W0, const float* __restrict__ b0,
                   const float* __restrict__ W1, const float* __restrict__ b1,
                   const float* __restrict__ W2, const float* __restrict__ b2,
                   float* __restrict__ out)
{
  __shared__ float x[512];
  __shared__ float h1[128];
  __shared__ float h2[256];
  int tid = threadIdx.x;
  int r = blockIdx.x;
  int n = r >> 5, b = r & 31;
  int o = b * 52 + n;
  const float* xs = obj + (size_t)o * 512;
  x[tid] = xs[tid];
  x[tid + 256] = xs[tid + 256];
  __syncthreads();
  if (tid < 128) {
    float a = b0[tid];
    #pragma unroll 8
    for (int k = 0; k < 512; ++k) a += x[k] * W0[k * 128 + tid];
    h1[tid] = fmaxf(a, 0.f);
  }
  __syncthreads();
  {
    float a = b1[tid];
    #pragma unroll 8
    for (int k = 0; k < 128; ++k) a += h1[k] * W1[k * 256 + tid];
    h2[tid] = fmaxf(a, 0.f);
  }
  __syncthreads();
  for (int j = tid; j < 607; j += 256) {
    float a = b2[j];
    #pragma unroll 8
    for (int k = 0; k < 256; ++k) a += h2[k] * W2[k * 607 + j];
    out[(size_t)r * 607 + j] = a;
  }
}

// ---------------------------------------------------------------------------
extern "C" void kernel_launch(void* const* d_in, const int* in_sizes, int n_in,
                              void* d_out, int out_size, void* d_ws, size_t ws_size,
                              hipStream_t stream)
{
  const float* objects = (const float*)d_in[1];
  const float* de_W0 = (const float*)d_in[3];  const float* de_b0 = (const float*)d_in[4];
  const float* de_W1 = (const float*)d_in[5];  const float* de_b1 = (const float*)d_in[6];
  const float* de_W2 = (const float*)d_in[7];  const float* de_b2 = (const float*)d_in[8];
  const float* de_W3 = (const float*)d_in[9];  const float* de_b3 = (const float*)d_in[10];
  const float* de_W4 = (const float*)d_in[11]; const float* de_b4 = (const float*)d_in[12];
  const float* se_W0 = (const float*)d_in[13]; const float* se_b0 = (const float*)d_in[14];
  const float* se_W1 = (const float*)d_in[15]; const float* se_b1 = (const float*)d_in[16];
  const float* se_W2 = (const float*)d_in[17]; const float* se_b2 = (const float*)d_in[18];
  const float* om_W0 = (const float*)d_in[19]; const float* om_b0 = (const float*)d_in[20];
  const float* om_W1 = (const float*)d_in[21]; const float* om_b1 = (const float*)d_in[22];
  const float* om_W2 = (const float*)d_in[23]; const float* om_b2 = (const float*)d_in[24];
  const float* r1_W = (const float*)d_in[25];  const float* r1_b = (const float*)d_in[26];
  const float* r2_W = (const float*)d_in[27];  const float* r2_b = (const float*)d_in[28];
  const float* m1_W = (const float*)d_in[29];  const float* m1_b = (const float*)d_in[30];
  const float* m2_W = (const float*)d_in[31];  const float* m2_b = (const float*)d_in[32];
  (void)in_sizes; (void)n_in; (void)out_size; (void)ws_size;

  (void)hipFuncSetAttribute(reinterpret_cast<const void*>(&gemmF<0>),
                            hipFuncAttributeMaxDynamicSharedMemorySize, 163840);
  (void)hipFuncSetAttribute(reinterpret_cast<const void*>(&gemmF<1>),
                            hipFuncAttributeMaxDynamicSharedMemorySize, 163840);
  (void)hipFuncSetAttribute(reinterpret_cast<const void*>(&gemmX<2, 64>),
                            hipFuncAttributeMaxDynamicSharedMemorySize, 131072);
  (void)hipFuncSetAttribute(reinterpret_cast<const void*>(&gemmX<1, 128>),
                            hipFuncAttributeMaxDynamicSharedMemorySize, 131072);

  float* outf = (float*)d_out;
  float* out_obj = outf;                          // [52,32,607]
  float* out_rel = outf + 1010048;                // [52,52,32,512]
  float* out_multi = out_rel + 44302336;

  // ---- workspace (~11 MB) ----
  char* ws = (char*)d_ws;
  size_t off = 0;
  auto alloc = [&](size_t bytes) -> void* {
    void* p = ws + off;
    off += (bytes + 255) & ~(size_t)255;
    return p;
  };
  unsigned short* wt_se2 = (unsigned short*)alloc((size_t)512 * 64 * 2);
  unsigned short* wt_de2 = (unsigned short*)alloc((size_t)256 * 128 * 2);
  unsigned short* wt_de3 = (unsigned short*)alloc((size_t)512 * 256 * 2);
  unsigned short* wt_de4 = (unsigned short*)alloc((size_t)512 * 512 * 2);
  unsigned short* wt_g   = (unsigned short*)alloc((size_t)1024 * 1024 * 2);
  unsigned short* wt_r2  = (unsigned short*)alloc((size_t)512 * 512 * 2);
  unsigned short* wt_m1  = (unsigned short*)alloc((size_t)512 * 512 * 2);
  unsigned short* wt_m2  = (unsigned short*)alloc((size_t)512 * 512 * 2);
  float* zbias = (float*)alloc((size_t)1024 * 4);
  float* Gbuf  = (float*)alloc((size_t)1664 * 1024 * 4);

  // ---- arena inside d_out (rel+multi regions) ----
  char* arena = (char*)out_rel;
  unsigned int* pnmax   = (unsigned int*)(arena);              // 3.4 MB
  float*        obj_f32 = (float*)(arena + 3407872);           // 3.4 MB
  unsigned short* pn_p  = (unsigned short*)(arena + 6815744);  // 1.7 MB
  char* cbuf = arena + 8519680;
  const size_t PC = 212992;                                    // 8 chunks
  unsigned short* s2_c = (unsigned short*)(cbuf);                    // 27.3 MB
  unsigned short* h2_c = (unsigned short*)(cbuf + PC * 128);         // 54.5 MB
  unsigned short* h3_c = (unsigned short*)(cbuf + PC * 384);         // 109  MB

  zero_kernel<<<(2 * 851968) / 256, 256, 0, stream>>>(pnmax, 2 * 851968);
  zero_kernel<<<4, 256, 0, stream>>>((unsigned int*)zbias, 1024);

  auto tsplit = [&](const float* W, unsigned short* Dst, int K, int N) {
    int n = K * N;
    transpose_split<<<(n + 255) / 256, 256, 0, stream>>>(W, Dst, K, N);
  };
  auto tcast = [&](const float* W, unsigned short* Dst, int K, int N) {
    int n = K * N;
    transpose_cast<<<(n + 255) / 256, 256, 0, stream>>>(W, Dst, K, N);
  };
  tcast(se_W2, wt_se2, 64, 512);
  tcast(de_W2, wt_de2, 128, 256);
  tcast(de_W3, wt_de3, 256, 512);
  tcast(de_W4, wt_de4, 512, 512);
  tsplit(r1_W,             wt_g,              512, 512);
  tsplit(r1_W + 512 * 512, wt_g + 512 * 1024, 512, 512);
  tcast(r2_W,  wt_r2, 512, 512);
  tcast(m1_W,  wt_m1, 512, 512);
  tcast(m2_W,  wt_m2, 512, 512);

  // ---- point-cloud chains: 8 chunks x 208 objects (212,992 pts) ----
  for (int c = 0; c < 8; ++c) {
    int base = c * (int)PC;
    points_kernel<<<PC / 256, 256, 0, stream>>>(
        objects + (size_t)base * 6,
        se_W0, se_b0, se_W1, se_b1, de_W0, de_b0, de_W1, de_b1, s2_c, h2_c);
    gemmX<2, 64><<<2 * (PC / 256), 512, 131072, stream>>>(
        s2_c, wt_se2, se_b2, nullptr, pnmax, 512, 2, 1, base);
    gemmX<1, 128><<<(PC / 256), 512, 131072, stream>>>(
        h2_c, wt_de2, de_b2, h3_c, nullptr, 256, 1, 1, 0);
    gemmF<0><<<PC / 128, 512, 163840, stream>>>(
        h3_c, nullptr, nullptr, wt_de3, de_b3, wt_de4, de_b4, nullptr, nullptr,
        nullptr, nullptr, (unsigned int*)obj_f32, base);
  }

  pn_pack_kernel<<<851968 / 256, 256, 0, stream>>>((const float*)pnmax, pn_p);
  objmlp_kernel<<<1664, 256, 0, stream>>>(obj_f32, om_W0, om_b0, om_W1, om_b1,
                                          om_W2, om_b2, out_obj);

  // ---- relation chain ----
  gemm3<<<13 * 8, 256, 0, stream>>>(pn_p, wt_g, zbias, Gbuf, 1664, 512, 1024, 8);
  gemmF<1><<<676, 512, 163840, stream>>>(
      nullptr, Gbuf, r1_b, wt_r2, r2_b, wt_m1, m1_b, wt_m2, m2_b,
      out_rel, out_multi, nullptr, 0);
}